// Round 2
// baseline (8536.413 us; speedup 1.0000x reference)
//
#include <hip/hip_runtime.h>
#include <math.h>

namespace {

constexpr int B_ = 256, H_ = 64, L0_ = 640, L1_ = 320, L2_ = 160;
constexpr int N2_ = 32, NL_ = 8, NM_ = 3;

typedef __attribute__((ext_vector_type(8))) short bf16x8;
typedef __attribute__((ext_vector_type(4))) float f32x4;

__device__ __forceinline__ unsigned short f2bf(float x) {
  unsigned int u = __float_as_uint(x);
  unsigned int r = (u + 0x7FFFu + ((u >> 16) & 1u)) >> 16;
  return (unsigned short)r;
}
__device__ __forceinline__ float bf2f(unsigned short h) {
  return __uint_as_float(((unsigned int)h) << 16);
}
__device__ __forceinline__ float gelu_f(float val) {
  const float t = 0.7978845608028654f * (val + 0.044715f * val * val * val);
  return 0.5f * val * (1.f + tanhf(t));
}

// ---------------------------------------------------------------------------
// K precompute: K[m,i,h,l] = 2*Re( sum_n Cc[n] * exp(dtA[n]*l) )
// ---------------------------------------------------------------------------
__global__ void k_compute_K(const float* __restrict__ log_dt,
                            const float* __restrict__ C,
                            const float* __restrict__ logA,
                            const float* __restrict__ Aim,
                            float* __restrict__ Kb) {
  const int bid = blockIdx.x;
  const int m = bid / (NL_ * H_);
  const int rest = bid % (NL_ * H_);
  const int li = rest / H_;
  const int h = rest % H_;
  const int ph = (m * NL_ + li) * H_ + h;
  __shared__ float sAr[N2_], sAi[N2_], sCr[N2_], sCi[N2_];
  const int tid = threadIdx.x;
  if (tid < N2_) {
    const int n = tid;
    const float dt = expf(log_dt[ph]);
    const float Are = -expf(logA[(size_t)ph * N2_ + n]);
    const float Ai = Aim[(size_t)ph * N2_ + n];
    const float ar = dt * Are, ai = dt * Ai;
    const float er = expf(ar);
    float sn, cs;
    sincosf(ai, &sn, &cs);
    const float mr = er * cs - 1.f;
    const float mi = er * sn;
    const float den = Are * Are + Ai * Ai;
    const float qr = (mr * Are + mi * Ai) / den;
    const float qi = (mi * Are - mr * Ai) / den;
    const float C0 = C[((size_t)ph * N2_ + n) * 2 + 0];
    const float C1 = C[((size_t)ph * N2_ + n) * 2 + 1];
    sCr[n] = C0 * qr - C1 * qi;
    sCi[n] = C0 * qi + C1 * qr;
    sAr[n] = ar;
    sAi[n] = ai;
  }
  __syncthreads();
  const int Lm = (m == 0) ? L2_ : (m == 1) ? L1_ : L0_;
  const size_t moff = (m == 0) ? 0
                    : (m == 1) ? (size_t)NL_ * H_ * L2_
                               : (size_t)NL_ * H_ * (L2_ + L1_);
  const size_t off = moff + (size_t)(li * H_ + h) * Lm;
  for (int l = tid; l < Lm; l += blockDim.x) {
    const float fl = (float)l;
    float acc = 0.f;
#pragma unroll
    for (int n = 0; n < N2_; ++n) {
      const float er = expf(sAr[n] * fl);
      float sn, cs;
      sincosf(sAi[n] * fl, &sn, &cs);
      acc += er * (sCr[n] * cs - sCi[n] * sn);
    }
    Kb[off + l] = 2.f * acc;
  }
}

// ---------------------------------------------------------------------------
// Strided conv k=3 s=2 p=1: (B,64,640) -> (B,64,320)
// ---------------------------------------------------------------------------
__global__ void k_conv_d1(const float* __restrict__ x, const float* __restrict__ W,
                          const float* __restrict__ bias, float* __restrict__ out) {
  const int p = blockIdx.x * 256 + threadIdx.x;
  const int t = p % L1_;
  const int o = (p / L1_) % H_;
  const int b = p / (L1_ * H_);
  float acc = bias[o];
  const float* xb = x + (size_t)b * H_ * L0_;
  const float* wo = W + (size_t)o * H_ * 3;
  const int x0 = 2 * t - 1;
  for (int i = 0; i < H_; ++i) {
    const float* xr = xb + (size_t)i * L0_;
    const float w0 = wo[i * 3 + 0], w1 = wo[i * 3 + 1], w2 = wo[i * 3 + 2];
    float s = w1 * xr[x0 + 1] + w2 * xr[x0 + 2];
    if (x0 >= 0) s += w0 * xr[x0];
    acc += s;
  }
  out[p] = acc;
}

// Strided conv k=2 s=2 p=0: (B,64,320) -> (B,64,160)
__global__ void k_conv_d2(const float* __restrict__ x, const float* __restrict__ W,
                          const float* __restrict__ bias, float* __restrict__ out) {
  const int p = blockIdx.x * 256 + threadIdx.x;
  const int t = p % L2_;
  const int o = (p / L2_) % H_;
  const int b = p / (L2_ * H_);
  float acc = bias[o];
  const float* xb = x + (size_t)b * H_ * L1_;
  const float* wo = W + (size_t)o * H_ * 2;
  for (int i = 0; i < H_; ++i) {
    const float* xr = xb + (size_t)i * L1_;
    acc += wo[i * 2 + 0] * xr[2 * t] + wo[i * 2 + 1] * xr[2 * t + 1];
  }
  out[p] = acc;
}

// ---------------------------------------------------------------------------
// ConvTranspose1d k=3 s=2 p=1 op=1, W layout (in,out,k). out = convT(in)+bias?+skip
// Thread per (b,j): computes outputs 2j (even) and 2j+1 (odd).
//   even: sum_i W[i,o,1]*x[i,j];  odd: sum_i W[i,o,2]*x[i,j] + W[i,o,0]*x[i,j+1]
// Weights transposed to LDS [k][o][i] once per block.
// ---------------------------------------------------------------------------
__global__ void k_convT(const float* __restrict__ in_, const float* __restrict__ W,
                        const float* __restrict__ bias, const float* __restrict__ skip,
                        float* __restrict__ out, int Lin, int hasBias) {
  __shared__ float Ws[3 * H_ * H_];  // [k][o][i]
  const int tid = threadIdx.x;
  for (int idx = tid; idx < 3 * H_ * H_; idx += 256) {
    const int i = idx / 192;
    const int o = (idx / 3) % H_;
    const int k = idx % 3;
    Ws[k * 4096 + o * 64 + i] = W[idx];
  }
  __syncthreads();
  const int p = blockIdx.x * 256 + tid;
  const int j = p % Lin;
  const int b = p / Lin;
  const int Lout = 2 * Lin;
  const float* xb = in_ + (size_t)b * H_ * Lin;
  float xr[H_], xn[H_];
  const bool ok1 = (j + 1) < Lin;
#pragma unroll
  for (int i = 0; i < H_; ++i) {
    const float* col = xb + (size_t)i * Lin + j;
    xr[i] = col[0];
    xn[i] = ok1 ? col[1] : 0.f;
  }
  const size_t ob = (size_t)b * H_ * Lout + 2 * j;
  for (int o = 0; o < H_; ++o) {
    const float4* w1 = (const float4*)(Ws + 4096 + o * 64);
    const float4* w2 = (const float4*)(Ws + 8192 + o * 64);
    const float4* w0 = (const float4*)(Ws + o * 64);
    float ae = 0.f, ao = 0.f;
#pragma unroll
    for (int q = 0; q < 16; ++q) {
      const float4 a = w1[q], c = w2[q], z = w0[q];
      const float x0 = xr[4 * q], x1 = xr[4 * q + 1], x2 = xr[4 * q + 2], x3 = xr[4 * q + 3];
      const float n0 = xn[4 * q], n1 = xn[4 * q + 1], n2 = xn[4 * q + 2], n3 = xn[4 * q + 3];
      ae += a.x * x0 + a.y * x1 + a.z * x2 + a.w * x3;
      ao += c.x * x0 + c.y * x1 + c.z * x2 + c.w * x3;
      ao += z.x * n0 + z.y * n1 + z.z * n2 + z.w * n3;
    }
    const float bb = hasBias ? bias[o] : 0.f;
    const size_t pos = ob + (size_t)o * Lout;
    out[pos] = ae + bb + skip[pos];
    out[pos + 1] = ao + bb + skip[pos + 1];
  }
}

// elementwise a += b
__global__ void k_add(float* a, const float* __restrict__ b) {
  const int p = blockIdx.x * 256 + threadIdx.x;
  a[p] += b[p];
}

// ---------------------------------------------------------------------------
// 1x1 encoder: out[b,o,l] = bias[o] + sum_i W[o,i]*in[b,i,l]  (in may == out)
// ---------------------------------------------------------------------------
__global__ void k_encoder(const float* __restrict__ W, const float* __restrict__ bvec,
                          const float* in_, float* out, int Lcur) {
  __shared__ float Ws[H_ * H_];
  __shared__ float bsh[H_];
  const int tid = threadIdx.x;
  for (int idx = tid; idx < H_ * H_; idx += 256) Ws[idx] = W[idx];
  if (tid < H_) bsh[tid] = bvec[tid];
  __syncthreads();
  const int p = blockIdx.x * 256 + tid;
  const int b = p / Lcur;
  const int l = p % Lcur;
  const size_t base = (size_t)b * H_ * Lcur + l;
  float xr[H_];
#pragma unroll
  for (int i = 0; i < H_; ++i) xr[i] = in_[base + (size_t)i * Lcur];
  for (int o = 0; o < H_; ++o) {
    float a = bsh[o];
    const float4* wr = (const float4*)(Ws + o * H_);
#pragma unroll
    for (int q = 0; q < 16; ++q) {
      const float4 v = wr[q];
      a += v.x * xr[4 * q] + v.y * xr[4 * q + 1] + v.z * xr[4 * q + 2] + v.w * xr[4 * q + 3];
    }
    out[base + (size_t)o * Lcur] = a;
  }
}

// ---------------------------------------------------------------------------
// MFMA causal conv + D-skip + gelu:  y = gelu(causal_conv(u,K) + u*D)
// Block: 256 thr (4 waves), handles (32 batches, one h). u split hi/lo bf16
// (u exact); K single bf16 in Toeplitz fragment tiles. Wave owns 2 b-tiles x
// 4 l-tiles; per j-step: 4 A-frag + <=4 B-frag ds_read_b128, up to 16 MFMA.
// ---------------------------------------------------------------------------
template <int L>
__global__ __launch_bounds__(256) void k_conv_gelu_mfma(
    const float* __restrict__ u, const float* __restrict__ Kl,
    const float* __restrict__ D, float* __restrict__ y) {
  constexpr int NT = L / 16;           // # 16-wide l-tiles (and Toeplitz tiles)
  constexpr int NG = (NT + 3) / 4;     // groups of 4 l-tiles
  constexpr int LP = L + 8;            // padded row stride (bank shift of 4)
  extern __shared__ char smem[];
  unsigned short* uhi = (unsigned short*)smem;          // [32][LP]
  unsigned short* ulo = uhi + 32 * LP;                  // [32][LP]
  unsigned short* Tt  = ulo + 32 * LP;                  // [NT][64][8]
  float* Ksh = (float*)(Tt + NT * 512);                 // [L]

  const int h = blockIdx.x & 63;
  const int b0 = (blockIdx.x >> 6) * 32;
  const int tid = threadIdx.x;

  // --- stage u (hi/lo bf16) ---
  constexpr int PR = L / 2;
  for (int wp = tid; wp < 32 * PR; wp += 256) {
    const int row = wp / PR, cp = wp % PR;
    const float2 v = *(const float2*)(u + ((size_t)(b0 + row) * H_ + h) * L + 2 * cp);
    const unsigned short h0 = f2bf(v.x), h1 = f2bf(v.y);
    const unsigned short q0 = f2bf(v.x - bf2f(h0)), q1 = f2bf(v.y - bf2f(h1));
    *(unsigned int*)&uhi[row * LP + 2 * cp] = (unsigned int)h0 | ((unsigned int)h1 << 16);
    *(unsigned int*)&ulo[row * LP + 2 * cp] = (unsigned int)q0 | ((unsigned int)q1 << 16);
  }
  // --- stage K row ---
  const float* Krow = Kl + (size_t)h * L;
  for (int l = tid; l < L; l += 256) Ksh[l] = Krow[l];
  __syncthreads();
  // --- build Toeplitz fragment tiles: Tt[nd][lane][i] = K[nd*16 + (lane&15) - (lane>>4)*8 - i]
  for (int w = tid; w < NT * 256; w += 256) {
    const int nd = w >> 8;
    const int rem = w & 255;
    const int lane = rem >> 2;
    const int pp = rem & 3;
    const int base = nd * 16 + (lane & 15) - ((lane >> 4) << 3) - 2 * pp;
    const float f0 = (base >= 0) ? Ksh[base] : 0.f;
    const float f1 = (base - 1 >= 0) ? Ksh[base - 1] : 0.f;
    *(unsigned int*)&Tt[nd * 512 + lane * 8 + 2 * pp] =
        (unsigned int)f2bf(f0) | ((unsigned int)f2bf(f1) << 16);
  }
  __syncthreads();

  const int wv = tid >> 6;
  const int lane = tid & 63;
  const float Dh = D[h];
  const int lquad = lane & 15;
  const int lhi = lane >> 4;

  for (int g = wv; g < NG; g += 4) {
    const int t0 = g * 4;
    const int ntile = (NT - t0 < 4) ? (NT - t0) : 4;
    f32x4 acc[2][4];
#pragma unroll
    for (int a = 0; a < 2; ++a)
#pragma unroll
      for (int t = 0; t < 4; ++t) acc[a][t] = (f32x4){0.f, 0.f, 0.f, 0.f};
    const int lt_last = (t0 + ntile - 1) * 16;
    const int nsteps = lt_last / 32 + 1;
    for (int s = 0; s < nsteps; ++s) {
      const int j0 = 32 * s;
      const int colbase = j0 + (lhi << 3);
      bf16x8 ah0 = *(const bf16x8*)&uhi[(0 + lquad) * LP + colbase];
      bf16x8 al0 = *(const bf16x8*)&ulo[(0 + lquad) * LP + colbase];
      bf16x8 ah1 = *(const bf16x8*)&uhi[(16 + lquad) * LP + colbase];
      bf16x8 al1 = *(const bf16x8*)&ulo[(16 + lquad) * LP + colbase];
#pragma unroll
      for (int t = 0; t < 4; ++t) {
        if (t >= ntile) break;
        const int d0 = (t0 + t) * 16 - j0;
        if (d0 < 0) continue;  // causal: uniform across wave
        const bf16x8 bf = *(const bf16x8*)&Tt[(d0 >> 4) * 512 + lane * 8];
        acc[0][t] = __builtin_amdgcn_mfma_f32_16x16x32_bf16(ah0, bf, acc[0][t], 0, 0, 0);
        acc[0][t] = __builtin_amdgcn_mfma_f32_16x16x32_bf16(al0, bf, acc[0][t], 0, 0, 0);
        acc[1][t] = __builtin_amdgcn_mfma_f32_16x16x32_bf16(ah1, bf, acc[1][t], 0, 0, 0);
        acc[1][t] = __builtin_amdgcn_mfma_f32_16x16x32_bf16(al1, bf, acc[1][t], 0, 0, 0);
      }
    }
    // epilogue: D-skip + gelu + store
#pragma unroll
    for (int t = 0; t < 4; ++t) {
      if (t >= ntile) break;
      const int l = (t0 + t) * 16 + lquad;
#pragma unroll
      for (int a = 0; a < 2; ++a) {
#pragma unroll
        for (int r = 0; r < 4; ++r) {
          const int row = a * 16 + (lhi << 2) + r;
          const float uv = bf2f(uhi[row * LP + l]) + bf2f(ulo[row * LP + l]);
          const float val = acc[a][t][r] + uv * Dh;
          y[((size_t)(b0 + row) * H_ + h) * L + l] = gelu_f(val);
        }
      }
    }
  }
}

// ---------------------------------------------------------------------------
// Out-proj (64->128) + GLU + residual + LayerNorm(channel).
// ---------------------------------------------------------------------------
__global__ void k_out_glu_ln(const float* __restrict__ oW, const float* __restrict__ ob,
                             const float* __restrict__ lng, const float* __restrict__ lnb,
                             float* __restrict__ ybuf, float* xbuf, float* obuf, int Lcur) {
  __shared__ float Ws[2 * H_ * H_];
  __shared__ float obs[2 * H_];
  __shared__ float gs[H_], bs[H_];
  const int tid = threadIdx.x;
  for (int idx = tid; idx < 2 * H_ * H_; idx += 256) Ws[idx] = oW[idx];
  if (tid < 2 * H_) obs[tid] = ob[tid];
  if (tid < H_) { gs[tid] = lng[tid]; bs[tid] = lnb[tid]; }
  __syncthreads();
  const int p = blockIdx.x * 256 + tid;
  const int b = p / Lcur;
  const int l = p % Lcur;
  const size_t base = (size_t)b * H_ * Lcur + l;
  float yr[H_];
#pragma unroll
  for (int c = 0; c < H_; ++c) yr[c] = ybuf[base + (size_t)c * Lcur];
  float sum = 0.f, ss = 0.f;
  for (int c = 0; c < H_; ++c) {
    float a = obs[c], g = obs[c + H_];
    const float4* wa = (const float4*)(Ws + c * H_);
    const float4* wg = (const float4*)(Ws + (c + H_) * H_);
#pragma unroll
    for (int q = 0; q < 16; ++q) {
      const float4 va = wa[q], vg = wg[q];
      a += va.x * yr[4 * q] + va.y * yr[4 * q + 1] + va.z * yr[4 * q + 2] + va.w * yr[4 * q + 3];
      g += vg.x * yr[4 * q] + vg.y * yr[4 * q + 1] + vg.z * yr[4 * q + 2] + vg.w * yr[4 * q + 3];
    }
    const float z = a / (1.f + expf(-g));
    const float wv = z + xbuf[base + (size_t)c * Lcur];
    sum += wv;
    ss += wv * wv;
    ybuf[base + (size_t)c * Lcur] = wv;
  }
  const float mean = sum * (1.f / 64.f);
  const float var = ss * (1.f / 64.f) - mean * mean;
  const float rstd = rsqrtf(var + 1e-5f);
  for (int c = 0; c < H_; ++c) {
    const float wv = ybuf[base + (size_t)c * Lcur];
    obuf[base + (size_t)c * Lcur] = (wv - mean) * rstd * gs[c] + bs[c];
  }
}

template <int L>
constexpr size_t conv_smem_bytes() {
  return (size_t)(2 * 32 * (L + 8)) * 2 + (size_t)(L / 16) * 512 * 2 + (size_t)L * 4;
}

}  // namespace

// ---------------------------------------------------------------------------
extern "C" void kernel_launch(void* const* d_in, const int* in_sizes, int n_in,
                              void* d_out, int out_size, void* d_ws, size_t ws_size,
                              hipStream_t stream) {
  const float* x       = (const float*)d_in[0];
  const float* enc_W   = (const float*)d_in[1];
  const float* enc_b   = (const float*)d_in[2];
  const float* ln_g    = (const float*)d_in[3];
  const float* ln_b    = (const float*)d_in[4];
  const float* s4_D    = (const float*)d_in[5];
  const float* s4_ldt  = (const float*)d_in[6];
  const float* s4_C    = (const float*)d_in[7];
  const float* s4_logA = (const float*)d_in[8];
  const float* s4_Aim  = (const float*)d_in[9];
  const float* out_W   = (const float*)d_in[10];
  const float* out_b   = (const float*)d_in[11];
  const float* cd1_W   = (const float*)d_in[12];
  const float* cd1_b   = (const float*)d_in[13];
  const float* cd2_W   = (const float*)d_in[14];
  const float* cd2_b   = (const float*)d_in[15];
  const float* up_W    = (const float*)d_in[16];
  const float* up_b    = (const float*)d_in[17];
  const float* up1_W   = (const float*)d_in[18];
  float* outp = (float*)d_out;

  // Allow >64KB dynamic LDS for the L=640 conv (126.5 KB). Idempotent.
  static_assert(conv_smem_bytes<L0_>() < 160 * 1024, "LDS overflow");
  hipFuncSetAttribute(reinterpret_cast<const void*>(&k_conv_gelu_mfma<L0_>),
                      hipFuncAttributeMaxDynamicSharedMemorySize,
                      (int)conv_smem_bytes<L0_>());
  hipFuncSetAttribute(reinterpret_cast<const void*>(&k_conv_gelu_mfma<L1_>),
                      hipFuncAttributeMaxDynamicSharedMemorySize,
                      (int)conv_smem_bytes<L1_>());
  hipFuncSetAttribute(reinterpret_cast<const void*>(&k_conv_gelu_mfma<L2_>),
                      hipFuncAttributeMaxDynamicSharedMemorySize,
                      (int)conv_smem_bytes<L2_>());

  // Workspace layout (floats); total ~112.2 MB
  float* ws   = (float*)d_ws;
  float* bufA = ws;                                   // B*H*L0
  float* bufB = bufA + (size_t)B_ * H_ * L0_;         // B*H*L0
  float* enc1 = bufB + (size_t)B_ * H_ * L0_;         // B*H*L1
  float* enc2 = enc1 + (size_t)B_ * H_ * L1_;         // B*H*L2
  float* Kb   = enc2 + (size_t)B_ * H_ * L2_;         // NL*H*(L2+L1+L0)

  const size_t koff0 = 0;
  const size_t koff1 = (size_t)NL_ * H_ * L2_;
  const size_t koff2 = koff1 + (size_t)NL_ * H_ * L1_;

  k_compute_K<<<NM_ * NL_ * H_, 256, 0, stream>>>(s4_ldt, s4_C, s4_logA, s4_Aim, Kb);
  k_conv_d1<<<(B_ * H_ * L1_) / 256, 256, 0, stream>>>(x, cd1_W, cd1_b, enc1);
  k_conv_d2<<<(B_ * H_ * L2_) / 256, 256, 0, stream>>>(enc1, cd2_W, cd2_b, enc2);

  auto run_model = [&](int m, const float* input, float* state, float* scratch,
                       int Lm, size_t koff, float* final_out) {
    const int BL = B_ * Lm;
    k_encoder<<<BL / 256, 256, 0, stream>>>(enc_W + (size_t)m * H_ * H_,
                                            enc_b + (size_t)m * H_, input, state, Lm);
    for (int i = 0; i < NL_; ++i) {
      const float* Kl = Kb + koff + (size_t)i * H_ * Lm;
      const float* Dl = s4_D + ((size_t)m * NL_ + i) * H_;
      if (Lm == L2_)
        k_conv_gelu_mfma<L2_><<<(B_ / 32) * H_, 256, conv_smem_bytes<L2_>(), stream>>>(
            state, Kl, Dl, scratch);
      else if (Lm == L1_)
        k_conv_gelu_mfma<L1_><<<(B_ / 32) * H_, 256, conv_smem_bytes<L1_>(), stream>>>(
            state, Kl, Dl, scratch);
      else
        k_conv_gelu_mfma<L0_><<<(B_ / 32) * H_, 256, conv_smem_bytes<L0_>(), stream>>>(
            state, Kl, Dl, scratch);
      float* obuf = (i == NL_ - 1 && final_out) ? final_out : state;
      k_out_glu_ln<<<BL / 256, 256, 0, stream>>>(
          out_W + ((size_t)m * NL_ + i) * 2 * H_ * H_,
          out_b + ((size_t)m * NL_ + i) * 2 * H_,
          ln_g + ((size_t)m * NL_ + i) * H_,
          ln_b + ((size_t)m * NL_ + i) * H_,
          scratch, state, obuf, Lm);
    }
  };

  // model 0 on enc2 (L=160)
  run_model(0, enc2, bufA, bufB, L2_, koff0, nullptr);
  // dec1 = enc2 + enc21
  k_add<<<(B_ * H_ * L2_) / 256, 256, 0, stream>>>(enc2, bufA);
  // dec21 = convT(dec1, up_W) + up_b + enc1  -> bufA
  k_convT<<<(B_ * L2_) / 256, 256, 0, stream>>>(enc2, up_W, up_b, enc1, bufA, L2_, 1);
  // model 1 on dec21 (L=320), in place in bufA
  run_model(1, bufA, bufA, bufB, L1_, koff1, nullptr);
  // dec32 = convT(dec2, up1_W) + enc0  -> bufB
  k_convT<<<(B_ * L1_) / 256, 256, 0, stream>>>(bufA, up1_W, up_b, x, bufB, L1_, 0);
  // model 2 on dec32 (L=640); final layer writes d_out
  run_model(2, bufB, bufB, bufA, L0_, koff2, outp);
}

// Round 3
// 5085.607 us; speedup vs baseline: 1.6785x; 1.6785x over previous
//
#include <hip/hip_runtime.h>
#include <math.h>

namespace {

constexpr int B_ = 256, H_ = 64, L0_ = 640, L1_ = 320, L2_ = 160;
constexpr int N2_ = 32, NL_ = 8, NM_ = 3;

typedef __attribute__((ext_vector_type(8))) short bf16x8;
typedef __attribute__((ext_vector_type(4))) float f32x4;

__device__ __forceinline__ unsigned short f2bf(float x) {
  unsigned int u = __float_as_uint(x);
  unsigned int r = (u + 0x7FFFu + ((u >> 16) & 1u)) >> 16;
  return (unsigned short)r;
}
__device__ __forceinline__ float bf2f(unsigned short h) {
  return __uint_as_float(((unsigned int)h) << 16);
}
__device__ __forceinline__ float gelu_f(float val) {
  const float t = 0.7978845608028654f * (val + 0.044715f * val * val * val);
  return 0.5f * val * (1.f + tanhf(t));
}

// ---------------------------------------------------------------------------
// K precompute: K[m,i,h,l] = 2*Re( sum_n Cc[n] * exp(dtA[n]*l) )
// ---------------------------------------------------------------------------
__global__ void k_compute_K(const float* __restrict__ log_dt,
                            const float* __restrict__ C,
                            const float* __restrict__ logA,
                            const float* __restrict__ Aim,
                            float* __restrict__ Kb) {
  const int bid = blockIdx.x;
  const int m = bid / (NL_ * H_);
  const int rest = bid % (NL_ * H_);
  const int li = rest / H_;
  const int h = rest % H_;
  const int ph = (m * NL_ + li) * H_ + h;
  __shared__ float sAr[N2_], sAi[N2_], sCr[N2_], sCi[N2_];
  const int tid = threadIdx.x;
  if (tid < N2_) {
    const int n = tid;
    const float dt = expf(log_dt[ph]);
    const float Are = -expf(logA[(size_t)ph * N2_ + n]);
    const float Ai = Aim[(size_t)ph * N2_ + n];
    const float ar = dt * Are, ai = dt * Ai;
    const float er = expf(ar);
    float sn, cs;
    sincosf(ai, &sn, &cs);
    const float mr = er * cs - 1.f;
    const float mi = er * sn;
    const float den = Are * Are + Ai * Ai;
    const float qr = (mr * Are + mi * Ai) / den;
    const float qi = (mi * Are - mr * Ai) / den;
    const float C0 = C[((size_t)ph * N2_ + n) * 2 + 0];
    const float C1 = C[((size_t)ph * N2_ + n) * 2 + 1];
    sCr[n] = C0 * qr - C1 * qi;
    sCi[n] = C0 * qi + C1 * qr;
    sAr[n] = ar;
    sAi[n] = ai;
  }
  __syncthreads();
  const int Lm = (m == 0) ? L2_ : (m == 1) ? L1_ : L0_;
  const size_t moff = (m == 0) ? 0
                    : (m == 1) ? (size_t)NL_ * H_ * L2_
                               : (size_t)NL_ * H_ * (L2_ + L1_);
  const size_t off = moff + (size_t)(li * H_ + h) * Lm;
  for (int l = tid; l < Lm; l += blockDim.x) {
    const float fl = (float)l;
    float acc = 0.f;
#pragma unroll
    for (int n = 0; n < N2_; ++n) {
      const float er = expf(sAr[n] * fl);
      float sn, cs;
      sincosf(sAi[n] * fl, &sn, &cs);
      acc += er * (sCr[n] * cs - sCi[n] * sn);
    }
    Kb[off + l] = 2.f * acc;
  }
}

// ---------------------------------------------------------------------------
// Strided conv k=3 s=2 p=1: (B,64,640) -> (B,64,320)
// ---------------------------------------------------------------------------
__global__ void k_conv_d1(const float* __restrict__ x, const float* __restrict__ W,
                          const float* __restrict__ bias, float* __restrict__ out) {
  const int p = blockIdx.x * 256 + threadIdx.x;
  const int t = p % L1_;
  const int o = (p / L1_) % H_;
  const int b = p / (L1_ * H_);
  float acc = bias[o];
  const float* xb = x + (size_t)b * H_ * L0_;
  const float* wo = W + (size_t)o * H_ * 3;
  const int x0 = 2 * t - 1;
  for (int i = 0; i < H_; ++i) {
    const float* xr = xb + (size_t)i * L0_;
    const float w0 = wo[i * 3 + 0], w1 = wo[i * 3 + 1], w2 = wo[i * 3 + 2];
    float s = w1 * xr[x0 + 1] + w2 * xr[x0 + 2];
    if (x0 >= 0) s += w0 * xr[x0];
    acc += s;
  }
  out[p] = acc;
}

// Strided conv k=2 s=2 p=0: (B,64,320) -> (B,64,160)
__global__ void k_conv_d2(const float* __restrict__ x, const float* __restrict__ W,
                          const float* __restrict__ bias, float* __restrict__ out) {
  const int p = blockIdx.x * 256 + threadIdx.x;
  const int t = p % L2_;
  const int o = (p / L2_) % H_;
  const int b = p / (L2_ * H_);
  float acc = bias[o];
  const float* xb = x + (size_t)b * H_ * L1_;
  const float* wo = W + (size_t)o * H_ * 2;
  for (int i = 0; i < H_; ++i) {
    const float* xr = xb + (size_t)i * L1_;
    acc += wo[i * 2 + 0] * xr[2 * t] + wo[i * 2 + 1] * xr[2 * t + 1];
  }
  out[p] = acc;
}

// ---------------------------------------------------------------------------
// ConvTranspose1d k=3 s=2 p=1 op=1, W layout (in,out,k). out = convT(in)+bias?+skip
// Thread owns ONE input column j (xr[64] regs, no second array -> no spill).
//   even out[2j]   = sum_i W[i,o,1]*x[i,j]                      = e
//   odd  out[2j+1] = sum_i W[i,o,2]*x[i,j] + W[i,o,0]*x[i,j+1]  = c_j + a_{j+1}
// a_{j+1} fetched from lane+1 via __shfl_down. Waves advance 63 positions so
// every odd output is produced by a lane<63; lane 63 only donates its a
// (its even write duplicates next wave's lane 0 - same value, benign).
// ---------------------------------------------------------------------------
__global__ __launch_bounds__(256) void k_convT(
    const float* __restrict__ in_, const float* __restrict__ W,
    const float* __restrict__ bias, const float* __restrict__ skip,
    float* __restrict__ out, int Lin, int hasBias, int nPos) {
  __shared__ float Ws[3 * H_ * H_];  // [k][o][i]
  __shared__ float bsh[H_];
  const int tid = threadIdx.x;
  for (int idx = tid; idx < 3 * H_ * H_; idx += 256) {
    const int k = idx >> 12;
    const int rem = idx & 4095;
    const int o = rem >> 6;
    const int i = rem & 63;
    Ws[idx] = W[((size_t)i * H_ + o) * 3 + k];
  }
  if (tid < H_) bsh[tid] = hasBias ? bias[tid] : 0.f;
  __syncthreads();

  const int gw = (blockIdx.x * 256 + tid) >> 6;  // global wave id
  const int lane = tid & 63;
  const int bj = gw * 63 + lane;
  const bool valid = bj < nPos;
  const int bjc = valid ? bj : (nPos - 1);
  const int b = bjc / Lin;
  const int j = bjc % Lin;
  const bool lastcol = (j == Lin - 1);
  const int Lout = 2 * Lin;

  float xr[H_];
  const float* xcol = in_ + (size_t)b * H_ * Lin + j;
#pragma unroll
  for (int i = 0; i < H_; ++i) xr[i] = valid ? xcol[(size_t)i * Lin] : 0.f;

  const size_t obase = (size_t)b * H_ * Lout + 2 * j;
  for (int o = 0; o < H_; ++o) {
    const float4* w0 = (const float4*)(Ws + o * 64);           // k=0
    const float4* w1 = (const float4*)(Ws + 4096 + o * 64);    // k=1
    const float4* w2 = (const float4*)(Ws + 8192 + o * 64);    // k=2
    float e = 0.f, c = 0.f, a = 0.f;
#pragma unroll
    for (int q = 0; q < 16; ++q) {
      const float4 v1 = w1[q], v2 = w2[q], v0 = w0[q];
      const float x0 = xr[4 * q], x1 = xr[4 * q + 1], x2 = xr[4 * q + 2], x3 = xr[4 * q + 3];
      e += v1.x * x0 + v1.y * x1 + v1.z * x2 + v1.w * x3;
      c += v2.x * x0 + v2.y * x1 + v2.z * x2 + v2.w * x3;
      a += v0.x * x0 + v0.y * x1 + v0.z * x2 + v0.w * x3;
    }
    const float an = __shfl_down(a, 1);  // a_{j+1} from lane+1
    if (valid) {
      const float bb = bsh[o];
      const size_t pe = obase + (size_t)o * Lout;
      out[pe] = e + bb + skip[pe];
      if (lane < 63) {
        const float oadd = lastcol ? 0.f : an;
        out[pe + 1] = c + oadd + bb + skip[pe + 1];
      }
    }
  }
}

// elementwise a += b
__global__ void k_add(float* a, const float* __restrict__ b) {
  const int p = blockIdx.x * 256 + threadIdx.x;
  a[p] += b[p];
}

// ---------------------------------------------------------------------------
// 1x1 encoder: out[b,o,l] = bias[o] + sum_i W[o,i]*in[b,i,l]  (in may == out)
// ---------------------------------------------------------------------------
__global__ void k_encoder(const float* __restrict__ W, const float* __restrict__ bvec,
                          const float* in_, float* out, int Lcur) {
  __shared__ float Ws[H_ * H_];
  __shared__ float bsh[H_];
  const int tid = threadIdx.x;
  for (int idx = tid; idx < H_ * H_; idx += 256) Ws[idx] = W[idx];
  if (tid < H_) bsh[tid] = bvec[tid];
  __syncthreads();
  const int p = blockIdx.x * 256 + tid;
  const int b = p / Lcur;
  const int l = p % Lcur;
  const size_t base = (size_t)b * H_ * Lcur + l;
  float xr[H_];
#pragma unroll
  for (int i = 0; i < H_; ++i) xr[i] = in_[base + (size_t)i * Lcur];
  for (int o = 0; o < H_; ++o) {
    float a = bsh[o];
    const float4* wr = (const float4*)(Ws + o * H_);
#pragma unroll
    for (int q = 0; q < 16; ++q) {
      const float4 v = wr[q];
      a += v.x * xr[4 * q] + v.y * xr[4 * q + 1] + v.z * xr[4 * q + 2] + v.w * xr[4 * q + 3];
    }
    out[base + (size_t)o * Lcur] = a;
  }
}

// ---------------------------------------------------------------------------
// MFMA causal conv + D-skip + gelu:  y = gelu(causal_conv(u,K) + u*D)
// ---------------------------------------------------------------------------
template <int L>
__global__ __launch_bounds__(256) void k_conv_gelu_mfma(
    const float* __restrict__ u, const float* __restrict__ Kl,
    const float* __restrict__ D, float* __restrict__ y) {
  constexpr int NT = L / 16;
  constexpr int NG = (NT + 3) / 4;
  constexpr int LP = L + 8;
  extern __shared__ char smem[];
  unsigned short* uhi = (unsigned short*)smem;          // [32][LP]
  unsigned short* ulo = uhi + 32 * LP;                  // [32][LP]
  unsigned short* Tt  = ulo + 32 * LP;                  // [NT][64][8]
  float* Ksh = (float*)(Tt + NT * 512);                 // [L]

  const int h = blockIdx.x & 63;
  const int b0 = (blockIdx.x >> 6) * 32;
  const int tid = threadIdx.x;

  constexpr int PR = L / 2;
  for (int wp = tid; wp < 32 * PR; wp += 256) {
    const int row = wp / PR, cp = wp % PR;
    const float2 v = *(const float2*)(u + ((size_t)(b0 + row) * H_ + h) * L + 2 * cp);
    const unsigned short h0 = f2bf(v.x), h1 = f2bf(v.y);
    const unsigned short q0 = f2bf(v.x - bf2f(h0)), q1 = f2bf(v.y - bf2f(h1));
    *(unsigned int*)&uhi[row * LP + 2 * cp] = (unsigned int)h0 | ((unsigned int)h1 << 16);
    *(unsigned int*)&ulo[row * LP + 2 * cp] = (unsigned int)q0 | ((unsigned int)q1 << 16);
  }
  const float* Krow = Kl + (size_t)h * L;
  for (int l = tid; l < L; l += 256) Ksh[l] = Krow[l];
  __syncthreads();
  for (int w = tid; w < NT * 256; w += 256) {
    const int nd = w >> 8;
    const int rem = w & 255;
    const int lane = rem >> 2;
    const int pp = rem & 3;
    const int base = nd * 16 + (lane & 15) - ((lane >> 4) << 3) - 2 * pp;
    const float f0 = (base >= 0) ? Ksh[base] : 0.f;
    const float f1 = (base - 1 >= 0) ? Ksh[base - 1] : 0.f;
    *(unsigned int*)&Tt[nd * 512 + lane * 8 + 2 * pp] =
        (unsigned int)f2bf(f0) | ((unsigned int)f2bf(f1) << 16);
  }
  __syncthreads();

  const int wv = tid >> 6;
  const int lane = tid & 63;
  const float Dh = D[h];
  const int lquad = lane & 15;
  const int lhi = lane >> 4;

  for (int g = wv; g < NG; g += 4) {
    const int t0 = g * 4;
    const int ntile = (NT - t0 < 4) ? (NT - t0) : 4;
    f32x4 acc[2][4];
#pragma unroll
    for (int a = 0; a < 2; ++a)
#pragma unroll
      for (int t = 0; t < 4; ++t) acc[a][t] = (f32x4){0.f, 0.f, 0.f, 0.f};
    const int lt_last = (t0 + ntile - 1) * 16;
    const int nsteps = lt_last / 32 + 1;
    for (int s = 0; s < nsteps; ++s) {
      const int j0 = 32 * s;
      const int colbase = j0 + (lhi << 3);
      bf16x8 ah0 = *(const bf16x8*)&uhi[(0 + lquad) * LP + colbase];
      bf16x8 al0 = *(const bf16x8*)&ulo[(0 + lquad) * LP + colbase];
      bf16x8 ah1 = *(const bf16x8*)&uhi[(16 + lquad) * LP + colbase];
      bf16x8 al1 = *(const bf16x8*)&ulo[(16 + lquad) * LP + colbase];
#pragma unroll
      for (int t = 0; t < 4; ++t) {
        if (t >= ntile) break;
        const int d0 = (t0 + t) * 16 - j0;
        if (d0 < 0) continue;
        const bf16x8 bf = *(const bf16x8*)&Tt[(d0 >> 4) * 512 + lane * 8];
        acc[0][t] = __builtin_amdgcn_mfma_f32_16x16x32_bf16(ah0, bf, acc[0][t], 0, 0, 0);
        acc[0][t] = __builtin_amdgcn_mfma_f32_16x16x32_bf16(al0, bf, acc[0][t], 0, 0, 0);
        acc[1][t] = __builtin_amdgcn_mfma_f32_16x16x32_bf16(ah1, bf, acc[1][t], 0, 0, 0);
        acc[1][t] = __builtin_amdgcn_mfma_f32_16x16x32_bf16(al1, bf, acc[1][t], 0, 0, 0);
      }
    }
#pragma unroll
    for (int t = 0; t < 4; ++t) {
      if (t >= ntile) break;
      const int l = (t0 + t) * 16 + lquad;
#pragma unroll
      for (int a = 0; a < 2; ++a) {
#pragma unroll
        for (int r = 0; r < 4; ++r) {
          const int row = a * 16 + (lhi << 2) + r;
          const float uv = bf2f(uhi[row * LP + l]) + bf2f(ulo[row * LP + l]);
          const float val = acc[a][t][r] + uv * Dh;
          y[((size_t)(b0 + row) * H_ + h) * L + l] = gelu_f(val);
        }
      }
    }
  }
}

// ---------------------------------------------------------------------------
// Out-proj (64->128) + GLU + residual + LayerNorm(channel).
// ---------------------------------------------------------------------------
__global__ void k_out_glu_ln(const float* __restrict__ oW, const float* __restrict__ ob,
                             const float* __restrict__ lng, const float* __restrict__ lnb,
                             float* __restrict__ ybuf, float* xbuf, float* obuf, int Lcur) {
  __shared__ float Ws[2 * H_ * H_];
  __shared__ float obs[2 * H_];
  __shared__ float gs[H_], bs[H_];
  const int tid = threadIdx.x;
  for (int idx = tid; idx < 2 * H_ * H_; idx += 256) Ws[idx] = oW[idx];
  if (tid < 2 * H_) obs[tid] = ob[tid];
  if (tid < H_) { gs[tid] = lng[tid]; bs[tid] = lnb[tid]; }
  __syncthreads();
  const int p = blockIdx.x * 256 + tid;
  const int b = p / Lcur;
  const int l = p % Lcur;
  const size_t base = (size_t)b * H_ * Lcur + l;
  float yr[H_];
#pragma unroll
  for (int c = 0; c < H_; ++c) yr[c] = ybuf[base + (size_t)c * Lcur];
  float sum = 0.f, ss = 0.f;
  for (int c = 0; c < H_; ++c) {
    float a = obs[c], g = obs[c + H_];
    const float4* wa = (const float4*)(Ws + c * H_);
    const float4* wg = (const float4*)(Ws + (c + H_) * H_);
#pragma unroll
    for (int q = 0; q < 16; ++q) {
      const float4 va = wa[q], vg = wg[q];
      a += va.x * yr[4 * q] + va.y * yr[4 * q + 1] + va.z * yr[4 * q + 2] + va.w * yr[4 * q + 3];
      g += vg.x * yr[4 * q] + vg.y * yr[4 * q + 1] + vg.z * yr[4 * q + 2] + vg.w * yr[4 * q + 3];
    }
    const float z = a / (1.f + expf(-g));
    const float wv = z + xbuf[base + (size_t)c * Lcur];
    sum += wv;
    ss += wv * wv;
    ybuf[base + (size_t)c * Lcur] = wv;
  }
  const float mean = sum * (1.f / 64.f);
  const float var = ss * (1.f / 64.f) - mean * mean;
  const float rstd = rsqrtf(var + 1e-5f);
  for (int c = 0; c < H_; ++c) {
    const float wv = ybuf[base + (size_t)c * Lcur];
    obuf[base + (size_t)c * Lcur] = (wv - mean) * rstd * gs[c] + bs[c];
  }
}

template <int L>
constexpr size_t conv_smem_bytes() {
  return (size_t)(2 * 32 * (L + 8)) * 2 + (size_t)(L / 16) * 512 * 2 + (size_t)L * 4;
}

}  // namespace

// ---------------------------------------------------------------------------
extern "C" void kernel_launch(void* const* d_in, const int* in_sizes, int n_in,
                              void* d_out, int out_size, void* d_ws, size_t ws_size,
                              hipStream_t stream) {
  const float* x       = (const float*)d_in[0];
  const float* enc_W   = (const float*)d_in[1];
  const float* enc_b   = (const float*)d_in[2];
  const float* ln_g    = (const float*)d_in[3];
  const float* ln_b    = (const float*)d_in[4];
  const float* s4_D    = (const float*)d_in[5];
  const float* s4_ldt  = (const float*)d_in[6];
  const float* s4_C    = (const float*)d_in[7];
  const float* s4_logA = (const float*)d_in[8];
  const float* s4_Aim  = (const float*)d_in[9];
  const float* out_W   = (const float*)d_in[10];
  const float* out_b   = (const float*)d_in[11];
  const float* cd1_W   = (const float*)d_in[12];
  const float* cd1_b   = (const float*)d_in[13];
  const float* cd2_W   = (const float*)d_in[14];
  const float* cd2_b   = (const float*)d_in[15];
  const float* up_W    = (const float*)d_in[16];
  const float* up_b    = (const float*)d_in[17];
  const float* up1_W   = (const float*)d_in[18];
  float* outp = (float*)d_out;

  static_assert(conv_smem_bytes<L0_>() < 160 * 1024, "LDS overflow");
  hipFuncSetAttribute(reinterpret_cast<const void*>(&k_conv_gelu_mfma<L0_>),
                      hipFuncAttributeMaxDynamicSharedMemorySize,
                      (int)conv_smem_bytes<L0_>());
  hipFuncSetAttribute(reinterpret_cast<const void*>(&k_conv_gelu_mfma<L1_>),
                      hipFuncAttributeMaxDynamicSharedMemorySize,
                      (int)conv_smem_bytes<L1_>());
  hipFuncSetAttribute(reinterpret_cast<const void*>(&k_conv_gelu_mfma<L2_>),
                      hipFuncAttributeMaxDynamicSharedMemorySize,
                      (int)conv_smem_bytes<L2_>());

  // Workspace layout (floats); total ~112.2 MB
  float* ws   = (float*)d_ws;
  float* bufA = ws;                                   // B*H*L0
  float* bufB = bufA + (size_t)B_ * H_ * L0_;         // B*H*L0
  float* enc1 = bufB + (size_t)B_ * H_ * L0_;         // B*H*L1
  float* enc2 = enc1 + (size_t)B_ * H_ * L1_;         // B*H*L2
  float* Kb   = enc2 + (size_t)B_ * H_ * L2_;         // NL*H*(L2+L1+L0)

  const size_t koff0 = 0;
  const size_t koff1 = (size_t)NL_ * H_ * L2_;
  const size_t koff2 = koff1 + (size_t)NL_ * H_ * L1_;

  k_compute_K<<<NM_ * NL_ * H_, 256, 0, stream>>>(s4_ldt, s4_C, s4_logA, s4_Aim, Kb);
  k_conv_d1<<<(B_ * H_ * L1_) / 256, 256, 0, stream>>>(x, cd1_W, cd1_b, enc1);
  k_conv_d2<<<(B_ * H_ * L2_) / 256, 256, 0, stream>>>(enc1, cd2_W, cd2_b, enc2);

  auto run_model = [&](int m, const float* input, float* state, float* scratch,
                       int Lm, size_t koff, float* final_out) {
    const int BL = B_ * Lm;
    k_encoder<<<BL / 256, 256, 0, stream>>>(enc_W + (size_t)m * H_ * H_,
                                            enc_b + (size_t)m * H_, input, state, Lm);
    for (int i = 0; i < NL_; ++i) {
      const float* Kl = Kb + koff + (size_t)i * H_ * Lm;
      const float* Dl = s4_D + ((size_t)m * NL_ + i) * H_;
      if (Lm == L2_)
        k_conv_gelu_mfma<L2_><<<(B_ / 32) * H_, 256, conv_smem_bytes<L2_>(), stream>>>(
            state, Kl, Dl, scratch);
      else if (Lm == L1_)
        k_conv_gelu_mfma<L1_><<<(B_ / 32) * H_, 256, conv_smem_bytes<L1_>(), stream>>>(
            state, Kl, Dl, scratch);
      else
        k_conv_gelu_mfma<L0_><<<(B_ / 32) * H_, 256, conv_smem_bytes<L0_>(), stream>>>(
            state, Kl, Dl, scratch);
      float* obuf = (i == NL_ - 1 && final_out) ? final_out : state;
      k_out_glu_ln<<<BL / 256, 256, 0, stream>>>(
          out_W + ((size_t)m * NL_ + i) * 2 * H_ * H_,
          out_b + ((size_t)m * NL_ + i) * 2 * H_,
          ln_g + ((size_t)m * NL_ + i) * H_,
          ln_b + ((size_t)m * NL_ + i) * H_,
          scratch, state, obuf, Lm);
    }
  };

  // convT grid helper: waves advance 63 positions
  auto convt_blocks = [](int nPos) {
    const int nWaves = (nPos + 62) / 63;
    return (nWaves * 64 + 255) / 256;
  };

  // model 0 on enc2 (L=160)
  run_model(0, enc2, bufA, bufB, L2_, koff0, nullptr);
  // dec1 = enc2 + enc21
  k_add<<<(B_ * H_ * L2_) / 256, 256, 0, stream>>>(enc2, bufA);
  // dec21 = convT(dec1, up_W) + up_b + enc1  -> bufA
  k_convT<<<convt_blocks(B_ * L2_), 256, 0, stream>>>(enc2, up_W, up_b, enc1, bufA, L2_, 1,
                                                      B_ * L2_);
  // model 1 on dec21 (L=320), in place in bufA
  run_model(1, bufA, bufA, bufB, L1_, koff1, nullptr);
  // dec32 = convT(dec2, up1_W) + enc0  -> bufB
  k_convT<<<convt_blocks(B_ * L1_), 256, 0, stream>>>(bufA, up1_W, up_b, x, bufB, L1_, 0,
                                                      B_ * L1_);
  // model 2 on dec32 (L=640); final layer writes d_out
  run_model(2, bufB, bufB, bufA, L0_, koff2, outp);
}

// Round 4
// 4586.629 us; speedup vs baseline: 1.8612x; 1.1088x over previous
//
#include <hip/hip_runtime.h>
#include <math.h>

namespace {

constexpr int B_ = 256, H_ = 64, L0_ = 640, L1_ = 320, L2_ = 160;
constexpr int N2_ = 32, NL_ = 8, NM_ = 3;

typedef __attribute__((ext_vector_type(8))) short bf16x8;
typedef __attribute__((ext_vector_type(4))) float f32x4;

__device__ __forceinline__ unsigned short f2bf(float x) {
  unsigned int u = __float_as_uint(x);
  unsigned int r = (u + 0x7FFFu + ((u >> 16) & 1u)) >> 16;
  return (unsigned short)r;
}
__device__ __forceinline__ float bf2f(unsigned short h) {
  return __uint_as_float(((unsigned int)h) << 16);
}
__device__ __forceinline__ float gelu_f(float val) {
  const float t = 0.7978845608028654f * (val + 0.044715f * val * val * val);
  return 0.5f * val * (1.f + tanhf(t));
}

// ---------------------------------------------------------------------------
// K precompute: K[m,i,h,l] = 2*Re( sum_n Cc[n] * exp(dtA[n]*l) )
// ---------------------------------------------------------------------------
__global__ void k_compute_K(const float* __restrict__ log_dt,
                            const float* __restrict__ C,
                            const float* __restrict__ logA,
                            const float* __restrict__ Aim,
                            float* __restrict__ Kb) {
  const int bid = blockIdx.x;
  const int m = bid / (NL_ * H_);
  const int rest = bid % (NL_ * H_);
  const int li = rest / H_;
  const int h = rest % H_;
  const int ph = (m * NL_ + li) * H_ + h;
  __shared__ float sAr[N2_], sAi[N2_], sCr[N2_], sCi[N2_];
  const int tid = threadIdx.x;
  if (tid < N2_) {
    const int n = tid;
    const float dt = expf(log_dt[ph]);
    const float Are = -expf(logA[(size_t)ph * N2_ + n]);
    const float Ai = Aim[(size_t)ph * N2_ + n];
    const float ar = dt * Are, ai = dt * Ai;
    const float er = expf(ar);
    float sn, cs;
    sincosf(ai, &sn, &cs);
    const float mr = er * cs - 1.f;
    const float mi = er * sn;
    const float den = Are * Are + Ai * Ai;
    const float qr = (mr * Are + mi * Ai) / den;
    const float qi = (mi * Are - mr * Ai) / den;
    const float C0 = C[((size_t)ph * N2_ + n) * 2 + 0];
    const float C1 = C[((size_t)ph * N2_ + n) * 2 + 1];
    sCr[n] = C0 * qr - C1 * qi;
    sCi[n] = C0 * qi + C1 * qr;
    sAr[n] = ar;
    sAi[n] = ai;
  }
  __syncthreads();
  const int Lm = (m == 0) ? L2_ : (m == 1) ? L1_ : L0_;
  const size_t moff = (m == 0) ? 0
                    : (m == 1) ? (size_t)NL_ * H_ * L2_
                               : (size_t)NL_ * H_ * (L2_ + L1_);
  const size_t off = moff + (size_t)(li * H_ + h) * Lm;
  for (int l = tid; l < Lm; l += blockDim.x) {
    const float fl = (float)l;
    float acc = 0.f;
#pragma unroll
    for (int n = 0; n < N2_; ++n) {
      const float er = expf(sAr[n] * fl);
      float sn, cs;
      sincosf(sAi[n] * fl, &sn, &cs);
      acc += er * (sCr[n] * cs - sCi[n] * sn);
    }
    Kb[off + l] = 2.f * acc;
  }
}

// ---------------------------------------------------------------------------
// Strided down-conv (k=KW, s=2, pad=PAD): out[b,o,t] = bias[o] +
//   sum_i sum_k W[o,i,k] * x[b,i,2t-PAD+k]
// Block = (b, 32-output tile). x window + transposed weights staged in LDS.
// Thread = (o = tid&63, t-group tg = tid>>6 owning 8 outputs). x reads are
// wave-uniform (broadcast); weight reads stride-65 rows (conflict-free).
// ---------------------------------------------------------------------------
template <int KW, int PAD>
__global__ __launch_bounds__(256) void k_conv_down(
    const float* __restrict__ x, const float* __restrict__ W,
    const float* __restrict__ bias, float* __restrict__ out,
    int Lin, int Lout) {
  constexpr int TT = 32;                 // outputs per block
  constexpr int WCOLS = 2 * TT + KW - 2; // 65 (KW=3) or 64 (KW=2)
  constexpr int WROW = 68;               // padded x row stride (16B-aligned)
  __shared__ __align__(16) float xs[64][WROW];
  __shared__ float Wt[64 * KW * 65];     // [i*KW+k][o] row stride 65
  __shared__ float bsh[64];
  const int tid = threadIdx.x;

  const int tilesPerB = Lout / TT;
  const int b = blockIdx.x / tilesPerB;
  const int t0 = (blockIdx.x % tilesPerB) * TT;
  const int c0 = 2 * t0 - PAD;

  // stage weights: source-coalesced read, conflict-free LDS write
  for (int idx = tid; idx < 64 * 64 * KW; idx += 256) {
    const int o = idx / (64 * KW);
    const int rem = idx % (64 * KW);
    Wt[rem * 65 + o] = W[idx];
  }
  if (tid < 64) bsh[tid] = bias[tid];
  // stage x window (coalesced rows)
  for (int idx = tid; idx < 64 * WCOLS; idx += 256) {
    const int i = idx / WCOLS;
    const int c = idx % WCOLS;
    const int gc = c0 + c;
    xs[i][c] = (gc >= 0 && gc < Lin) ? x[((size_t)b * 64 + i) * Lin + gc] : 0.f;
  }
  __syncthreads();

  const int o = tid & 63;
  const int tg = tid >> 6;
  const int tb = tg * 8;  // local t base; local col for (t=tb+r,k) is 2*(tb+r)+k
  float acc[8];
#pragma unroll
  for (int r = 0; r < 8; ++r) acc[r] = bsh[o];

#pragma unroll 4
  for (int i = 0; i < 64; ++i) {
    const float4* xv = (const float4*)(&xs[i][2 * tb]);
    float xl[18];
    *(float4*)&xl[0] = xv[0];
    *(float4*)&xl[4] = xv[1];
    *(float4*)&xl[8] = xv[2];
    *(float4*)&xl[12] = xv[3];
    if (KW == 3) xl[16] = xs[i][2 * tb + 16];
    const float w0 = Wt[(i * KW + 0) * 65 + o];
    const float w1 = Wt[(i * KW + 1) * 65 + o];
    const float w2 = (KW == 3) ? Wt[(i * KW + 2) * 65 + o] : 0.f;
#pragma unroll
    for (int r = 0; r < 8; ++r) {
      float s = w0 * xl[2 * r] + w1 * xl[2 * r + 1];
      if (KW == 3) s += w2 * xl[2 * r + 2];
      acc[r] += s;
    }
  }
  // write out: thread covers t0+tb .. t0+tb+7 for channel o
  float* orow = out + ((size_t)b * 64 + o) * Lout + t0 + tb;
#pragma unroll
  for (int r = 0; r < 8; ++r) orow[r] = acc[r];
}

// ---------------------------------------------------------------------------
// ConvTranspose1d k=3 s=2 p=1 op=1, W layout (in,out,k). out = convT(in)+bias?+skip
// Thread owns ONE input column j; odd output's cross term via __shfl_down.
// ---------------------------------------------------------------------------
__global__ __launch_bounds__(256) void k_convT(
    const float* __restrict__ in_, const float* __restrict__ W,
    const float* __restrict__ bias, const float* __restrict__ skip,
    float* __restrict__ out, int Lin, int hasBias, int nPos) {
  __shared__ float Ws[3 * H_ * H_];  // [k][o][i]
  __shared__ float bsh[H_];
  const int tid = threadIdx.x;
  for (int idx = tid; idx < 3 * H_ * H_; idx += 256) {
    const int k = idx >> 12;
    const int rem = idx & 4095;
    const int o = rem >> 6;
    const int i = rem & 63;
    Ws[idx] = W[((size_t)i * H_ + o) * 3 + k];
  }
  if (tid < H_) bsh[tid] = hasBias ? bias[tid] : 0.f;
  __syncthreads();

  const int gw = (blockIdx.x * 256 + tid) >> 6;
  const int lane = tid & 63;
  const int bj = gw * 63 + lane;
  const bool valid = bj < nPos;
  const int bjc = valid ? bj : (nPos - 1);
  const int b = bjc / Lin;
  const int j = bjc % Lin;
  const bool lastcol = (j == Lin - 1);
  const int Lout = 2 * Lin;

  float xr[H_];
  const float* xcol = in_ + (size_t)b * H_ * Lin + j;
#pragma unroll
  for (int i = 0; i < H_; ++i) xr[i] = valid ? xcol[(size_t)i * Lin] : 0.f;

  const size_t obase = (size_t)b * H_ * Lout + 2 * j;
  for (int o = 0; o < H_; ++o) {
    const float4* w0 = (const float4*)(Ws + o * 64);
    const float4* w1 = (const float4*)(Ws + 4096 + o * 64);
    const float4* w2 = (const float4*)(Ws + 8192 + o * 64);
    float e = 0.f, c = 0.f, a = 0.f;
#pragma unroll
    for (int q = 0; q < 16; ++q) {
      const float4 v1 = w1[q], v2 = w2[q], v0 = w0[q];
      const float x0 = xr[4 * q], x1 = xr[4 * q + 1], x2 = xr[4 * q + 2], x3 = xr[4 * q + 3];
      e += v1.x * x0 + v1.y * x1 + v1.z * x2 + v1.w * x3;
      c += v2.x * x0 + v2.y * x1 + v2.z * x2 + v2.w * x3;
      a += v0.x * x0 + v0.y * x1 + v0.z * x2 + v0.w * x3;
    }
    const float an = __shfl_down(a, 1);
    if (valid) {
      const float bb = bsh[o];
      const size_t pe = obase + (size_t)o * Lout;
      out[pe] = e + bb + skip[pe];
      if (lane < 63) {
        const float oadd = lastcol ? 0.f : an;
        out[pe + 1] = c + oadd + bb + skip[pe + 1];
      }
    }
  }
}

// elementwise a += b
__global__ void k_add(float* a, const float* __restrict__ b) {
  const int p = blockIdx.x * 256 + threadIdx.x;
  a[p] += b[p];
}

// ---------------------------------------------------------------------------
// 1x1 encoder: out[b,o,l] = bias[o] + sum_i W[o,i]*in[b,i,l]  (in may == out)
// ---------------------------------------------------------------------------
__global__ void k_encoder(const float* __restrict__ W, const float* __restrict__ bvec,
                          const float* in_, float* out, int Lcur) {
  __shared__ float Ws[H_ * H_];
  __shared__ float bsh[H_];
  const int tid = threadIdx.x;
  for (int idx = tid; idx < H_ * H_; idx += 256) Ws[idx] = W[idx];
  if (tid < H_) bsh[tid] = bvec[tid];
  __syncthreads();
  const int p = blockIdx.x * 256 + tid;
  const int b = p / Lcur;
  const int l = p % Lcur;
  const size_t base = (size_t)b * H_ * Lcur + l;
  float xr[H_];
#pragma unroll
  for (int i = 0; i < H_; ++i) xr[i] = in_[base + (size_t)i * Lcur];
  for (int o = 0; o < H_; ++o) {
    float a = bsh[o];
    const float4* wr = (const float4*)(Ws + o * H_);
#pragma unroll
    for (int q = 0; q < 16; ++q) {
      const float4 v = wr[q];
      a += v.x * xr[4 * q] + v.y * xr[4 * q + 1] + v.z * xr[4 * q + 2] + v.w * xr[4 * q + 3];
    }
    out[base + (size_t)o * Lcur] = a;
  }
}

// ---------------------------------------------------------------------------
// MFMA causal conv + D-skip + gelu:  y = gelu(causal_conv(u,K) + u*D)
// ---------------------------------------------------------------------------
template <int L>
__global__ __launch_bounds__(256) void k_conv_gelu_mfma(
    const float* __restrict__ u, const float* __restrict__ Kl,
    const float* __restrict__ D, float* __restrict__ y) {
  constexpr int NT = L / 16;
  constexpr int NG = (NT + 3) / 4;
  constexpr int LP = L + 8;
  extern __shared__ char smem[];
  unsigned short* uhi = (unsigned short*)smem;          // [32][LP]
  unsigned short* ulo = uhi + 32 * LP;                  // [32][LP]
  unsigned short* Tt  = ulo + 32 * LP;                  // [NT][64][8]
  float* Ksh = (float*)(Tt + NT * 512);                 // [L]

  const int h = blockIdx.x & 63;
  const int b0 = (blockIdx.x >> 6) * 32;
  const int tid = threadIdx.x;

  constexpr int PR = L / 2;
  for (int wp = tid; wp < 32 * PR; wp += 256) {
    const int row = wp / PR, cp = wp % PR;
    const float2 v = *(const float2*)(u + ((size_t)(b0 + row) * H_ + h) * L + 2 * cp);
    const unsigned short h0 = f2bf(v.x), h1 = f2bf(v.y);
    const unsigned short q0 = f2bf(v.x - bf2f(h0)), q1 = f2bf(v.y - bf2f(h1));
    *(unsigned int*)&uhi[row * LP + 2 * cp] = (unsigned int)h0 | ((unsigned int)h1 << 16);
    *(unsigned int*)&ulo[row * LP + 2 * cp] = (unsigned int)q0 | ((unsigned int)q1 << 16);
  }
  const float* Krow = Kl + (size_t)h * L;
  for (int l = tid; l < L; l += 256) Ksh[l] = Krow[l];
  __syncthreads();
  for (int w = tid; w < NT * 256; w += 256) {
    const int nd = w >> 8;
    const int rem = w & 255;
    const int lane = rem >> 2;
    const int pp = rem & 3;
    const int base = nd * 16 + (lane & 15) - ((lane >> 4) << 3) - 2 * pp;
    const float f0 = (base >= 0) ? Ksh[base] : 0.f;
    const float f1 = (base - 1 >= 0) ? Ksh[base - 1] : 0.f;
    *(unsigned int*)&Tt[nd * 512 + lane * 8 + 2 * pp] =
        (unsigned int)f2bf(f0) | ((unsigned int)f2bf(f1) << 16);
  }
  __syncthreads();

  const int wv = tid >> 6;
  const int lane = tid & 63;
  const float Dh = D[h];
  const int lquad = lane & 15;
  const int lhi = lane >> 4;

  for (int g = wv; g < NG; g += 4) {
    const int t0 = g * 4;
    const int ntile = (NT - t0 < 4) ? (NT - t0) : 4;
    f32x4 acc[2][4];
#pragma unroll
    for (int a = 0; a < 2; ++a)
#pragma unroll
      for (int t = 0; t < 4; ++t) acc[a][t] = (f32x4){0.f, 0.f, 0.f, 0.f};
    const int lt_last = (t0 + ntile - 1) * 16;
    const int nsteps = lt_last / 32 + 1;
    for (int s = 0; s < nsteps; ++s) {
      const int j0 = 32 * s;
      const int colbase = j0 + (lhi << 3);
      bf16x8 ah0 = *(const bf16x8*)&uhi[(0 + lquad) * LP + colbase];
      bf16x8 al0 = *(const bf16x8*)&ulo[(0 + lquad) * LP + colbase];
      bf16x8 ah1 = *(const bf16x8*)&uhi[(16 + lquad) * LP + colbase];
      bf16x8 al1 = *(const bf16x8*)&ulo[(16 + lquad) * LP + colbase];
#pragma unroll
      for (int t = 0; t < 4; ++t) {
        if (t >= ntile) break;
        const int d0 = (t0 + t) * 16 - j0;
        if (d0 < 0) continue;
        const bf16x8 bf = *(const bf16x8*)&Tt[(d0 >> 4) * 512 + lane * 8];
        acc[0][t] = __builtin_amdgcn_mfma_f32_16x16x32_bf16(ah0, bf, acc[0][t], 0, 0, 0);
        acc[0][t] = __builtin_amdgcn_mfma_f32_16x16x32_bf16(al0, bf, acc[0][t], 0, 0, 0);
        acc[1][t] = __builtin_amdgcn_mfma_f32_16x16x32_bf16(ah1, bf, acc[1][t], 0, 0, 0);
        acc[1][t] = __builtin_amdgcn_mfma_f32_16x16x32_bf16(al1, bf, acc[1][t], 0, 0, 0);
      }
    }
#pragma unroll
    for (int t = 0; t < 4; ++t) {
      if (t >= ntile) break;
      const int l = (t0 + t) * 16 + lquad;
#pragma unroll
      for (int a = 0; a < 2; ++a) {
#pragma unroll
        for (int r = 0; r < 4; ++r) {
          const int row = a * 16 + (lhi << 2) + r;
          const float uv = bf2f(uhi[row * LP + l]) + bf2f(ulo[row * LP + l]);
          const float val = acc[a][t][r] + uv * Dh;
          y[((size_t)(b0 + row) * H_ + h) * L + l] = gelu_f(val);
        }
      }
    }
  }
}

// ---------------------------------------------------------------------------
// Out-proj (64->128) + GLU + residual + LayerNorm(channel).
// ---------------------------------------------------------------------------
__global__ void k_out_glu_ln(const float* __restrict__ oW, const float* __restrict__ ob,
                             const float* __restrict__ lng, const float* __restrict__ lnb,
                             float* __restrict__ ybuf, float* xbuf, float* obuf, int Lcur) {
  __shared__ float Ws[2 * H_ * H_];
  __shared__ float obs[2 * H_];
  __shared__ float gs[H_], bs[H_];
  const int tid = threadIdx.x;
  for (int idx = tid; idx < 2 * H_ * H_; idx += 256) Ws[idx] = oW[idx];
  if (tid < 2 * H_) obs[tid] = ob[tid];
  if (tid < H_) { gs[tid] = lng[tid]; bs[tid] = lnb[tid]; }
  __syncthreads();
  const int p = blockIdx.x * 256 + tid;
  const int b = p / Lcur;
  const int l = p % Lcur;
  const size_t base = (size_t)b * H_ * Lcur + l;
  float yr[H_];
#pragma unroll
  for (int c = 0; c < H_; ++c) yr[c] = ybuf[base + (size_t)c * Lcur];
  float sum = 0.f, ss = 0.f;
  for (int c = 0; c < H_; ++c) {
    float a = obs[c], g = obs[c + H_];
    const float4* wa = (const float4*)(Ws + c * H_);
    const float4* wg = (const float4*)(Ws + (c + H_) * H_);
#pragma unroll
    for (int q = 0; q < 16; ++q) {
      const float4 va = wa[q], vg = wg[q];
      a += va.x * yr[4 * q] + va.y * yr[4 * q + 1] + va.z * yr[4 * q + 2] + va.w * yr[4 * q + 3];
      g += vg.x * yr[4 * q] + vg.y * yr[4 * q + 1] + vg.z * yr[4 * q + 2] + vg.w * yr[4 * q + 3];
    }
    const float z = a / (1.f + expf(-g));
    const float wv = z + xbuf[base + (size_t)c * Lcur];
    sum += wv;
    ss += wv * wv;
    ybuf[base + (size_t)c * Lcur] = wv;
  }
  const float mean = sum * (1.f / 64.f);
  const float var = ss * (1.f / 64.f) - mean * mean;
  const float rstd = rsqrtf(var + 1e-5f);
  for (int c = 0; c < H_; ++c) {
    const float wv = ybuf[base + (size_t)c * Lcur];
    obuf[base + (size_t)c * Lcur] = (wv - mean) * rstd * gs[c] + bs[c];
  }
}

template <int L>
constexpr size_t conv_smem_bytes() {
  return (size_t)(2 * 32 * (L + 8)) * 2 + (size_t)(L / 16) * 512 * 2 + (size_t)L * 4;
}

}  // namespace

// ---------------------------------------------------------------------------
extern "C" void kernel_launch(void* const* d_in, const int* in_sizes, int n_in,
                              void* d_out, int out_size, void* d_ws, size_t ws_size,
                              hipStream_t stream) {
  const float* x       = (const float*)d_in[0];
  const float* enc_W   = (const float*)d_in[1];
  const float* enc_b   = (const float*)d_in[2];
  const float* ln_g    = (const float*)d_in[3];
  const float* ln_b    = (const float*)d_in[4];
  const float* s4_D    = (const float*)d_in[5];
  const float* s4_ldt  = (const float*)d_in[6];
  const float* s4_C    = (const float*)d_in[7];
  const float* s4_logA = (const float*)d_in[8];
  const float* s4_Aim  = (const float*)d_in[9];
  const float* out_W   = (const float*)d_in[10];
  const float* out_b   = (const float*)d_in[11];
  const float* cd1_W   = (const float*)d_in[12];
  const float* cd1_b   = (const float*)d_in[13];
  const float* cd2_W   = (const float*)d_in[14];
  const float* cd2_b   = (const float*)d_in[15];
  const float* up_W    = (const float*)d_in[16];
  const float* up_b    = (const float*)d_in[17];
  const float* up1_W   = (const float*)d_in[18];
  float* outp = (float*)d_out;

  static_assert(conv_smem_bytes<L0_>() < 160 * 1024, "LDS overflow");
  hipFuncSetAttribute(reinterpret_cast<const void*>(&k_conv_gelu_mfma<L0_>),
                      hipFuncAttributeMaxDynamicSharedMemorySize,
                      (int)conv_smem_bytes<L0_>());
  hipFuncSetAttribute(reinterpret_cast<const void*>(&k_conv_gelu_mfma<L1_>),
                      hipFuncAttributeMaxDynamicSharedMemorySize,
                      (int)conv_smem_bytes<L1_>());
  hipFuncSetAttribute(reinterpret_cast<const void*>(&k_conv_gelu_mfma<L2_>),
                      hipFuncAttributeMaxDynamicSharedMemorySize,
                      (int)conv_smem_bytes<L2_>());

  // Workspace layout (floats); total ~112.2 MB
  float* ws   = (float*)d_ws;
  float* bufA = ws;                                   // B*H*L0
  float* bufB = bufA + (size_t)B_ * H_ * L0_;         // B*H*L0
  float* enc1 = bufB + (size_t)B_ * H_ * L0_;         // B*H*L1
  float* enc2 = enc1 + (size_t)B_ * H_ * L1_;         // B*H*L2
  float* Kb   = enc2 + (size_t)B_ * H_ * L2_;         // NL*H*(L2+L1+L0)

  const size_t koff0 = 0;
  const size_t koff1 = (size_t)NL_ * H_ * L2_;
  const size_t koff2 = koff1 + (size_t)NL_ * H_ * L1_;

  k_compute_K<<<NM_ * NL_ * H_, 256, 0, stream>>>(s4_ldt, s4_C, s4_logA, s4_Aim, Kb);
  // enc1 = conv_d1(x): B * (L1/32) blocks
  k_conv_down<3, 1><<<B_ * (L1_ / 32), 256, 0, stream>>>(x, cd1_W, cd1_b, enc1, L0_, L1_);
  // enc2 = conv_d2(enc1): B * (L2/32) blocks
  k_conv_down<2, 0><<<B_ * (L2_ / 32), 256, 0, stream>>>(enc1, cd2_W, cd2_b, enc2, L1_, L2_);

  auto run_model = [&](int m, const float* input, float* state, float* scratch,
                       int Lm, size_t koff, float* final_out) {
    const int BL = B_ * Lm;
    k_encoder<<<BL / 256, 256, 0, stream>>>(enc_W + (size_t)m * H_ * H_,
                                            enc_b + (size_t)m * H_, input, state, Lm);
    for (int i = 0; i < NL_; ++i) {
      const float* Kl = Kb + koff + (size_t)i * H_ * Lm;
      const float* Dl = s4_D + ((size_t)m * NL_ + i) * H_;
      if (Lm == L2_)
        k_conv_gelu_mfma<L2_><<<(B_ / 32) * H_, 256, conv_smem_bytes<L2_>(), stream>>>(
            state, Kl, Dl, scratch);
      else if (Lm == L1_)
        k_conv_gelu_mfma<L1_><<<(B_ / 32) * H_, 256, conv_smem_bytes<L1_>(), stream>>>(
            state, Kl, Dl, scratch);
      else
        k_conv_gelu_mfma<L0_><<<(B_ / 32) * H_, 256, conv_smem_bytes<L0_>(), stream>>>(
            state, Kl, Dl, scratch);
      float* obuf = (i == NL_ - 1 && final_out) ? final_out : state;
      k_out_glu_ln<<<BL / 256, 256, 0, stream>>>(
          out_W + ((size_t)m * NL_ + i) * 2 * H_ * H_,
          out_b + ((size_t)m * NL_ + i) * 2 * H_,
          ln_g + ((size_t)m * NL_ + i) * H_,
          ln_b + ((size_t)m * NL_ + i) * H_,
          scratch, state, obuf, Lm);
    }
  };

  // convT grid helper: waves advance 63 positions
  auto convt_blocks = [](int nPos) {
    const int nWaves = (nPos + 62) / 63;
    return (nWaves * 64 + 255) / 256;
  };

  // model 0 on enc2 (L=160)
  run_model(0, enc2, bufA, bufB, L2_, koff0, nullptr);
  // dec1 = enc2 + enc21
  k_add<<<(B_ * H_ * L2_) / 256, 256, 0, stream>>>(enc2, bufA);
  // dec21 = convT(dec1, up_W) + up_b + enc1  -> bufA
  k_convT<<<convt_blocks(B_ * L2_), 256, 0, stream>>>(enc2, up_W, up_b, enc1, bufA, L2_, 1,
                                                      B_ * L2_);
  // model 1 on dec21 (L=320), in place in bufA
  run_model(1, bufA, bufA, bufB, L1_, koff1, nullptr);
  // dec32 = convT(dec2, up1_W) + enc0  -> bufB
  k_convT<<<convt_blocks(B_ * L1_), 256, 0, stream>>>(bufA, up1_W, up_b, x, bufB, L1_, 0,
                                                      B_ * L1_);
  // model 2 on dec32 (L=640); final layer writes d_out
  run_model(2, bufB, bufB, bufA, L0_, koff2, outp);
}

// Round 5
// 2410.276 us; speedup vs baseline: 3.5417x; 1.9029x over previous
//
#include <hip/hip_runtime.h>
#include <math.h>

namespace {

constexpr int B_ = 256, H_ = 64, L0_ = 640, L1_ = 320, L2_ = 160;
constexpr int N2_ = 32, NL_ = 8, NM_ = 3;

typedef __attribute__((ext_vector_type(8))) short bf16x8;
typedef __attribute__((ext_vector_type(4))) float f32x4;

__device__ __forceinline__ unsigned short f2bf(float x) {
  unsigned int u = __float_as_uint(x);
  unsigned int r = (u + 0x7FFFu + ((u >> 16) & 1u)) >> 16;
  return (unsigned short)r;
}
__device__ __forceinline__ float bf2f(unsigned short h) {
  return __uint_as_float(((unsigned int)h) << 16);
}
__device__ __forceinline__ float gelu_f(float val) {
  const float t = 0.7978845608028654f * (val + 0.044715f * val * val * val);
  return 0.5f * val * (1.f + tanhf(t));
}

// ---------------------------------------------------------------------------
// K precompute via complex binary powering (no transcendentals in hot loop):
// K[l] = 2*Re( sum_n Cc[n] * q[n]^l ),  q = exp(dtA).
// Thread n<32 computes q and q^(2^k) (k=0..8) by repeated squaring -> LDS.
// Each thread handles l = tid, tid+256, ...: init p=q^tid by bit decomposition,
// then p *= q^256 per step. grid = NM*NL*H blocks, 256 threads.
// ---------------------------------------------------------------------------
__global__ void k_compute_K(const float* __restrict__ log_dt,
                            const float* __restrict__ C,
                            const float* __restrict__ logA,
                            const float* __restrict__ Aim,
                            float* __restrict__ Kb) {
  const int bid = blockIdx.x;
  const int m = bid / (NL_ * H_);
  const int rest = bid % (NL_ * H_);
  const int li = rest / H_;
  const int h = rest % H_;
  const int ph = (m * NL_ + li) * H_ + h;
  __shared__ float qkr[9][N2_], qki[9][N2_];
  __shared__ float sCr[N2_], sCi[N2_];
  const int tid = threadIdx.x;
  if (tid < N2_) {
    const int n = tid;
    const float dt = expf(log_dt[ph]);
    const float Are = -expf(logA[(size_t)ph * N2_ + n]);
    const float Ai = Aim[(size_t)ph * N2_ + n];
    const float ar = dt * Are, ai = dt * Ai;
    const float er = expf(ar);
    float sn, cs;
    sincosf(ai, &sn, &cs);   // small args: |ai| < ~10, fast path
    const float mr = er * cs - 1.f;
    const float mi = er * sn;
    const float den = Are * Are + Ai * Ai;
    const float qr_ = (mr * Are + mi * Ai) / den;
    const float qi_ = (mi * Are - mr * Ai) / den;
    const float C0 = C[((size_t)ph * N2_ + n) * 2 + 0];
    const float C1 = C[((size_t)ph * N2_ + n) * 2 + 1];
    sCr[n] = C0 * qr_ - C1 * qi_;
    sCi[n] = C0 * qi_ + C1 * qr_;
    float qr = er * cs, qi = er * sn;  // q = exp(dtA)
#pragma unroll
    for (int k = 0; k < 9; ++k) {
      qkr[k][n] = qr;
      qki[k][n] = qi;
      const float nr = qr * qr - qi * qi;
      qi = 2.f * qr * qi;
      qr = nr;
    }
  }
  __syncthreads();
  const int Lm = (m == 0) ? L2_ : (m == 1) ? L1_ : L0_;
  const size_t moff = (m == 0) ? 0
                    : (m == 1) ? (size_t)NL_ * H_ * L2_
                               : (size_t)NL_ * H_ * (L2_ + L1_);
  const size_t off = moff + (size_t)(li * H_ + h) * Lm;

  float pr[N2_], pi[N2_];
#pragma unroll
  for (int n = 0; n < N2_; ++n) { pr[n] = 1.f; pi[n] = 0.f; }
#pragma unroll
  for (int k = 0; k < 8; ++k) {
    if ((tid >> k) & 1) {
#pragma unroll
      for (int n = 0; n < N2_; ++n) {
        const float qr = qkr[k][n], qi = qki[k][n];
        const float nr = pr[n] * qr - pi[n] * qi;
        pi[n] = pr[n] * qi + pi[n] * qr;
        pr[n] = nr;
      }
    }
  }
  for (int l = tid; l < Lm; l += 256) {
    float acc = 0.f;
#pragma unroll
    for (int n = 0; n < N2_; ++n) acc += sCr[n] * pr[n] - sCi[n] * pi[n];
    Kb[off + l] = 2.f * acc;
    if (l + 256 < Lm) {
#pragma unroll
      for (int n = 0; n < N2_; ++n) {
        const float qr = qkr[8][n], qi = qki[8][n];
        const float nr = pr[n] * qr - pi[n] * qi;
        pi[n] = pr[n] * qi + pi[n] * qr;
        pr[n] = nr;
      }
    }
  }
}

// ---------------------------------------------------------------------------
// Pack f32 weights into bf16 hi/lo pair arrays (identity indexing).
// ---------------------------------------------------------------------------
__global__ void k_pack_w(const float* __restrict__ W, unsigned short* __restrict__ hi,
                         unsigned short* __restrict__ lo, int n) {
  const int p = blockIdx.x * 256 + threadIdx.x;
  if (p < n) {
    const float w = W[p];
    const unsigned short h = f2bf(w);
    hi[p] = h;
    lo[p] = f2bf(w - bf2f(h));
  }
}

// ---------------------------------------------------------------------------
// Strided down-conv (k=KW, s=2, pad=PAD). Block = (b, 32-output tile).
// ---------------------------------------------------------------------------
template <int KW, int PAD>
__global__ __launch_bounds__(256) void k_conv_down(
    const float* __restrict__ x, const float* __restrict__ W,
    const float* __restrict__ bias, float* __restrict__ out,
    int Lin, int Lout) {
  constexpr int TT = 32;
  constexpr int WCOLS = 2 * TT + KW - 2;
  constexpr int WROW = 68;
  __shared__ __align__(16) float xs[64][WROW];
  __shared__ float Wt[64 * KW * 65];
  __shared__ float bsh[64];
  const int tid = threadIdx.x;

  const int tilesPerB = Lout / TT;
  const int b = blockIdx.x / tilesPerB;
  const int t0 = (blockIdx.x % tilesPerB) * TT;
  const int c0 = 2 * t0 - PAD;

  for (int idx = tid; idx < 64 * 64 * KW; idx += 256) {
    const int o = idx / (64 * KW);
    const int rem = idx % (64 * KW);
    Wt[rem * 65 + o] = W[idx];
  }
  if (tid < 64) bsh[tid] = bias[tid];
  for (int idx = tid; idx < 64 * WCOLS; idx += 256) {
    const int i = idx / WCOLS;
    const int c = idx % WCOLS;
    const int gc = c0 + c;
    xs[i][c] = (gc >= 0 && gc < Lin) ? x[((size_t)b * 64 + i) * Lin + gc] : 0.f;
  }
  __syncthreads();

  const int o = tid & 63;
  const int tg = tid >> 6;
  const int tb = tg * 8;
  float acc[8];
#pragma unroll
  for (int r = 0; r < 8; ++r) acc[r] = bsh[o];

#pragma unroll 4
  for (int i = 0; i < 64; ++i) {
    const float4* xv = (const float4*)(&xs[i][2 * tb]);
    float xl[18];
    *(float4*)&xl[0] = xv[0];
    *(float4*)&xl[4] = xv[1];
    *(float4*)&xl[8] = xv[2];
    *(float4*)&xl[12] = xv[3];
    if (KW == 3) xl[16] = xs[i][2 * tb + 16];
    const float w0 = Wt[(i * KW + 0) * 65 + o];
    const float w1 = Wt[(i * KW + 1) * 65 + o];
    const float w2 = (KW == 3) ? Wt[(i * KW + 2) * 65 + o] : 0.f;
#pragma unroll
    for (int r = 0; r < 8; ++r) {
      float s = w0 * xl[2 * r] + w1 * xl[2 * r + 1];
      if (KW == 3) s += w2 * xl[2 * r + 2];
      acc[r] += s;
    }
  }
  float* orow = out + ((size_t)b * 64 + o) * Lout + t0 + tb;
#pragma unroll
  for (int r = 0; r < 8; ++r) orow[r] = acc[r];
}

// ---------------------------------------------------------------------------
// ConvTranspose1d k=3 s=2 p=1 op=1; thread owns one input column j.
// ---------------------------------------------------------------------------
__global__ __launch_bounds__(256) void k_convT(
    const float* __restrict__ in_, const float* __restrict__ W,
    const float* __restrict__ bias, const float* __restrict__ skip,
    float* __restrict__ out, int Lin, int hasBias, int nPos) {
  __shared__ float Ws[3 * H_ * H_];
  __shared__ float bsh[H_];
  const int tid = threadIdx.x;
  for (int idx = tid; idx < 3 * H_ * H_; idx += 256) {
    const int k = idx >> 12;
    const int rem = idx & 4095;
    const int o = rem >> 6;
    const int i = rem & 63;
    Ws[idx] = W[((size_t)i * H_ + o) * 3 + k];
  }
  if (tid < H_) bsh[tid] = hasBias ? bias[tid] : 0.f;
  __syncthreads();

  const int gw = (blockIdx.x * 256 + tid) >> 6;
  const int lane = tid & 63;
  const int bj = gw * 63 + lane;
  const bool valid = bj < nPos;
  const int bjc = valid ? bj : (nPos - 1);
  const int b = bjc / Lin;
  const int j = bjc % Lin;
  const bool lastcol = (j == Lin - 1);
  const int Lout = 2 * Lin;

  float xr[H_];
  const float* xcol = in_ + (size_t)b * H_ * Lin + j;
#pragma unroll
  for (int i = 0; i < H_; ++i) xr[i] = valid ? xcol[(size_t)i * Lin] : 0.f;

  const size_t obase = (size_t)b * H_ * Lout + 2 * j;
  for (int o = 0; o < H_; ++o) {
    const float4* w0 = (const float4*)(Ws + o * 64);
    const float4* w1 = (const float4*)(Ws + 4096 + o * 64);
    const float4* w2 = (const float4*)(Ws + 8192 + o * 64);
    float e = 0.f, c = 0.f, a = 0.f;
#pragma unroll
    for (int q = 0; q < 16; ++q) {
      const float4 v1 = w1[q], v2 = w2[q], v0 = w0[q];
      const float x0 = xr[4 * q], x1 = xr[4 * q + 1], x2 = xr[4 * q + 2], x3 = xr[4 * q + 3];
      e += v1.x * x0 + v1.y * x1 + v1.z * x2 + v1.w * x3;
      c += v2.x * x0 + v2.y * x1 + v2.z * x2 + v2.w * x3;
      a += v0.x * x0 + v0.y * x1 + v0.z * x2 + v0.w * x3;
    }
    const float an = __shfl_down(a, 1);
    if (valid) {
      const float bb = bsh[o];
      const size_t pe = obase + (size_t)o * Lout;
      out[pe] = e + bb + skip[pe];
      if (lane < 63) {
        const float oadd = lastcol ? 0.f : an;
        out[pe + 1] = c + oadd + bb + skip[pe + 1];
      }
    }
  }
}

// elementwise a += b
__global__ void k_add(float* a, const float* __restrict__ b) {
  const int p = blockIdx.x * 256 + threadIdx.x;
  a[p] += b[p];
}

// ---------------------------------------------------------------------------
// 1x1 encoder: out[b,o,l] = bias[o] + sum_i W[o,i]*in[b,i,l]
// ---------------------------------------------------------------------------
__global__ void k_encoder(const float* __restrict__ W, const float* __restrict__ bvec,
                          const float* in_, float* out, int Lcur) {
  __shared__ float Ws[H_ * H_];
  __shared__ float bsh[H_];
  const int tid = threadIdx.x;
  for (int idx = tid; idx < H_ * H_; idx += 256) Ws[idx] = W[idx];
  if (tid < H_) bsh[tid] = bvec[tid];
  __syncthreads();
  const int p = blockIdx.x * 256 + tid;
  const int b = p / Lcur;
  const int l = p % Lcur;
  const size_t base = (size_t)b * H_ * Lcur + l;
  float xr[H_];
#pragma unroll
  for (int i = 0; i < H_; ++i) xr[i] = in_[base + (size_t)i * Lcur];
  for (int o = 0; o < H_; ++o) {
    float a = bsh[o];
    const float4* wr = (const float4*)(Ws + o * H_);
#pragma unroll
    for (int q = 0; q < 16; ++q) {
      const float4 v = wr[q];
      a += v.x * xr[4 * q] + v.y * xr[4 * q + 1] + v.z * xr[4 * q + 2] + v.w * xr[4 * q + 3];
    }
    out[base + (size_t)o * Lcur] = a;
  }
}

// ---------------------------------------------------------------------------
// MFMA causal conv + D-skip + gelu:  y = gelu(causal_conv(u,K) + u*D)
// ---------------------------------------------------------------------------
template <int L>
__global__ __launch_bounds__(256) void k_conv_gelu_mfma(
    const float* __restrict__ u, const float* __restrict__ Kl,
    const float* __restrict__ D, float* __restrict__ y) {
  constexpr int NT = L / 16;
  constexpr int NG = (NT + 3) / 4;
  constexpr int LP = L + 8;
  extern __shared__ char smem[];
  unsigned short* uhi = (unsigned short*)smem;          // [32][LP]
  unsigned short* ulo = uhi + 32 * LP;                  // [32][LP]
  unsigned short* Tt  = ulo + 32 * LP;                  // [NT][64][8]
  float* Ksh = (float*)(Tt + NT * 512);                 // [L]

  const int h = blockIdx.x & 63;
  const int b0 = (blockIdx.x >> 6) * 32;
  const int tid = threadIdx.x;

  constexpr int PR = L / 2;
  for (int wp = tid; wp < 32 * PR; wp += 256) {
    const int row = wp / PR, cp = wp % PR;
    const float2 v = *(const float2*)(u + ((size_t)(b0 + row) * H_ + h) * L + 2 * cp);
    const unsigned short h0 = f2bf(v.x), h1 = f2bf(v.y);
    const unsigned short q0 = f2bf(v.x - bf2f(h0)), q1 = f2bf(v.y - bf2f(h1));
    *(unsigned int*)&uhi[row * LP + 2 * cp] = (unsigned int)h0 | ((unsigned int)h1 << 16);
    *(unsigned int*)&ulo[row * LP + 2 * cp] = (unsigned int)q0 | ((unsigned int)q1 << 16);
  }
  const float* Krow = Kl + (size_t)h * L;
  for (int l = tid; l < L; l += 256) Ksh[l] = Krow[l];
  __syncthreads();
  for (int w = tid; w < NT * 256; w += 256) {
    const int nd = w >> 8;
    const int rem = w & 255;
    const int lane = rem >> 2;
    const int pp = rem & 3;
    const int base = nd * 16 + (lane & 15) - ((lane >> 4) << 3) - 2 * pp;
    const float f0 = (base >= 0) ? Ksh[base] : 0.f;
    const float f1 = (base - 1 >= 0) ? Ksh[base - 1] : 0.f;
    *(unsigned int*)&Tt[nd * 512 + lane * 8 + 2 * pp] =
        (unsigned int)f2bf(f0) | ((unsigned int)f2bf(f1) << 16);
  }
  __syncthreads();

  const int wv = tid >> 6;
  const int lane = tid & 63;
  const float Dh = D[h];
  const int lquad = lane & 15;
  const int lhi = lane >> 4;

  for (int g = wv; g < NG; g += 4) {
    const int t0 = g * 4;
    const int ntile = (NT - t0 < 4) ? (NT - t0) : 4;
    f32x4 acc[2][4];
#pragma unroll
    for (int a = 0; a < 2; ++a)
#pragma unroll
      for (int t = 0; t < 4; ++t) acc[a][t] = (f32x4){0.f, 0.f, 0.f, 0.f};
    const int lt_last = (t0 + ntile - 1) * 16;
    const int nsteps = lt_last / 32 + 1;
    for (int s = 0; s < nsteps; ++s) {
      const int j0 = 32 * s;
      const int colbase = j0 + (lhi << 3);
      bf16x8 ah0 = *(const bf16x8*)&uhi[(0 + lquad) * LP + colbase];
      bf16x8 al0 = *(const bf16x8*)&ulo[(0 + lquad) * LP + colbase];
      bf16x8 ah1 = *(const bf16x8*)&uhi[(16 + lquad) * LP + colbase];
      bf16x8 al1 = *(const bf16x8*)&ulo[(16 + lquad) * LP + colbase];
#pragma unroll
      for (int t = 0; t < 4; ++t) {
        if (t >= ntile) break;
        const int d0 = (t0 + t) * 16 - j0;
        if (d0 < 0) continue;
        const bf16x8 bf = *(const bf16x8*)&Tt[(d0 >> 4) * 512 + lane * 8];
        acc[0][t] = __builtin_amdgcn_mfma_f32_16x16x32_bf16(ah0, bf, acc[0][t], 0, 0, 0);
        acc[0][t] = __builtin_amdgcn_mfma_f32_16x16x32_bf16(al0, bf, acc[0][t], 0, 0, 0);
        acc[1][t] = __builtin_amdgcn_mfma_f32_16x16x32_bf16(ah1, bf, acc[1][t], 0, 0, 0);
        acc[1][t] = __builtin_amdgcn_mfma_f32_16x16x32_bf16(al1, bf, acc[1][t], 0, 0, 0);
      }
    }
#pragma unroll
    for (int t = 0; t < 4; ++t) {
      if (t >= ntile) break;
      const int l = (t0 + t) * 16 + lquad;
#pragma unroll
      for (int a = 0; a < 2; ++a) {
#pragma unroll
        for (int r = 0; r < 4; ++r) {
          const int row = a * 16 + (lhi << 2) + r;
          const float uv = bf2f(uhi[row * LP + l]) + bf2f(ulo[row * LP + l]);
          const float val = acc[a][t][r] + uv * Dh;
          y[((size_t)(b0 + row) * H_ + h) * L + l] = gelu_f(val);
        }
      }
    }
  }
}

// ---------------------------------------------------------------------------
// MFMA out-proj (64->128) + GLU + residual + LayerNorm(channel).
// Block = (b, 16-l tile), 4 waves. Wave w owns a-tile (rows 16w..16w+15) and
// g-tile (rows 64+16w..); N = 16 l. No GEMM LDS: W frags (pre-packed bf16
// hi/lo) and Y B-frags load direct from global; Y split hi/lo in-register.
// C/D map: col(l) = lane&15, row(c) = 16w + 4*(lane>>4) + r  [m89].
// In-place safe: thread reads x exactly where it later writes out.
// ---------------------------------------------------------------------------
__global__ __launch_bounds__(256) void k_glu_ln_mfma(
    const unsigned short* __restrict__ Whi, const unsigned short* __restrict__ Wlo,
    const float* __restrict__ ob, const float* __restrict__ lng,
    const float* __restrict__ lnb, const float* __restrict__ ybuf,
    const float* __restrict__ xbuf, float* __restrict__ obuf, int Lcur) {
  const int tid = threadIdx.x;
  const int w = tid >> 6;
  const int lane = tid & 63;
  const int c15 = lane & 15;
  const int g4 = lane >> 4;
  const int tilesPerB = Lcur >> 4;
  const int b = blockIdx.x / tilesPerB;
  const int l = ((blockIdx.x % tilesPerB) << 4) + c15;
  const size_t bbase = (size_t)b * H_ * Lcur;

  f32x4 accA = {0.f, 0.f, 0.f, 0.f}, accG = {0.f, 0.f, 0.f, 0.f};
#pragma unroll
  for (int k0 = 0; k0 < 64; k0 += 32) {
    const int crow = k0 + 8 * g4;
    float yv[8];
#pragma unroll
    for (int i = 0; i < 8; ++i)
      yv[i] = ybuf[bbase + (size_t)(crow + i) * Lcur + l];
    bf16x8 yhi, ylo;
#pragma unroll
    for (int i = 0; i < 8; ++i) {
      const unsigned short hh = f2bf(yv[i]);
      yhi[i] = (short)hh;
      ylo[i] = (short)f2bf(yv[i] - bf2f(hh));
    }
    const int ra = (16 * w + c15) * 64 + crow;        // a-rows
    const int rg = ((64 + 16 * w) + c15) * 64 + crow; // g-rows
    const bf16x8 wa_hi = *(const bf16x8*)(Whi + ra);
    const bf16x8 wa_lo = *(const bf16x8*)(Wlo + ra);
    const bf16x8 wg_hi = *(const bf16x8*)(Whi + rg);
    const bf16x8 wg_lo = *(const bf16x8*)(Wlo + rg);
    accA = __builtin_amdgcn_mfma_f32_16x16x32_bf16(wa_hi, yhi, accA, 0, 0, 0);
    accA = __builtin_amdgcn_mfma_f32_16x16x32_bf16(wa_hi, ylo, accA, 0, 0, 0);
    accA = __builtin_amdgcn_mfma_f32_16x16x32_bf16(wa_lo, yhi, accA, 0, 0, 0);
    accG = __builtin_amdgcn_mfma_f32_16x16x32_bf16(wg_hi, yhi, accG, 0, 0, 0);
    accG = __builtin_amdgcn_mfma_f32_16x16x32_bf16(wg_hi, ylo, accG, 0, 0, 0);
    accG = __builtin_amdgcn_mfma_f32_16x16x32_bf16(wg_lo, yhi, accG, 0, 0, 0);
  }

  __shared__ float red[4][16][2];
  float wv[4];
  float s1 = 0.f, s2 = 0.f;
#pragma unroll
  for (int r = 0; r < 4; ++r) {
    const int ca = 16 * w + 4 * g4 + r;
    const float a = accA[r] + ob[ca];
    const float g = accG[r] + ob[H_ + ca];
    const float z = a / (1.f + expf(-g));
    const float xv = xbuf[bbase + (size_t)ca * Lcur + l];
    wv[r] = z + xv;
    s1 += wv[r];
    s2 += wv[r] * wv[r];
  }
  s1 += __shfl_xor(s1, 16);
  s2 += __shfl_xor(s2, 16);
  s1 += __shfl_xor(s1, 32);
  s2 += __shfl_xor(s2, 32);
  if (g4 == 0) {
    red[w][c15][0] = s1;
    red[w][c15][1] = s2;
  }
  __syncthreads();
  float t1 = 0.f, t2 = 0.f;
#pragma unroll
  for (int q = 0; q < 4; ++q) {
    t1 += red[q][c15][0];
    t2 += red[q][c15][1];
  }
  const float mean = t1 * (1.f / 64.f);
  const float var = t2 * (1.f / 64.f) - mean * mean;
  const float rstd = rsqrtf(var + 1e-5f);
#pragma unroll
  for (int r = 0; r < 4; ++r) {
    const int ca = 16 * w + 4 * g4 + r;
    obuf[bbase + (size_t)ca * Lcur + l] = (wv[r] - mean) * rstd * lng[ca] + lnb[ca];
  }
}

template <int L>
constexpr size_t conv_smem_bytes() {
  return (size_t)(2 * 32 * (L + 8)) * 2 + (size_t)(L / 16) * 512 * 2 + (size_t)L * 4;
}

}  // namespace

// ---------------------------------------------------------------------------
extern "C" void kernel_launch(void* const* d_in, const int* in_sizes, int n_in,
                              void* d_out, int out_size, void* d_ws, size_t ws_size,
                              hipStream_t stream) {
  const float* x       = (const float*)d_in[0];
  const float* enc_W   = (const float*)d_in[1];
  const float* enc_b   = (const float*)d_in[2];
  const float* ln_g    = (const float*)d_in[3];
  const float* ln_b    = (const float*)d_in[4];
  const float* s4_D    = (const float*)d_in[5];
  const float* s4_ldt  = (const float*)d_in[6];
  const float* s4_C    = (const float*)d_in[7];
  const float* s4_logA = (const float*)d_in[8];
  const float* s4_Aim  = (const float*)d_in[9];
  const float* out_W   = (const float*)d_in[10];
  const float* out_b   = (const float*)d_in[11];
  const float* cd1_W   = (const float*)d_in[12];
  const float* cd1_b   = (const float*)d_in[13];
  const float* cd2_W   = (const float*)d_in[14];
  const float* cd2_b   = (const float*)d_in[15];
  const float* up_W    = (const float*)d_in[16];
  const float* up_b    = (const float*)d_in[17];
  const float* up1_W   = (const float*)d_in[18];
  float* outp = (float*)d_out;

  static_assert(conv_smem_bytes<L0_>() < 160 * 1024, "LDS overflow");
  hipFuncSetAttribute(reinterpret_cast<const void*>(&k_conv_gelu_mfma<L0_>),
                      hipFuncAttributeMaxDynamicSharedMemorySize,
                      (int)conv_smem_bytes<L0_>());
  hipFuncSetAttribute(reinterpret_cast<const void*>(&k_conv_gelu_mfma<L1_>),
                      hipFuncAttributeMaxDynamicSharedMemorySize,
                      (int)conv_smem_bytes<L1_>());
  hipFuncSetAttribute(reinterpret_cast<const void*>(&k_conv_gelu_mfma<L2_>),
                      hipFuncAttributeMaxDynamicSharedMemorySize,
                      (int)conv_smem_bytes<L2_>());

  // Workspace layout (floats); ~113 MB
  float* ws   = (float*)d_ws;
  float* bufA = ws;                                   // B*H*L0
  float* bufB = bufA + (size_t)B_ * H_ * L0_;         // B*H*L0
  float* enc1 = bufB + (size_t)B_ * H_ * L0_;         // B*H*L1
  float* enc2 = enc1 + (size_t)B_ * H_ * L1_;         // B*H*L2
  float* Kb   = enc2 + (size_t)B_ * H_ * L2_;         // NL*H*(L2+L1+L0)
  unsigned short* oWhi = (unsigned short*)(Kb + (size_t)NL_ * H_ * (L2_ + L1_ + L0_));
  unsigned short* oWlo = oWhi + (size_t)NM_ * NL_ * 2 * H_ * H_;

  const size_t koff0 = 0;
  const size_t koff1 = (size_t)NL_ * H_ * L2_;
  const size_t koff2 = koff1 + (size_t)NL_ * H_ * L1_;

  k_compute_K<<<NM_ * NL_ * H_, 256, 0, stream>>>(s4_ldt, s4_C, s4_logA, s4_Aim, Kb);
  const int nW = NM_ * NL_ * 2 * H_ * H_;
  k_pack_w<<<(nW + 255) / 256, 256, 0, stream>>>(out_W, oWhi, oWlo, nW);
  k_conv_down<3, 1><<<B_ * (L1_ / 32), 256, 0, stream>>>(x, cd1_W, cd1_b, enc1, L0_, L1_);
  k_conv_down<2, 0><<<B_ * (L2_ / 32), 256, 0, stream>>>(enc1, cd2_W, cd2_b, enc2, L1_, L2_);

  auto run_model = [&](int m, const float* input, float* state, float* scratch,
                       int Lm, size_t koff, float* final_out) {
    const int BL = B_ * Lm;
    k_encoder<<<BL / 256, 256, 0, stream>>>(enc_W + (size_t)m * H_ * H_,
                                            enc_b + (size_t)m * H_, input, state, Lm);
    for (int i = 0; i < NL_; ++i) {
      const float* Kl = Kb + koff + (size_t)i * H_ * Lm;
      const float* Dl = s4_D + ((size_t)m * NL_ + i) * H_;
      if (Lm == L2_)
        k_conv_gelu_mfma<L2_><<<(B_ / 32) * H_, 256, conv_smem_bytes<L2_>(), stream>>>(
            state, Kl, Dl, scratch);
      else if (Lm == L1_)
        k_conv_gelu_mfma<L1_><<<(B_ / 32) * H_, 256, conv_smem_bytes<L1_>(), stream>>>(
            state, Kl, Dl, scratch);
      else
        k_conv_gelu_mfma<L0_><<<(B_ / 32) * H_, 256, conv_smem_bytes<L0_>(), stream>>>(
            state, Kl, Dl, scratch);
      float* obuf = (i == NL_ - 1 && final_out) ? final_out : state;
      const size_t wbase = ((size_t)m * NL_ + i) * 2 * H_ * H_;
      k_glu_ln_mfma<<<B_ * (Lm / 16), 256, 0, stream>>>(
          oWhi + wbase, oWlo + wbase,
          out_b + ((size_t)m * NL_ + i) * 2 * H_,
          ln_g + ((size_t)m * NL_ + i) * H_,
          ln_b + ((size_t)m * NL_ + i) * H_,
          scratch, state, obuf, Lm);
    }
  };

  auto convt_blocks = [](int nPos) {
    const int nWaves = (nPos + 62) / 63;
    return (nWaves * 64 + 255) / 256;
  };

  // model 0 on enc2 (L=160)
  run_model(0, enc2, bufA, bufB, L2_, koff0, nullptr);
  // dec1 = enc2 + enc21
  k_add<<<(B_ * H_ * L2_) / 256, 256, 0, stream>>>(enc2, bufA);
  // dec21 = convT(dec1, up_W) + up_b + enc1  -> bufA
  k_convT<<<convt_blocks(B_ * L2_), 256, 0, stream>>>(enc2, up_W, up_b, enc1, bufA, L2_, 1,
                                                      B_ * L2_);
  // model 1 on dec21 (L=320), in place in bufA
  run_model(1, bufA, bufA, bufB, L1_, koff1, nullptr);
  // dec32 = convT(dec2, up1_W) + enc0  -> bufB
  k_convT<<<convt_blocks(B_ * L1_), 256, 0, stream>>>(bufA, up1_W, up_b, x, bufB, L1_, 0,
                                                      B_ * L1_);
  // model 2 on dec32 (L=640); final layer writes d_out
  run_model(2, bufB, bufB, bufA, L0_, koff2, outp);
}

// Round 7
// 2192.798 us; speedup vs baseline: 3.8929x; 1.0992x over previous
//
#include <hip/hip_runtime.h>
#include <math.h>

namespace {

constexpr int B_ = 256, H_ = 64, L0_ = 640, L1_ = 320, L2_ = 160;
constexpr int N2_ = 32, NL_ = 8, NM_ = 3;

typedef __attribute__((ext_vector_type(8))) short bf16x8;
typedef __attribute__((ext_vector_type(4))) float f32x4;

__device__ __forceinline__ unsigned short f2bf(float x) {
  unsigned int u = __float_as_uint(x);
  unsigned int r = (u + 0x7FFFu + ((u >> 16) & 1u)) >> 16;
  return (unsigned short)r;
}
__device__ __forceinline__ float bf2f(unsigned short h) {
  return __uint_as_float(((unsigned int)h) << 16);
}
__device__ __forceinline__ float gelu_f(float x) {
  // gelu(x) = x * sigmoid(2t); overflow-safe: exp(-2t) underflows (t>>0) or
  // overflows to +inf -> x/inf = 0 (t<<0). Never inf/inf.
  const float t = 0.7978845608028654f * (x + 0.044715f * x * x * x);
  return x / (1.f + __expf(-2.f * t));
}

// ---------------------------------------------------------------------------
// K + Toeplitz-fragment precompute. One block per (m, layer, h).
// K[l] = 2*Re( sum_n Cc[n] * q^l ) computed by complex binary powering into
// LDS; then Toeplitz MFMA B-fragments written to global TtG (bf16):
//   Tt[nd][lane][i] = K[nd*16 + (lane&15) - 8*(lane>>4) - i]   (0 if idx<0)
// ---------------------------------------------------------------------------
__global__ void k_compute_K_tt(const float* __restrict__ log_dt,
                               const float* __restrict__ C,
                               const float* __restrict__ logA,
                               const float* __restrict__ Aim,
                               unsigned short* __restrict__ TtG) {
  const int bid = blockIdx.x;
  const int m = bid / (NL_ * H_);
  const int rest = bid % (NL_ * H_);
  const int li = rest / H_;
  const int h = rest % H_;
  const int ph = (m * NL_ + li) * H_ + h;
  __shared__ float qkr[9][N2_], qki[9][N2_];
  __shared__ float sCr[N2_], sCi[N2_];
  __shared__ float Ksh[L0_];
  const int tid = threadIdx.x;
  if (tid < N2_) {
    const int n = tid;
    const float dt = expf(log_dt[ph]);
    const float Are = -expf(logA[(size_t)ph * N2_ + n]);
    const float Ai = Aim[(size_t)ph * N2_ + n];
    const float ar = dt * Are, ai = dt * Ai;
    const float er = expf(ar);
    float sn, cs;
    sincosf(ai, &sn, &cs);  // small args: fast path
    const float mr = er * cs - 1.f;
    const float mi = er * sn;
    const float den = Are * Are + Ai * Ai;
    const float qr_ = (mr * Are + mi * Ai) / den;
    const float qi_ = (mi * Are - mr * Ai) / den;
    const float C0 = C[((size_t)ph * N2_ + n) * 2 + 0];
    const float C1 = C[((size_t)ph * N2_ + n) * 2 + 1];
    sCr[n] = C0 * qr_ - C1 * qi_;
    sCi[n] = C0 * qi_ + C1 * qr_;
    float qr = er * cs, qi = er * sn;
#pragma unroll
    for (int k = 0; k < 9; ++k) {
      qkr[k][n] = qr;
      qki[k][n] = qi;
      const float nr = qr * qr - qi * qi;
      qi = 2.f * qr * qi;
      qr = nr;
    }
  }
  __syncthreads();
  const int Lm = (m == 0) ? L2_ : (m == 1) ? L1_ : L0_;
  const int NT = Lm / 16;

  float pr[N2_], pi[N2_];
#pragma unroll
  for (int n = 0; n < N2_; ++n) { pr[n] = 1.f; pi[n] = 0.f; }
#pragma unroll
  for (int k = 0; k < 8; ++k) {
    if ((tid >> k) & 1) {
#pragma unroll
      for (int n = 0; n < N2_; ++n) {
        const float qr = qkr[k][n], qi = qki[k][n];
        const float nr = pr[n] * qr - pi[n] * qi;
        pi[n] = pr[n] * qi + pi[n] * qr;
        pr[n] = nr;
      }
    }
  }
  for (int l = tid; l < Lm; l += 256) {
    float acc = 0.f;
#pragma unroll
    for (int n = 0; n < N2_; ++n) acc += sCr[n] * pr[n] - sCi[n] * pi[n];
    Ksh[l] = 2.f * acc;
    if (l + 256 < Lm) {
#pragma unroll
      for (int n = 0; n < N2_; ++n) {
        const float qr = qkr[8][n], qi = qki[8][n];
        const float nr = pr[n] * qr - pi[n] * qi;
        pi[n] = pr[n] * qi + pi[n] * qr;
        pr[n] = nr;
      }
    }
  }
  __syncthreads();
  // Toeplitz fragment build -> global (bf16)
  const size_t base_tiles = ((m == 0) ? 0 : (m == 1) ? (size_t)64 * NL_ * 10
                                                     : (size_t)64 * NL_ * 30) +
                            (size_t)li * 64 * NT + (size_t)h * NT;
  unsigned short* Tg = TtG + base_tiles * 512;
  for (int w = tid; w < NT * 256; w += 256) {
    const int nd = w >> 8;
    const int rem = w & 255;
    const int lane = rem >> 2;
    const int pp = rem & 3;
    const int base = nd * 16 + (lane & 15) - ((lane >> 4) << 3) - 2 * pp;
    const float f0 = (base >= 0) ? Ksh[base] : 0.f;
    const float f1 = (base - 1 >= 0) ? Ksh[base - 1] : 0.f;
    *(unsigned int*)&Tg[nd * 512 + lane * 8 + 2 * pp] =
        (unsigned int)f2bf(f0) | ((unsigned int)f2bf(f1) << 16);
  }
}

// ---------------------------------------------------------------------------
// Pack f32 weights into bf16 hi/lo pair arrays (identity indexing).
// ---------------------------------------------------------------------------
__global__ void k_pack_w(const float* __restrict__ W, unsigned short* __restrict__ hi,
                         unsigned short* __restrict__ lo, int n) {
  const int p = blockIdx.x * 256 + threadIdx.x;
  if (p < n) {
    const float w = W[p];
    const unsigned short h = f2bf(w);
    hi[p] = h;
    lo[p] = f2bf(w - bf2f(h));
  }
}

// ---------------------------------------------------------------------------
// Strided down-conv (k=KW, s=2, pad=PAD). Block = (b, 32-output tile).
// ---------------------------------------------------------------------------
template <int KW, int PAD>
__global__ __launch_bounds__(256) void k_conv_down(
    const float* __restrict__ x, const float* __restrict__ W,
    const float* __restrict__ bias, float* __restrict__ out,
    int Lin, int Lout) {
  constexpr int TT = 32;
  constexpr int WCOLS = 2 * TT + KW - 2;
  constexpr int WROW = 68;
  __shared__ __align__(16) float xs[64][WROW];
  __shared__ float Wt[64 * KW * 65];
  __shared__ float bsh[64];
  const int tid = threadIdx.x;

  const int tilesPerB = Lout / TT;
  const int b = blockIdx.x / tilesPerB;
  const int t0 = (blockIdx.x % tilesPerB) * TT;
  const int c0 = 2 * t0 - PAD;

  for (int idx = tid; idx < 64 * 64 * KW; idx += 256) {
    const int o = idx / (64 * KW);
    const int rem = idx % (64 * KW);
    Wt[rem * 65 + o] = W[idx];
  }
  if (tid < 64) bsh[tid] = bias[tid];
  for (int idx = tid; idx < 64 * WCOLS; idx += 256) {
    const int i = idx / WCOLS;
    const int c = idx % WCOLS;
    const int gc = c0 + c;
    xs[i][c] = (gc >= 0 && gc < Lin) ? x[((size_t)b * 64 + i) * Lin + gc] : 0.f;
  }
  __syncthreads();

  const int o = tid & 63;
  const int tg = tid >> 6;
  const int tb = tg * 8;
  float acc[8];
#pragma unroll
  for (int r = 0; r < 8; ++r) acc[r] = bsh[o];

#pragma unroll 4
  for (int i = 0; i < 64; ++i) {
    const float4* xv = (const float4*)(&xs[i][2 * tb]);
    float xl[18];
    *(float4*)&xl[0] = xv[0];
    *(float4*)&xl[4] = xv[1];
    *(float4*)&xl[8] = xv[2];
    *(float4*)&xl[12] = xv[3];
    if (KW == 3) xl[16] = xs[i][2 * tb + 16];
    const float w0 = Wt[(i * KW + 0) * 65 + o];
    const float w1 = Wt[(i * KW + 1) * 65 + o];
    const float w2 = (KW == 3) ? Wt[(i * KW + 2) * 65 + o] : 0.f;
#pragma unroll
    for (int r = 0; r < 8; ++r) {
      float s = w0 * xl[2 * r] + w1 * xl[2 * r + 1];
      if (KW == 3) s += w2 * xl[2 * r + 2];
      acc[r] += s;
    }
  }
  float* orow = out + ((size_t)b * 64 + o) * Lout + t0 + tb;
#pragma unroll
  for (int r = 0; r < 8; ++r) orow[r] = acc[r];
}

// ---------------------------------------------------------------------------
// ConvTranspose1d k=3 s=2 p=1 op=1; thread owns one input column j.
// ---------------------------------------------------------------------------
__global__ __launch_bounds__(256) void k_convT(
    const float* __restrict__ in_, const float* __restrict__ W,
    const float* __restrict__ bias, const float* __restrict__ skip,
    float* __restrict__ out, int Lin, int hasBias, int nPos) {
  __shared__ float Ws[3 * H_ * H_];
  __shared__ float bsh[H_];
  const int tid = threadIdx.x;
  for (int idx = tid; idx < 3 * H_ * H_; idx += 256) {
    const int k = idx >> 12;
    const int rem = idx & 4095;
    const int o = rem >> 6;
    const int i = rem & 63;
    Ws[idx] = W[((size_t)i * H_ + o) * 3 + k];
  }
  if (tid < H_) bsh[tid] = hasBias ? bias[tid] : 0.f;
  __syncthreads();

  const int gw = (blockIdx.x * 256 + tid) >> 6;
  const int lane = tid & 63;
  const int bj = gw * 63 + lane;
  const bool valid = bj < nPos;
  const int bjc = valid ? bj : (nPos - 1);
  const int b = bjc / Lin;
  const int j = bjc % Lin;
  const bool lastcol = (j == Lin - 1);
  const int Lout = 2 * Lin;

  float xr[H_];
  const float* xcol = in_ + (size_t)b * H_ * Lin + j;
#pragma unroll
  for (int i = 0; i < H_; ++i) xr[i] = valid ? xcol[(size_t)i * Lin] : 0.f;

  const size_t obase = (size_t)b * H_ * Lout + 2 * j;
  for (int o = 0; o < H_; ++o) {
    const float4* w0 = (const float4*)(Ws + o * 64);
    const float4* w1 = (const float4*)(Ws + 4096 + o * 64);
    const float4* w2 = (const float4*)(Ws + 8192 + o * 64);
    float e = 0.f, c = 0.f, a = 0.f;
#pragma unroll
    for (int q = 0; q < 16; ++q) {
      const float4 v1 = w1[q], v2 = w2[q], v0 = w0[q];
      const float x0 = xr[4 * q], x1 = xr[4 * q + 1], x2 = xr[4 * q + 2], x3 = xr[4 * q + 3];
      e += v1.x * x0 + v1.y * x1 + v1.z * x2 + v1.w * x3;
      c += v2.x * x0 + v2.y * x1 + v2.z * x2 + v2.w * x3;
      a += v0.x * x0 + v0.y * x1 + v0.z * x2 + v0.w * x3;
    }
    const float an = __shfl_down(a, 1);
    if (valid) {
      const float bb = bsh[o];
      const size_t pe = obase + (size_t)o * Lout;
      out[pe] = e + bb + skip[pe];
      if (lane < 63) {
        const float oadd = lastcol ? 0.f : an;
        out[pe + 1] = c + oadd + bb + skip[pe + 1];
      }
    }
  }
}

// elementwise a += b
__global__ void k_add(float* a, const float* __restrict__ b) {
  const int p = blockIdx.x * 256 + threadIdx.x;
  a[p] += b[p];
}

// ---------------------------------------------------------------------------
// 1x1 encoder: out[b,o,l] = bias[o] + sum_i W[o,i]*in[b,i,l]  (in-place safe)
// ---------------------------------------------------------------------------
__global__ void k_encoder(const float* __restrict__ W, const float* __restrict__ bvec,
                          const float* in_, float* out, int Lcur) {
  __shared__ float Ws[H_ * H_];
  __shared__ float bsh[H_];
  const int tid = threadIdx.x;
  for (int idx = tid; idx < H_ * H_; idx += 256) Ws[idx] = W[idx];
  if (tid < H_) bsh[tid] = bvec[tid];
  __syncthreads();
  const int p = blockIdx.x * 256 + tid;
  const int b = p / Lcur;
  const int l = p % Lcur;
  const size_t base = (size_t)b * H_ * Lcur + l;
  float xr[H_];
#pragma unroll
  for (int i = 0; i < H_; ++i) xr[i] = in_[base + (size_t)i * Lcur];
  for (int o = 0; o < H_; ++o) {
    float a = bsh[o];
    const float4* wr = (const float4*)(Ws + o * H_);
#pragma unroll
    for (int q = 0; q < 16; ++q) {
      const float4 v = wr[q];
      a += v.x * xr[4 * q] + v.y * xr[4 * q + 1] + v.z * xr[4 * q + 2] + v.w * xr[4 * q + 3];
    }
    out[base + (size_t)o * Lcur] = a;
  }
}

// ---------------------------------------------------------------------------
// MFMA causal conv + D-skip + gelu:  y = gelu(causal_conv(u,K) + u*D)
// Block = (16 batches, one h); u hi/lo bf16 in LDS (41.5KB @L0 -> 3 blk/CU).
// Toeplitz B-frags read from global TtG (prebuilt, L2-hot, coalesced 1KB).
// ---------------------------------------------------------------------------
template <int L>
__global__ __launch_bounds__(256) void k_conv_gelu_mfma(
    const float* __restrict__ u, const unsigned short* __restrict__ Tt,
    const float* __restrict__ D, float* __restrict__ y) {
  constexpr int NT = L / 16;
  constexpr int NG = (NT + 3) / 4;
  constexpr int LP = L + 8;
  __shared__ unsigned short uhi[16 * LP];
  __shared__ unsigned short ulo[16 * LP];

  const int h = blockIdx.x & 63;
  const int b0 = (blockIdx.x >> 6) * 16;
  const int tid = threadIdx.x;

  constexpr int PR = L / 2;
  for (int wp = tid; wp < 16 * PR; wp += 256) {
    const int row = wp / PR, cp = wp % PR;
    const float2 v = *(const float2*)(u + ((size_t)(b0 + row) * H_ + h) * L + 2 * cp);
    const unsigned short h0 = f2bf(v.x), h1 = f2bf(v.y);
    const unsigned short q0 = f2bf(v.x - bf2f(h0)), q1 = f2bf(v.y - bf2f(h1));
    *(unsigned int*)&uhi[row * LP + 2 * cp] = (unsigned int)h0 | ((unsigned int)h1 << 16);
    *(unsigned int*)&ulo[row * LP + 2 * cp] = (unsigned int)q0 | ((unsigned int)q1 << 16);
  }
  __syncthreads();

  const int wv = tid >> 6;
  const int lane = tid & 63;
  const float Dh = D[h];
  const int lquad = lane & 15;
  const int lhi = lane >> 4;
  const unsigned short* Th = Tt + (size_t)h * NT * 512 + lane * 8;

  for (int g = wv; g < NG; g += 4) {
    const int t0 = g * 4;
    const int ntile = (NT - t0 < 4) ? (NT - t0) : 4;
    f32x4 acc[4];
#pragma unroll
    for (int t = 0; t < 4; ++t) acc[t] = (f32x4){0.f, 0.f, 0.f, 0.f};
    const int nsteps = ((t0 + ntile - 1) * 16) / 32 + 1;
    for (int s = 0; s < nsteps; ++s) {
      const int j0 = 32 * s;
      const int colbase = j0 + (lhi << 3);
      const bf16x8 ah = *(const bf16x8*)&uhi[lquad * LP + colbase];
      const bf16x8 al = *(const bf16x8*)&ulo[lquad * LP + colbase];
#pragma unroll
      for (int t = 0; t < 4; ++t) {
        if (t >= ntile) break;
        const int d0 = (t0 + t) * 16 - j0;
        if (d0 < 0) continue;  // causal: wave-uniform skip
        const bf16x8 bf = *(const bf16x8*)(Th + (size_t)(d0 >> 4) * 512);
        acc[t] = __builtin_amdgcn_mfma_f32_16x16x32_bf16(ah, bf, acc[t], 0, 0, 0);
        acc[t] = __builtin_amdgcn_mfma_f32_16x16x32_bf16(al, bf, acc[t], 0, 0, 0);
      }
    }
#pragma unroll
    for (int t = 0; t < 4; ++t) {
      if (t >= ntile) break;
      const int l = (t0 + t) * 16 + lquad;
#pragma unroll
      for (int r = 0; r < 4; ++r) {
        const int row = (lhi << 2) + r;
        const float uv = bf2f(uhi[row * LP + l]) + bf2f(ulo[row * LP + l]);
        const float val = acc[t][r] + uv * Dh;
        y[((size_t)(b0 + row) * H_ + h) * L + l] = gelu_f(val);
      }
    }
  }
}

// ---------------------------------------------------------------------------
// MFMA out-proj (64->128) + GLU + residual + LayerNorm(channel).
// ---------------------------------------------------------------------------
__global__ __launch_bounds__(256) void k_glu_ln_mfma(
    const unsigned short* __restrict__ Whi, const unsigned short* __restrict__ Wlo,
    const float* __restrict__ ob, const float* __restrict__ lng,
    const float* __restrict__ lnb, const float* __restrict__ ybuf,
    const float* __restrict__ xbuf, float* __restrict__ obuf, int Lcur) {
  const int tid = threadIdx.x;
  const int w = tid >> 6;
  const int lane = tid & 63;
  const int c15 = lane & 15;
  const int g4 = lane >> 4;
  const int tilesPerB = Lcur >> 4;
  const int b = blockIdx.x / tilesPerB;
  const int l = ((blockIdx.x % tilesPerB) << 4) + c15;
  const size_t bbase = (size_t)b * H_ * Lcur;

  f32x4 accA = {0.f, 0.f, 0.f, 0.f}, accG = {0.f, 0.f, 0.f, 0.f};
#pragma unroll
  for (int k0 = 0; k0 < 64; k0 += 32) {
    const int crow = k0 + 8 * g4;
    float yv[8];
#pragma unroll
    for (int i = 0; i < 8; ++i)
      yv[i] = ybuf[bbase + (size_t)(crow + i) * Lcur + l];
    bf16x8 yhi, ylo;
#pragma unroll
    for (int i = 0; i < 8; ++i) {
      const unsigned short hh = f2bf(yv[i]);
      yhi[i] = (short)hh;
      ylo[i] = (short)f2bf(yv[i] - bf2f(hh));
    }
    const int ra = (16 * w + c15) * 64 + crow;
    const int rg = ((64 + 16 * w) + c15) * 64 + crow;
    const bf16x8 wa_hi = *(const bf16x8*)(Whi + ra);
    const bf16x8 wa_lo = *(const bf16x8*)(Wlo + ra);
    const bf16x8 wg_hi = *(const bf16x8*)(Whi + rg);
    const bf16x8 wg_lo = *(const bf16x8*)(Wlo + rg);
    accA = __builtin_amdgcn_mfma_f32_16x16x32_bf16(wa_hi, yhi, accA, 0, 0, 0);
    accA = __builtin_amdgcn_mfma_f32_16x16x32_bf16(wa_hi, ylo, accA, 0, 0, 0);
    accA = __builtin_amdgcn_mfma_f32_16x16x32_bf16(wa_lo, yhi, accA, 0, 0, 0);
    accG = __builtin_amdgcn_mfma_f32_16x16x32_bf16(wg_hi, yhi, accG, 0, 0, 0);
    accG = __builtin_amdgcn_mfma_f32_16x16x32_bf16(wg_hi, ylo, accG, 0, 0, 0);
    accG = __builtin_amdgcn_mfma_f32_16x16x32_bf16(wg_lo, yhi, accG, 0, 0, 0);
  }

  __shared__ float red[4][16][2];
  float wv[4];
  float s1 = 0.f, s2 = 0.f;
#pragma unroll
  for (int r = 0; r < 4; ++r) {
    const int ca = 16 * w + 4 * g4 + r;
    const float a = accA[r] + ob[ca];
    const float g = accG[r] + ob[H_ + ca];
    const float z = a / (1.f + expf(-g));
    const float xv = xbuf[bbase + (size_t)ca * Lcur + l];
    wv[r] = z + xv;
    s1 += wv[r];
    s2 += wv[r] * wv[r];
  }
  s1 += __shfl_xor(s1, 16);
  s2 += __shfl_xor(s2, 16);
  s1 += __shfl_xor(s1, 32);
  s2 += __shfl_xor(s2, 32);
  if (g4 == 0) {
    red[w][c15][0] = s1;
    red[w][c15][1] = s2;
  }
  __syncthreads();
  float t1 = 0.f, t2 = 0.f;
#pragma unroll
  for (int q = 0; q < 4; ++q) {
    t1 += red[q][c15][0];
    t2 += red[q][c15][1];
  }
  const float mean = t1 * (1.f / 64.f);
  const float var = t2 * (1.f / 64.f) - mean * mean;
  const float rstd = rsqrtf(var + 1e-5f);
#pragma unroll
  for (int r = 0; r < 4; ++r) {
    const int ca = 16 * w + 4 * g4 + r;
    obuf[bbase + (size_t)ca * Lcur + l] = (wv[r] - mean) * rstd * lng[ca] + lnb[ca];
  }
}

}  // namespace

// ---------------------------------------------------------------------------
extern "C" void kernel_launch(void* const* d_in, const int* in_sizes, int n_in,
                              void* d_out, int out_size, void* d_ws, size_t ws_size,
                              hipStream_t stream) {
  const float* x       = (const float*)d_in[0];
  const float* enc_W   = (const float*)d_in[1];
  const float* enc_b   = (const float*)d_in[2];
  const float* ln_g    = (const float*)d_in[3];
  const float* ln_b    = (const float*)d_in[4];
  const float* s4_D    = (const float*)d_in[5];
  const float* s4_ldt  = (const float*)d_in[6];
  const float* s4_C    = (const float*)d_in[7];
  const float* s4_logA = (const float*)d_in[8];
  const float* s4_Aim  = (const float*)d_in[9];
  const float* out_W   = (const float*)d_in[10];
  const float* out_b   = (const float*)d_in[11];
  const float* cd1_W   = (const float*)d_in[12];
  const float* cd1_b   = (const float*)d_in[13];
  const float* cd2_W   = (const float*)d_in[14];
  const float* cd2_b   = (const float*)d_in[15];
  const float* up_W    = (const float*)d_in[16];
  const float* up_b    = (const float*)d_in[17];
  const float* up1_W   = (const float*)d_in[18];
  float* outp = (float*)d_out;

  // ---- workspace arena (~121.4 MB total, lifetime-overlapped) ----
  // TtG: all-layer Toeplitz frags: 64h * 512sh * 8L * (10+20+40)NT = 18.35M shorts
  unsigned short* TtG = (unsigned short*)d_ws;
  const size_t ttg_shorts = (size_t)64 * NL_ * 70 * 512;
  unsigned short* oWhi = TtG + ttg_shorts;
  const size_t nWsz = (size_t)NM_ * NL_ * 2 * H_ * H_;
  unsigned short* oWlo = oWhi + nWsz;
  float* slotA = (float*)(oWlo + nWsz);                 // B*H*L0 floats
  float* slotB = slotA + (size_t)B_ * H_ * L0_;         // B*H*L0 floats

  // lifetime map (stream-serial):
  float* enc1   = slotA;                                // B*H*L1
  float* enc2   = slotA + (size_t)B_ * H_ * L1_;        // B*H*L2
  float* m0st   = slotB;                                // B*H*L2
  float* m0scr  = slotB + (size_t)B_ * H_ * L2_;        // B*H*L2
  float* dec21  = slotB;                                // B*H*L1 (m0st/m0scr dead)
  float* scr1   = slotA;                                // B*H*L1 (enc1/enc2 dead)
  float* dec32  = slotA;                                // B*H*L0
  float* scr2   = slotB;                                // B*H*L0 (dec2 consumed)

  auto tt_layer = [&](int m, int i) -> const unsigned short* {
    const size_t NTm = (m == 0) ? 10 : (m == 1) ? 20 : 40;
    const size_t base = (m == 0) ? 0 : (m == 1) ? (size_t)64 * NL_ * 10
                                                : (size_t)64 * NL_ * 30;
    return TtG + (base + (size_t)i * 64 * NTm) * 512;
  };

  k_compute_K_tt<<<NM_ * NL_ * H_, 256, 0, stream>>>(s4_ldt, s4_C, s4_logA, s4_Aim, TtG);
  k_pack_w<<<((int)nWsz + 255) / 256, 256, 0, stream>>>(out_W, oWhi, oWlo, (int)nWsz);
  k_conv_down<3, 1><<<B_ * (L1_ / 32), 256, 0, stream>>>(x, cd1_W, cd1_b, enc1, L0_, L1_);
  k_conv_down<2, 0><<<B_ * (L2_ / 32), 256, 0, stream>>>(enc1, cd2_W, cd2_b, enc2, L1_, L2_);

  auto run_model = [&](int m, const float* input, float* state, float* scratch,
                       int Lm, float* final_out) {
    const int BL = B_ * Lm;
    k_encoder<<<BL / 256, 256, 0, stream>>>(enc_W + (size_t)m * H_ * H_,
                                            enc_b + (size_t)m * H_, input, state, Lm);
    for (int i = 0; i < NL_; ++i) {
      const unsigned short* Tl = tt_layer(m, i);
      const float* Dl = s4_D + ((size_t)m * NL_ + i) * H_;
      const int cgrid = (B_ / 16) * H_;
      if (Lm == L2_)
        k_conv_gelu_mfma<L2_><<<cgrid, 256, 0, stream>>>(state, Tl, Dl, scratch);
      else if (Lm == L1_)
        k_conv_gelu_mfma<L1_><<<cgrid, 256, 0, stream>>>(state, Tl, Dl, scratch);
      else
        k_conv_gelu_mfma<L0_><<<cgrid, 256, 0, stream>>>(state, Tl, Dl, scratch);
      float* obuf = (i == NL_ - 1 && final_out) ? final_out : state;
      const size_t wbase = ((size_t)m * NL_ + i) * 2 * H_ * H_;
      k_glu_ln_mfma<<<B_ * (Lm / 16), 256, 0, stream>>>(
          oWhi + wbase, oWlo + wbase,
          out_b + ((size_t)m * NL_ + i) * 2 * H_,
          ln_g + ((size_t)m * NL_ + i) * H_,
          ln_b + ((size_t)m * NL_ + i) * H_,
          scratch, state, obuf, Lm);
    }
  };

  auto convt_blocks = [](int nPos) {
    const int nWaves = (nPos + 62) / 63;
    return (nWaves * 64 + 255) / 256;
  };

  // model 0 on enc2 (L=160)
  run_model(0, enc2, m0st, m0scr, L2_, nullptr);
  // dec1 = enc2 + enc21   (in place into enc2)
  k_add<<<(B_ * H_ * L2_) / 256, 256, 0, stream>>>(enc2, m0st);
  // dec21 = convT(dec1, up_W) + up_b + enc1
  k_convT<<<convt_blocks(B_ * L2_), 256, 0, stream>>>(enc2, up_W, up_b, enc1, dec21, L2_, 1,
                                                      B_ * L2_);
  // model 1 on dec21 (L=320), in place
  run_model(1, dec21, dec21, scr1, L1_, nullptr);
  // dec32 = convT(dec2, up1_W) + enc0
  k_convT<<<convt_blocks(B_ * L1_), 256, 0, stream>>>(dec21, up1_W, up_b, x, dec32, L1_, 0,
                                                      B_ * L1_);
  // model 2 on dec32 (L=640); final layer writes d_out
  run_model(2, dec32, dec32, scr2, L0_, outp);
}

// Round 8
// 1946.084 us; speedup vs baseline: 4.3865x; 1.1268x over previous
//
#include <hip/hip_runtime.h>
#include <math.h>

namespace {

constexpr int B_ = 256, H_ = 64, L0_ = 640, L1_ = 320, L2_ = 160;
constexpr int N2_ = 32, NL_ = 8, NM_ = 3;

typedef __attribute__((ext_vector_type(8))) short bf16x8;
typedef __attribute__((ext_vector_type(4))) float f32x4;

__device__ __forceinline__ unsigned short f2bf(float x) {
  unsigned int u = __float_as_uint(x);
  unsigned int r = (u + 0x7FFFu + ((u >> 16) & 1u)) >> 16;
  return (unsigned short)r;
}
__device__ __forceinline__ float bf2f(unsigned short h) {
  return __uint_as_float(((unsigned int)h) << 16);
}
__device__ __forceinline__ float gelu_f(float x) {
  // x * sigmoid(2t); overflow-safe (never inf/inf)
  const float t = 0.7978845608028654f * (x + 0.044715f * x * x * x);
  return x / (1.f + __expf(-2.f * t));
}
__device__ __forceinline__ void split8(const float* v, bf16x8& hi, bf16x8& lo) {
#pragma unroll
  for (int i = 0; i < 8; ++i) {
    const unsigned short hh = f2bf(v[i]);
    hi[i] = (short)hh;
    lo[i] = (short)f2bf(v[i] - bf2f(hh));
  }
}

// ---------------------------------------------------------------------------
// K + Toeplitz-fragment precompute (complex binary powering). One block per
// (m, layer, h); fragments to global TtG (bf16).
// ---------------------------------------------------------------------------
__global__ void k_compute_K_tt(const float* __restrict__ log_dt,
                               const float* __restrict__ C,
                               const float* __restrict__ logA,
                               const float* __restrict__ Aim,
                               unsigned short* __restrict__ TtG) {
  const int bid = blockIdx.x;
  const int m = bid / (NL_ * H_);
  const int rest = bid % (NL_ * H_);
  const int li = rest / H_;
  const int h = rest % H_;
  const int ph = (m * NL_ + li) * H_ + h;
  __shared__ float qkr[9][N2_], qki[9][N2_];
  __shared__ float sCr[N2_], sCi[N2_];
  __shared__ float Ksh[L0_];
  const int tid = threadIdx.x;
  if (tid < N2_) {
    const int n = tid;
    const float dt = expf(log_dt[ph]);
    const float Are = -expf(logA[(size_t)ph * N2_ + n]);
    const float Ai = Aim[(size_t)ph * N2_ + n];
    const float ar = dt * Are, ai = dt * Ai;
    const float er = expf(ar);
    float sn, cs;
    sincosf(ai, &sn, &cs);
    const float mr = er * cs - 1.f;
    const float mi = er * sn;
    const float den = Are * Are + Ai * Ai;
    const float qr_ = (mr * Are + mi * Ai) / den;
    const float qi_ = (mi * Are - mr * Ai) / den;
    const float C0 = C[((size_t)ph * N2_ + n) * 2 + 0];
    const float C1 = C[((size_t)ph * N2_ + n) * 2 + 1];
    sCr[n] = C0 * qr_ - C1 * qi_;
    sCi[n] = C0 * qi_ + C1 * qr_;
    float qr = er * cs, qi = er * sn;
#pragma unroll
    for (int k = 0; k < 9; ++k) {
      qkr[k][n] = qr;
      qki[k][n] = qi;
      const float nr = qr * qr - qi * qi;
      qi = 2.f * qr * qi;
      qr = nr;
    }
  }
  __syncthreads();
  const int Lm = (m == 0) ? L2_ : (m == 1) ? L1_ : L0_;
  const int NT = Lm / 16;

  float pr[N2_], pi[N2_];
#pragma unroll
  for (int n = 0; n < N2_; ++n) { pr[n] = 1.f; pi[n] = 0.f; }
#pragma unroll
  for (int k = 0; k < 8; ++k) {
    if ((tid >> k) & 1) {
#pragma unroll
      for (int n = 0; n < N2_; ++n) {
        const float qr = qkr[k][n], qi = qki[k][n];
        const float nr = pr[n] * qr - pi[n] * qi;
        pi[n] = pr[n] * qi + pi[n] * qr;
        pr[n] = nr;
      }
    }
  }
  for (int l = tid; l < Lm; l += 256) {
    float acc = 0.f;
#pragma unroll
    for (int n = 0; n < N2_; ++n) acc += sCr[n] * pr[n] - sCi[n] * pi[n];
    Ksh[l] = 2.f * acc;
    if (l + 256 < Lm) {
#pragma unroll
      for (int n = 0; n < N2_; ++n) {
        const float qr = qkr[8][n], qi = qki[8][n];
        const float nr = pr[n] * qr - pi[n] * qi;
        pi[n] = pr[n] * qi + pi[n] * qr;
        pr[n] = nr;
      }
    }
  }
  __syncthreads();
  const size_t base_tiles = ((m == 0) ? 0 : (m == 1) ? (size_t)64 * NL_ * 10
                                                     : (size_t)64 * NL_ * 30) +
                            (size_t)li * 64 * NT + (size_t)h * NT;
  unsigned short* Tg = TtG + base_tiles * 512;
  for (int w = tid; w < NT * 256; w += 256) {
    const int nd = w >> 8;
    const int rem = w & 255;
    const int lane = rem >> 2;
    const int pp = rem & 3;
    const int base = nd * 16 + (lane & 15) - ((lane >> 4) << 3) - 2 * pp;
    const float f0 = (base >= 0) ? Ksh[base] : 0.f;
    const float f1 = (base - 1 >= 0) ? Ksh[base - 1] : 0.f;
    *(unsigned int*)&Tg[nd * 512 + lane * 8 + 2 * pp] =
        (unsigned int)f2bf(f0) | ((unsigned int)f2bf(f1) << 16);
  }
}

// ---------------------------------------------------------------------------
// Pack f32 weights -> bf16 hi/lo (identity indexing).
// ---------------------------------------------------------------------------
__global__ void k_pack_w(const float* __restrict__ W, unsigned short* __restrict__ hi,
                         unsigned short* __restrict__ lo, int n) {
  const int p = blockIdx.x * 256 + threadIdx.x;
  if (p < n) {
    const float w = W[p];
    const unsigned short h = f2bf(w);
    hi[p] = h;
    lo[p] = f2bf(w - bf2f(h));
  }
}

// Gather-pack conv weights into P[k][o*64+i] hi/lo. src = o*so + i*si + k.
__global__ void k_pack_gather(const float* __restrict__ W, unsigned short* __restrict__ hi,
                              unsigned short* __restrict__ lo, int n, int so, int si) {
  const int idx = blockIdx.x * 256 + threadIdx.x;
  if (idx < n) {
    const int k = idx >> 12;
    const int rem = idx & 4095;
    const int o = rem >> 6;
    const int i = rem & 63;
    const float w = W[o * so + i * si + k];
    const unsigned short h = f2bf(w);
    hi[idx] = h;
    lo[idx] = f2bf(w - bf2f(h));
  }
}

// elementwise a += b
__global__ void k_add(float* a, const float* __restrict__ b) {
  const int p = blockIdx.x * 256 + threadIdx.x;
  a[p] += b[p];
}

// ---------------------------------------------------------------------------
// MFMA 1x1 encoder: out[b,o,l] = bias[o] + sum_i W[o,i] in[b,i,l].
// Block = (b, 16-l tile), wave w owns o-rows 16w..16w+15. OUT-OF-PLACE only.
// ---------------------------------------------------------------------------
__global__ __launch_bounds__(256) void k_enc_mfma(
    const unsigned short* __restrict__ Whi, const unsigned short* __restrict__ Wlo,
    const float* __restrict__ bvec, const float* __restrict__ in_,
    float* __restrict__ out, int Lcur) {
  const int tid = threadIdx.x;
  const int w = tid >> 6, lane = tid & 63, c15 = lane & 15, g4 = lane >> 4;
  const int tilesPerB = Lcur >> 4;
  const int b = blockIdx.x / tilesPerB;
  const int l = ((blockIdx.x % tilesPerB) << 4) + c15;
  const size_t bbase = (size_t)b * H_ * Lcur;
  f32x4 acc = {0.f, 0.f, 0.f, 0.f};
#pragma unroll
  for (int k0 = 0; k0 < 64; k0 += 32) {
    const int crow = k0 + 8 * g4;
    float xv[8];
#pragma unroll
    for (int i = 0; i < 8; ++i) xv[i] = in_[bbase + (size_t)(crow + i) * Lcur + l];
    bf16x8 xh, xl;
    split8(xv, xh, xl);
    const int ra = (16 * w + c15) * 64 + crow;
    const bf16x8 wh = *(const bf16x8*)(Whi + ra);
    const bf16x8 wl = *(const bf16x8*)(Wlo + ra);
    acc = __builtin_amdgcn_mfma_f32_16x16x32_bf16(wh, xh, acc, 0, 0, 0);
    acc = __builtin_amdgcn_mfma_f32_16x16x32_bf16(wh, xl, acc, 0, 0, 0);
    acc = __builtin_amdgcn_mfma_f32_16x16x32_bf16(wl, xh, acc, 0, 0, 0);
  }
#pragma unroll
  for (int r = 0; r < 4; ++r) {
    const int ca = 16 * w + 4 * g4 + r;
    out[bbase + (size_t)ca * Lcur + l] = acc[r] + bvec[ca];
  }
}

// ---------------------------------------------------------------------------
// MFMA strided down-conv (k=KW, s=2, pad=PAD):
// out[b,o,t] = bias[o] + sum_k sum_i P[k][o,i] x[b,i,2t-PAD+k].
// ---------------------------------------------------------------------------
template <int KW, int PAD>
__global__ __launch_bounds__(256) void k_down_mfma(
    const unsigned short* __restrict__ Phi, const unsigned short* __restrict__ Plo,
    const float* __restrict__ bias, const float* __restrict__ in_,
    float* __restrict__ out, int Lin, int Lout) {
  const int tid = threadIdx.x;
  const int w = tid >> 6, lane = tid & 63, c15 = lane & 15, g4 = lane >> 4;
  const int tilesPerB = Lout >> 4;
  const int b = blockIdx.x / tilesPerB;
  const int t = ((blockIdx.x % tilesPerB) << 4) + c15;
  const size_t ibase = (size_t)b * H_ * Lin;
  f32x4 acc = {0.f, 0.f, 0.f, 0.f};
#pragma unroll
  for (int k0 = 0; k0 < 64; k0 += 32) {
    const int crow = k0 + 8 * g4;
#pragma unroll
    for (int k = 0; k < KW; ++k) {
      const int c = 2 * t - PAD + k;
      const bool ok = (c >= 0) && (c < Lin);
      float xv[8];
#pragma unroll
      for (int i = 0; i < 8; ++i)
        xv[i] = ok ? in_[ibase + (size_t)(crow + i) * Lin + c] : 0.f;
      bf16x8 xh, xl;
      split8(xv, xh, xl);
      const int ra = (k << 12) + (16 * w + c15) * 64 + crow;
      const bf16x8 wh = *(const bf16x8*)(Phi + ra);
      const bf16x8 wl = *(const bf16x8*)(Plo + ra);
      acc = __builtin_amdgcn_mfma_f32_16x16x32_bf16(wh, xh, acc, 0, 0, 0);
      acc = __builtin_amdgcn_mfma_f32_16x16x32_bf16(wh, xl, acc, 0, 0, 0);
      acc = __builtin_amdgcn_mfma_f32_16x16x32_bf16(wl, xh, acc, 0, 0, 0);
    }
  }
  const size_t obase = (size_t)b * H_ * Lout;
#pragma unroll
  for (int r = 0; r < 4; ++r) {
    const int ca = 16 * w + 4 * g4 + r;
    out[obase + (size_t)ca * Lout + t] = acc[r] + bias[ca];
  }
}

// ---------------------------------------------------------------------------
// MFMA ConvTranspose1d k=3 s=2 p=1 op=1 (+bias? +skip). W prepacked [k][o,i].
//   even out[2j]   = sum_i P1[o,i] x[i,j]
//   odd  out[2j+1] = sum_i P2[o,i] x[i,j] + P0[o,i] x[i,j+1]
// ---------------------------------------------------------------------------
__global__ __launch_bounds__(256) void k_convT_mfma(
    const unsigned short* __restrict__ Phi, const unsigned short* __restrict__ Plo,
    const float* __restrict__ bias, const float* __restrict__ skip,
    const float* __restrict__ in_, float* __restrict__ out, int Lin, int hasBias) {
  const int tid = threadIdx.x;
  const int w = tid >> 6, lane = tid & 63, c15 = lane & 15, g4 = lane >> 4;
  const int tilesPerB = Lin >> 4;
  const int b = blockIdx.x / tilesPerB;
  const int j = ((blockIdx.x % tilesPerB) << 4) + c15;
  const int Lout = 2 * Lin;
  const size_t ibase = (size_t)b * H_ * Lin;
  const bool nok = (j + 1) < Lin;
  f32x4 aE = {0.f, 0.f, 0.f, 0.f}, aO = {0.f, 0.f, 0.f, 0.f};
#pragma unroll
  for (int k0 = 0; k0 < 64; k0 += 32) {
    const int crow = k0 + 8 * g4;
    float xj[8], xn[8];
#pragma unroll
    for (int i = 0; i < 8; ++i) {
      const size_t rowo = ibase + (size_t)(crow + i) * Lin;
      xj[i] = in_[rowo + j];
      xn[i] = nok ? in_[rowo + j + 1] : 0.f;
    }
    bf16x8 jh, jl, nh, nl;
    split8(xj, jh, jl);
    split8(xn, nh, nl);
    const int rbase = (16 * w + c15) * 64 + crow;
    const bf16x8 w1h = *(const bf16x8*)(Phi + 4096 + rbase);
    const bf16x8 w1l = *(const bf16x8*)(Plo + 4096 + rbase);
    const bf16x8 w2h = *(const bf16x8*)(Phi + 8192 + rbase);
    const bf16x8 w2l = *(const bf16x8*)(Plo + 8192 + rbase);
    const bf16x8 w0h = *(const bf16x8*)(Phi + rbase);
    const bf16x8 w0l = *(const bf16x8*)(Plo + rbase);
    aE = __builtin_amdgcn_mfma_f32_16x16x32_bf16(w1h, jh, aE, 0, 0, 0);
    aE = __builtin_amdgcn_mfma_f32_16x16x32_bf16(w1h, jl, aE, 0, 0, 0);
    aE = __builtin_amdgcn_mfma_f32_16x16x32_bf16(w1l, jh, aE, 0, 0, 0);
    aO = __builtin_amdgcn_mfma_f32_16x16x32_bf16(w2h, jh, aO, 0, 0, 0);
    aO = __builtin_amdgcn_mfma_f32_16x16x32_bf16(w2h, jl, aO, 0, 0, 0);
    aO = __builtin_amdgcn_mfma_f32_16x16x32_bf16(w2l, jh, aO, 0, 0, 0);
    aO = __builtin_amdgcn_mfma_f32_16x16x32_bf16(w0h, nh, aO, 0, 0, 0);
    aO = __builtin_amdgcn_mfma_f32_16x16x32_bf16(w0h, nl, aO, 0, 0, 0);
    aO = __builtin_amdgcn_mfma_f32_16x16x32_bf16(w0l, nh, aO, 0, 0, 0);
  }
  const size_t obase = (size_t)b * H_ * Lout + 2 * j;
#pragma unroll
  for (int r = 0; r < 4; ++r) {
    const int ca = 16 * w + 4 * g4 + r;
    const float bb = hasBias ? bias[ca] : 0.f;
    const size_t pos = obase + (size_t)ca * Lout;
    out[pos] = aE[r] + bb + skip[pos];
    out[pos + 1] = aO[r] + bb + skip[pos + 1];
  }
}

// ---------------------------------------------------------------------------
// MFMA causal conv + D-skip + gelu (unchanged from round 7).
// ---------------------------------------------------------------------------
template <int L>
__global__ __launch_bounds__(256) void k_conv_gelu_mfma(
    const float* __restrict__ u, const unsigned short* __restrict__ Tt,
    const float* __restrict__ D, float* __restrict__ y) {
  constexpr int NT = L / 16;
  constexpr int NG = (NT + 3) / 4;
  constexpr int LP = L + 8;
  __shared__ unsigned short uhi[16 * LP];
  __shared__ unsigned short ulo[16 * LP];

  const int h = blockIdx.x & 63;
  const int b0 = (blockIdx.x >> 6) * 16;
  const int tid = threadIdx.x;

  constexpr int PR = L / 2;
  for (int wp = tid; wp < 16 * PR; wp += 256) {
    const int row = wp / PR, cp = wp % PR;
    const float2 v = *(const float2*)(u + ((size_t)(b0 + row) * H_ + h) * L + 2 * cp);
    const unsigned short h0 = f2bf(v.x), h1 = f2bf(v.y);
    const unsigned short q0 = f2bf(v.x - bf2f(h0)), q1 = f2bf(v.y - bf2f(h1));
    *(unsigned int*)&uhi[row * LP + 2 * cp] = (unsigned int)h0 | ((unsigned int)h1 << 16);
    *(unsigned int*)&ulo[row * LP + 2 * cp] = (unsigned int)q0 | ((unsigned int)q1 << 16);
  }
  __syncthreads();

  const int wv = tid >> 6;
  const int lane = tid & 63;
  const float Dh = D[h];
  const int lquad = lane & 15;
  const int lhi = lane >> 4;
  const unsigned short* Th = Tt + (size_t)h * NT * 512 + lane * 8;

  for (int g = wv; g < NG; g += 4) {
    const int t0 = g * 4;
    const int ntile = (NT - t0 < 4) ? (NT - t0) : 4;
    f32x4 acc[4];
#pragma unroll
    for (int t = 0; t < 4; ++t) acc[t] = (f32x4){0.f, 0.f, 0.f, 0.f};
    const int nsteps = ((t0 + ntile - 1) * 16) / 32 + 1;
    for (int s = 0; s < nsteps; ++s) {
      const int j0 = 32 * s;
      const int colbase = j0 + (lhi << 3);
      const bf16x8 ah = *(const bf16x8*)&uhi[lquad * LP + colbase];
      const bf16x8 al = *(const bf16x8*)&ulo[lquad * LP + colbase];
#pragma unroll
      for (int t = 0; t < 4; ++t) {
        if (t >= ntile) break;
        const int d0 = (t0 + t) * 16 - j0;
        if (d0 < 0) continue;
        const bf16x8 bf = *(const bf16x8*)(Th + (size_t)(d0 >> 4) * 512);
        acc[t] = __builtin_amdgcn_mfma_f32_16x16x32_bf16(ah, bf, acc[t], 0, 0, 0);
        acc[t] = __builtin_amdgcn_mfma_f32_16x16x32_bf16(al, bf, acc[t], 0, 0, 0);
      }
    }
#pragma unroll
    for (int t = 0; t < 4; ++t) {
      if (t >= ntile) break;
      const int l = (t0 + t) * 16 + lquad;
#pragma unroll
      for (int r = 0; r < 4; ++r) {
        const int row = (lhi << 2) + r;
        const float uv = bf2f(uhi[row * LP + l]) + bf2f(ulo[row * LP + l]);
        const float val = acc[t][r] + uv * Dh;
        y[((size_t)(b0 + row) * H_ + h) * L + l] = gelu_f(val);
      }
    }
  }
}

// ---------------------------------------------------------------------------
// MFMA out-proj (64->128) + GLU + residual + LayerNorm (unchanged).
// ---------------------------------------------------------------------------
__global__ __launch_bounds__(256) void k_glu_ln_mfma(
    const unsigned short* __restrict__ Whi, const unsigned short* __restrict__ Wlo,
    const float* __restrict__ ob, const float* __restrict__ lng,
    const float* __restrict__ lnb, const float* __restrict__ ybuf,
    const float* __restrict__ xbuf, float* __restrict__ obuf, int Lcur) {
  const int tid = threadIdx.x;
  const int w = tid >> 6;
  const int lane = tid & 63;
  const int c15 = lane & 15;
  const int g4 = lane >> 4;
  const int tilesPerB = Lcur >> 4;
  const int b = blockIdx.x / tilesPerB;
  const int l = ((blockIdx.x % tilesPerB) << 4) + c15;
  const size_t bbase = (size_t)b * H_ * Lcur;

  f32x4 accA = {0.f, 0.f, 0.f, 0.f}, accG = {0.f, 0.f, 0.f, 0.f};
#pragma unroll
  for (int k0 = 0; k0 < 64; k0 += 32) {
    const int crow = k0 + 8 * g4;
    float yv[8];
#pragma unroll
    for (int i = 0; i < 8; ++i)
      yv[i] = ybuf[bbase + (size_t)(crow + i) * Lcur + l];
    bf16x8 yhi, ylo;
    split8(yv, yhi, ylo);
    const int ra = (16 * w + c15) * 64 + crow;
    const int rg = ((64 + 16 * w) + c15) * 64 + crow;
    const bf16x8 wa_hi = *(const bf16x8*)(Whi + ra);
    const bf16x8 wa_lo = *(const bf16x8*)(Wlo + ra);
    const bf16x8 wg_hi = *(const bf16x8*)(Whi + rg);
    const bf16x8 wg_lo = *(const bf16x8*)(Wlo + rg);
    accA = __builtin_amdgcn_mfma_f32_16x16x32_bf16(wa_hi, yhi, accA, 0, 0, 0);
    accA = __builtin_amdgcn_mfma_f32_16x16x32_bf16(wa_hi, ylo, accA, 0, 0, 0);
    accA = __builtin_amdgcn_mfma_f32_16x16x32_bf16(wa_lo, yhi, accA, 0, 0, 0);
    accG = __builtin_amdgcn_mfma_f32_16x16x32_bf16(wg_hi, yhi, accG, 0, 0, 0);
    accG = __builtin_amdgcn_mfma_f32_16x16x32_bf16(wg_hi, ylo, accG, 0, 0, 0);
    accG = __builtin_amdgcn_mfma_f32_16x16x32_bf16(wg_lo, yhi, accG, 0, 0, 0);
  }

  __shared__ float red[4][16][2];
  float wv[4];
  float s1 = 0.f, s2 = 0.f;
#pragma unroll
  for (int r = 0; r < 4; ++r) {
    const int ca = 16 * w + 4 * g4 + r;
    const float a = accA[r] + ob[ca];
    const float g = accG[r] + ob[H_ + ca];
    const float z = a / (1.f + expf(-g));
    const float xv = xbuf[bbase + (size_t)ca * Lcur + l];
    wv[r] = z + xv;
    s1 += wv[r];
    s2 += wv[r] * wv[r];
  }
  s1 += __shfl_xor(s1, 16);
  s2 += __shfl_xor(s2, 16);
  s1 += __shfl_xor(s1, 32);
  s2 += __shfl_xor(s2, 32);
  if (g4 == 0) {
    red[w][c15][0] = s1;
    red[w][c15][1] = s2;
  }
  __syncthreads();
  float t1 = 0.f, t2 = 0.f;
#pragma unroll
  for (int q = 0; q < 4; ++q) {
    t1 += red[q][c15][0];
    t2 += red[q][c15][1];
  }
  const float mean = t1 * (1.f / 64.f);
  const float var = t2 * (1.f / 64.f) - mean * mean;
  const float rstd = rsqrtf(var + 1e-5f);
#pragma unroll
  for (int r = 0; r < 4; ++r) {
    const int ca = 16 * w + 4 * g4 + r;
    obuf[bbase + (size_t)ca * Lcur + l] = (wv[r] - mean) * rstd * lng[ca] + lnb[ca];
  }
}

}  // namespace

// ---------------------------------------------------------------------------
extern "C" void kernel_launch(void* const* d_in, const int* in_sizes, int n_in,
                              void* d_out, int out_size, void* d_ws, size_t ws_size,
                              hipStream_t stream) {
  const float* x       = (const float*)d_in[0];
  const float* enc_W   = (const float*)d_in[1];
  const float* enc_b   = (const float*)d_in[2];
  const float* ln_g    = (const float*)d_in[3];
  const float* ln_b    = (const float*)d_in[4];
  const float* s4_D    = (const float*)d_in[5];
  const float* s4_ldt  = (const float*)d_in[6];
  const float* s4_C    = (const float*)d_in[7];
  const float* s4_logA = (const float*)d_in[8];
  const float* s4_Aim  = (const float*)d_in[9];
  const float* out_W   = (const float*)d_in[10];
  const float* out_b   = (const float*)d_in[11];
  const float* cd1_W   = (const float*)d_in[12];
  const float* cd1_b   = (const float*)d_in[13];
  const float* cd2_W   = (const float*)d_in[14];
  const float* cd2_b   = (const float*)d_in[15];
  const float* up_W    = (const float*)d_in[16];
  const float* up_b    = (const float*)d_in[17];
  const float* up1_W   = (const float*)d_in[18];
  float* outp = (float*)d_out;

  // ---- workspace arena (~127.2 MB, lifetime-overlapped) ----
  unsigned short* TtG = (unsigned short*)d_ws;
  const size_t ttg_shorts = (size_t)64 * NL_ * 70 * 512;      // 18.35M
  const size_t nWsz = (size_t)NM_ * NL_ * 2 * H_ * H_;        // 1.57M
  unsigned short* oWhi = TtG + ttg_shorts;
  unsigned short* oWlo = oWhi + nWsz;
  unsigned short* eWhi = oWlo + nWsz;        // 3*4096
  unsigned short* eWlo = eWhi + 3 * 4096;
  unsigned short* c1hi = eWlo + 3 * 4096;    // 3*4096
  unsigned short* c1lo = c1hi + 3 * 4096;
  unsigned short* c2hi = c1lo + 3 * 4096;    // 2*4096
  unsigned short* c2lo = c2hi + 2 * 4096;
  unsigned short* uphi = c2lo + 2 * 4096;    // 3*4096
  unsigned short* uplo = uphi + 3 * 4096;
  unsigned short* u1hi = uplo + 3 * 4096;    // 3*4096
  unsigned short* u1lo = u1hi + 3 * 4096;
  float* slotA = (float*)(u1lo + 3 * 4096);            // B*H*L0 floats
  float* slotB = slotA + (size_t)B_ * H_ * L0_;        // B*H*L0 floats

  // lifetime map (stream-serial, encoders all OUT-OF-PLACE):
  float* enc1  = slotA;                                // B*H*L1
  float* enc2  = slotA + (size_t)B_ * H_ * L1_;        // B*H*L2
  float* st0   = slotB;                                // B*H*L2 (model-0 state)
  float* scr0  = slotB + (size_t)B_ * H_ * L2_;        // B*H*L2
  float* dec21 = slotB;                                // B*H*L1 (st0/scr0 dead)
  float* st1   = slotA;                                // B*H*L1 (enc1/enc2 dead)
  float* scr1  = slotA + (size_t)B_ * H_ * L1_;        // B*H*L1
  float* dec32 = slotB;                                // B*H*L0 (dec21 dead)
  float* st2   = slotA;                                // B*H*L0 (st1/scr1 dead)
  float* scr2  = slotB;                                // B*H*L0 (dec32 dead post-enc)

  auto tt_layer = [&](int m, int i) -> const unsigned short* {
    const size_t NTm = (m == 0) ? 10 : (m == 1) ? 20 : 40;
    const size_t base = (m == 0) ? 0 : (m == 1) ? (size_t)64 * NL_ * 10
                                                : (size_t)64 * NL_ * 30;
    return TtG + (base + (size_t)i * 64 * NTm) * 512;
  };

  k_compute_K_tt<<<NM_ * NL_ * H_, 256, 0, stream>>>(s4_ldt, s4_C, s4_logA, s4_Aim, TtG);
  k_pack_w<<<((int)nWsz + 255) / 256, 256, 0, stream>>>(out_W, oWhi, oWlo, (int)nWsz);
  k_pack_w<<<48, 256, 0, stream>>>(enc_W, eWhi, eWlo, 3 * 4096);
  k_pack_gather<<<48, 256, 0, stream>>>(cd1_W, c1hi, c1lo, 3 * 4096, 192, 3);
  k_pack_gather<<<32, 256, 0, stream>>>(cd2_W, c2hi, c2lo, 2 * 4096, 128, 2);
  k_pack_gather<<<48, 256, 0, stream>>>(up_W, uphi, uplo, 3 * 4096, 3, 192);
  k_pack_gather<<<48, 256, 0, stream>>>(up1_W, u1hi, u1lo, 3 * 4096, 3, 192);

  // enc1 = conv_d1(x), enc2 = conv_d2(enc1)
  k_down_mfma<3, 1><<<B_ * (L1_ / 16), 256, 0, stream>>>(c1hi, c1lo, cd1_b, x, enc1,
                                                         L0_, L1_);
  k_down_mfma<2, 0><<<B_ * (L2_ / 16), 256, 0, stream>>>(c2hi, c2lo, cd2_b, enc1, enc2,
                                                         L1_, L2_);

  auto run_model = [&](int m, const float* input, float* state, float* scratch,
                       int Lm, float* final_out) {
    k_enc_mfma<<<B_ * (Lm / 16), 256, 0, stream>>>(eWhi + m * 4096, eWlo + m * 4096,
                                                   enc_b + (size_t)m * H_, input, state, Lm);
    for (int i = 0; i < NL_; ++i) {
      const unsigned short* Tl = tt_layer(m, i);
      const float* Dl = s4_D + ((size_t)m * NL_ + i) * H_;
      const int cgrid = (B_ / 16) * H_;
      if (Lm == L2_)
        k_conv_gelu_mfma<L2_><<<cgrid, 256, 0, stream>>>(state, Tl, Dl, scratch);
      else if (Lm == L1_)
        k_conv_gelu_mfma<L1_><<<cgrid, 256, 0, stream>>>(state, Tl, Dl, scratch);
      else
        k_conv_gelu_mfma<L0_><<<cgrid, 256, 0, stream>>>(state, Tl, Dl, scratch);
      float* obuf = (i == NL_ - 1 && final_out) ? final_out : state;
      const size_t wbase = ((size_t)m * NL_ + i) * 2 * H_ * H_;
      k_glu_ln_mfma<<<B_ * (Lm / 16), 256, 0, stream>>>(
          oWhi + wbase, oWlo + wbase,
          out_b + ((size_t)m * NL_ + i) * 2 * H_,
          ln_g + ((size_t)m * NL_ + i) * H_,
          ln_b + ((size_t)m * NL_ + i) * H_,
          scratch, state, obuf, Lm);
    }
  };

  // model 0 on enc2 (L=160): encoder out-of-place into st0
  run_model(0, enc2, st0, scr0, L2_, nullptr);
  // dec1 = enc2 + m0-out  (in place into enc2; elementwise, thread-local safe)
  k_add<<<(B_ * H_ * L2_) / 256, 256, 0, stream>>>(enc2, st0);
  // dec21 = convT(dec1, up_W) + up_b + enc1   -> slotB
  k_convT_mfma<<<B_ * (L2_ / 16), 256, 0, stream>>>(uphi, uplo, up_b, enc1, enc2, dec21,
                                                    L2_, 1);
  // model 1 on dec21 (L=320): encoder into st1 (slotA)
  run_model(1, dec21, st1, scr1, L1_, nullptr);
  // dec32 = convT(m1-out, up1_W) + enc0   -> slotB
  k_convT_mfma<<<B_ * (L1_ / 16), 256, 0, stream>>>(u1hi, u1lo, up_b, x, st1, dec32,
                                                    L1_, 0);
  // model 2 on dec32 (L=640): encoder into st2 (slotA); final layer -> d_out
  run_model(2, dec32, st2, scr2, L0_, outp);
}

// Round 9
// 1843.390 us; speedup vs baseline: 4.6308x; 1.0557x over previous
//
#include <hip/hip_runtime.h>
#include <math.h>

namespace {

constexpr int B_ = 256, H_ = 64, L0_ = 640, L1_ = 320, L2_ = 160;
constexpr int N2_ = 32, NL_ = 8, NM_ = 3;

typedef __attribute__((ext_vector_type(8))) short bf16x8;
typedef __attribute__((ext_vector_type(4))) float f32x4;

__device__ __forceinline__ unsigned short f2bf(float x) {
  unsigned int u = __float_as_uint(x);
  unsigned int r = (u + 0x7FFFu + ((u >> 16) & 1u)) >> 16;
  return (unsigned short)r;
}
__device__ __forceinline__ float bf2f(unsigned short h) {
  return __uint_as_float(((unsigned int)h) << 16);
}
__device__ __forceinline__ float gelu_f(float x) {
  // x * sigmoid(2t); overflow-safe (never inf/inf)
  const float t = 0.7978845608028654f * (x + 0.044715f * x * x * x);
  return x / (1.f + __expf(-2.f * t));
}
__device__ __forceinline__ void split8(const float* v, bf16x8& hi, bf16x8& lo) {
#pragma unroll
  for (int i = 0; i < 8; ++i) {
    const unsigned short hh = f2bf(v[i]);
    hi[i] = (short)hh;
    lo[i] = (short)f2bf(v[i] - bf2f(hh));
  }
}

// ---------------------------------------------------------------------------
// K + Toeplitz-fragment precompute. One block per (m, layer, h).
// Spill-free: thread (l0 = tid>>2, g = tid&3) holds only 8 poles (pr/pi[8]);
// K[l] partial sums reduced across the 4-lane group via shfl_xor.
// p = q^l0 via bit-decomposed init (qk[0..5]); advance by q^64 (qk[6]).
// ---------------------------------------------------------------------------
__global__ __launch_bounds__(256) void k_compute_K_tt(
    const float* __restrict__ log_dt, const float* __restrict__ C,
    const float* __restrict__ logA, const float* __restrict__ Aim,
    unsigned short* __restrict__ TtG) {
  const int bid = blockIdx.x;
  const int m = bid / (NL_ * H_);
  const int rest = bid % (NL_ * H_);
  const int li = rest / H_;
  const int h = rest % H_;
  const int ph = (m * NL_ + li) * H_ + h;
  __shared__ float qkr[7][N2_], qki[7][N2_];
  __shared__ float sCr[N2_], sCi[N2_];
  __shared__ float Ksh[L0_];
  const int tid = threadIdx.x;
  if (tid < N2_) {
    const int n = tid;
    const float dt = expf(log_dt[ph]);
    const float Are = -expf(logA[(size_t)ph * N2_ + n]);
    const float Ai = Aim[(size_t)ph * N2_ + n];
    const float ar = dt * Are, ai = dt * Ai;
    const float er = expf(ar);
    float sn, cs;
    sincosf(ai, &sn, &cs);  // small args: fast path
    const float mr = er * cs - 1.f;
    const float mi = er * sn;
    const float den = Are * Are + Ai * Ai;
    const float qr_ = (mr * Are + mi * Ai) / den;
    const float qi_ = (mi * Are - mr * Ai) / den;
    const float C0 = C[((size_t)ph * N2_ + n) * 2 + 0];
    const float C1 = C[((size_t)ph * N2_ + n) * 2 + 1];
    sCr[n] = C0 * qr_ - C1 * qi_;
    sCi[n] = C0 * qi_ + C1 * qr_;
    float qr = er * cs, qi = er * sn;  // q = exp(dtA)
#pragma unroll
    for (int k = 0; k < 7; ++k) {
      qkr[k][n] = qr;
      qki[k][n] = qi;
      const float nr = qr * qr - qi * qi;
      qi = 2.f * qr * qi;
      qr = nr;
    }
  }
  __syncthreads();
  const int Lm = (m == 0) ? L2_ : (m == 1) ? L1_ : L0_;
  const int NT = Lm / 16;

  const int l0 = tid >> 2;       // 0..63
  const int g = tid & 3;         // n-slice: n = g*8 + j
  float pr[8], pi[8];
#pragma unroll
  for (int j = 0; j < 8; ++j) { pr[j] = 1.f; pi[j] = 0.f; }
#pragma unroll
  for (int k = 0; k < 6; ++k) {
    if ((l0 >> k) & 1) {
#pragma unroll
      for (int j = 0; j < 8; ++j) {
        const int n = g * 8 + j;
        const float qr = qkr[k][n], qi = qki[k][n];
        const float nr = pr[j] * qr - pi[j] * qi;
        pi[j] = pr[j] * qi + pi[j] * qr;
        pr[j] = nr;
      }
    }
  }
  for (int l = l0; l < Lm; l += 64) {
    float acc = 0.f;
#pragma unroll
    for (int j = 0; j < 8; ++j) {
      const int n = g * 8 + j;
      acc += sCr[n] * pr[j] - sCi[n] * pi[j];
    }
    acc += __shfl_xor(acc, 1);
    acc += __shfl_xor(acc, 2);
    if (g == 0) Ksh[l] = 2.f * acc;
    if (l + 64 < Lm) {
#pragma unroll
      for (int j = 0; j < 8; ++j) {
        const int n = g * 8 + j;
        const float qr = qkr[6][n], qi = qki[6][n];
        const float nr = pr[j] * qr - pi[j] * qi;
        pi[j] = pr[j] * qi + pi[j] * qr;
        pr[j] = nr;
      }
    }
  }
  __syncthreads();
  // Toeplitz fragment build -> global (bf16)
  const size_t base_tiles = ((m == 0) ? 0 : (m == 1) ? (size_t)64 * NL_ * 10
                                                     : (size_t)64 * NL_ * 30) +
                            (size_t)li * 64 * NT + (size_t)h * NT;
  unsigned short* Tg = TtG + base_tiles * 512;
  for (int w = tid; w < NT * 256; w += 256) {
    const int nd = w >> 8;
    const int rem = w & 255;
    const int lane = rem >> 2;
    const int pp = rem & 3;
    const int base = nd * 16 + (lane & 15) - ((lane >> 4) << 3) - 2 * pp;
    const float f0 = (base >= 0) ? Ksh[base] : 0.f;
    const float f1 = (base - 1 >= 0) ? Ksh[base - 1] : 0.f;
    *(unsigned int*)&Tg[nd * 512 + lane * 8 + 2 * pp] =
        (unsigned int)f2bf(f0) | ((unsigned int)f2bf(f1) << 16);
  }
}

// ---------------------------------------------------------------------------
// Pack f32 weights -> bf16 hi/lo (identity indexing).
// ---------------------------------------------------------------------------
__global__ void k_pack_w(const float* __restrict__ W, unsigned short* __restrict__ hi,
                         unsigned short* __restrict__ lo, int n) {
  const int p = blockIdx.x * 256 + threadIdx.x;
  if (p < n) {
    const float w = W[p];
    const unsigned short h = f2bf(w);
    hi[p] = h;
    lo[p] = f2bf(w - bf2f(h));
  }
}

// Gather-pack conv weights into P[k][o*64+i] hi/lo. src = o*so + i*si + k.
__global__ void k_pack_gather(const float* __restrict__ W, unsigned short* __restrict__ hi,
                              unsigned short* __restrict__ lo, int n, int so, int si) {
  const int idx = blockIdx.x * 256 + threadIdx.x;
  if (idx < n) {
    const int k = idx >> 12;
    const int rem = idx & 4095;
    const int o = rem >> 6;
    const int i = rem & 63;
    const float w = W[o * so + i * si + k];
    const unsigned short h = f2bf(w);
    hi[idx] = h;
    lo[idx] = f2bf(w - bf2f(h));
  }
}

// elementwise a += b
__global__ void k_add(float* a, const float* __restrict__ b) {
  const int p = blockIdx.x * 256 + threadIdx.x;
  a[p] += b[p];
}

// ---------------------------------------------------------------------------
// MFMA 1x1 encoder: out[b,o,l] = bias[o] + sum_i W[o,i] in[b,i,l].
// Block = (b, 16-l tile), wave w owns o-rows 16w..16w+15. OUT-OF-PLACE only.
// ---------------------------------------------------------------------------
__global__ __launch_bounds__(256) void k_enc_mfma(
    const unsigned short* __restrict__ Whi, const unsigned short* __restrict__ Wlo,
    const float* __restrict__ bvec, const float* __restrict__ in_,
    float* __restrict__ out, int Lcur) {
  const int tid = threadIdx.x;
  const int w = tid >> 6, lane = tid & 63, c15 = lane & 15, g4 = lane >> 4;
  const int tilesPerB = Lcur >> 4;
  const int b = blockIdx.x / tilesPerB;
  const int l = ((blockIdx.x % tilesPerB) << 4) + c15;
  const size_t bbase = (size_t)b * H_ * Lcur;
  f32x4 acc = {0.f, 0.f, 0.f, 0.f};
#pragma unroll
  for (int k0 = 0; k0 < 64; k0 += 32) {
    const int crow = k0 + 8 * g4;
    float xv[8];
#pragma unroll
    for (int i = 0; i < 8; ++i) xv[i] = in_[bbase + (size_t)(crow + i) * Lcur + l];
    bf16x8 xh, xl;
    split8(xv, xh, xl);
    const int ra = (16 * w + c15) * 64 + crow;
    const bf16x8 wh = *(const bf16x8*)(Whi + ra);
    const bf16x8 wl = *(const bf16x8*)(Wlo + ra);
    acc = __builtin_amdgcn_mfma_f32_16x16x32_bf16(wh, xh, acc, 0, 0, 0);
    acc = __builtin_amdgcn_mfma_f32_16x16x32_bf16(wh, xl, acc, 0, 0, 0);
    acc = __builtin_amdgcn_mfma_f32_16x16x32_bf16(wl, xh, acc, 0, 0, 0);
  }
#pragma unroll
  for (int r = 0; r < 4; ++r) {
    const int ca = 16 * w + 4 * g4 + r;
    out[bbase + (size_t)ca * Lcur + l] = acc[r] + bvec[ca];
  }
}

// ---------------------------------------------------------------------------
// MFMA strided down-conv (k=KW, s=2, pad=PAD):
// out[b,o,t] = bias[o] + sum_k sum_i P[k][o,i] x[b,i,2t-PAD+k].
// ---------------------------------------------------------------------------
template <int KW, int PAD>
__global__ __launch_bounds__(256) void k_down_mfma(
    const unsigned short* __restrict__ Phi, const unsigned short* __restrict__ Plo,
    const float* __restrict__ bias, const float* __restrict__ in_,
    float* __restrict__ out, int Lin, int Lout) {
  const int tid = threadIdx.x;
  const int w = tid >> 6, lane = tid & 63, c15 = lane & 15, g4 = lane >> 4;
  const int tilesPerB = Lout >> 4;
  const int b = blockIdx.x / tilesPerB;
  const int t = ((blockIdx.x % tilesPerB) << 4) + c15;
  const size_t ibase = (size_t)b * H_ * Lin;
  f32x4 acc = {0.f, 0.f, 0.f, 0.f};
#pragma unroll
  for (int k0 = 0; k0 < 64; k0 += 32) {
    const int crow = k0 + 8 * g4;
#pragma unroll
    for (int k = 0; k < KW; ++k) {
      const int c = 2 * t - PAD + k;
      const bool ok = (c >= 0) && (c < Lin);
      float xv[8];
#pragma unroll
      for (int i = 0; i < 8; ++i)
        xv[i] = ok ? in_[ibase + (size_t)(crow + i) * Lin + c] : 0.f;
      bf16x8 xh, xl;
      split8(xv, xh, xl);
      const int ra = (k << 12) + (16 * w + c15) * 64 + crow;
      const bf16x8 wh = *(const bf16x8*)(Phi + ra);
      const bf16x8 wl = *(const bf16x8*)(Plo + ra);
      acc = __builtin_amdgcn_mfma_f32_16x16x32_bf16(wh, xh, acc, 0, 0, 0);
      acc = __builtin_amdgcn_mfma_f32_16x16x32_bf16(wh, xl, acc, 0, 0, 0);
      acc = __builtin_amdgcn_mfma_f32_16x16x32_bf16(wl, xh, acc, 0, 0, 0);
    }
  }
  const size_t obase = (size_t)b * H_ * Lout;
#pragma unroll
  for (int r = 0; r < 4; ++r) {
    const int ca = 16 * w + 4 * g4 + r;
    out[obase + (size_t)ca * Lout + t] = acc[r] + bias[ca];
  }
}

// ---------------------------------------------------------------------------
// MFMA ConvTranspose1d k=3 s=2 p=1 op=1 (+bias? +skip). W prepacked [k][o,i].
// ---------------------------------------------------------------------------
__global__ __launch_bounds__(256) void k_convT_mfma(
    const unsigned short* __restrict__ Phi, const unsigned short* __restrict__ Plo,
    const float* __restrict__ bias, const float* __restrict__ skip,
    const float* __restrict__ in_, float* __restrict__ out, int Lin, int hasBias) {
  const int tid = threadIdx.x;
  const int w = tid >> 6, lane = tid & 63, c15 = lane & 15, g4 = lane >> 4;
  const int tilesPerB = Lin >> 4;
  const int b = blockIdx.x / tilesPerB;
  const int j = ((blockIdx.x % tilesPerB) << 4) + c15;
  const int Lout = 2 * Lin;
  const size_t ibase = (size_t)b * H_ * Lin;
  const bool nok = (j + 1) < Lin;
  f32x4 aE = {0.f, 0.f, 0.f, 0.f}, aO = {0.f, 0.f, 0.f, 0.f};
#pragma unroll
  for (int k0 = 0; k0 < 64; k0 += 32) {
    const int crow = k0 + 8 * g4;
    float xj[8], xn[8];
#pragma unroll
    for (int i = 0; i < 8; ++i) {
      const size_t rowo = ibase + (size_t)(crow + i) * Lin;
      xj[i] = in_[rowo + j];
      xn[i] = nok ? in_[rowo + j + 1] : 0.f;
    }
    bf16x8 jh, jl, nh, nl;
    split8(xj, jh, jl);
    split8(xn, nh, nl);
    const int rbase = (16 * w + c15) * 64 + crow;
    const bf16x8 w1h = *(const bf16x8*)(Phi + 4096 + rbase);
    const bf16x8 w1l = *(const bf16x8*)(Plo + 4096 + rbase);
    const bf16x8 w2h = *(const bf16x8*)(Phi + 8192 + rbase);
    const bf16x8 w2l = *(const bf16x8*)(Plo + 8192 + rbase);
    const bf16x8 w0h = *(const bf16x8*)(Phi + rbase);
    const bf16x8 w0l = *(const bf16x8*)(Plo + rbase);
    aE = __builtin_amdgcn_mfma_f32_16x16x32_bf16(w1h, jh, aE, 0, 0, 0);
    aE = __builtin_amdgcn_mfma_f32_16x16x32_bf16(w1h, jl, aE, 0, 0, 0);
    aE = __builtin_amdgcn_mfma_f32_16x16x32_bf16(w1l, jh, aE, 0, 0, 0);
    aO = __builtin_amdgcn_mfma_f32_16x16x32_bf16(w2h, jh, aO, 0, 0, 0);
    aO = __builtin_amdgcn_mfma_f32_16x16x32_bf16(w2h, jl, aO, 0, 0, 0);
    aO = __builtin_amdgcn_mfma_f32_16x16x32_bf16(w2l, jh, aO, 0, 0, 0);
    aO = __builtin_amdgcn_mfma_f32_16x16x32_bf16(w0h, nh, aO, 0, 0, 0);
    aO = __builtin_amdgcn_mfma_f32_16x16x32_bf16(w0h, nl, aO, 0, 0, 0);
    aO = __builtin_amdgcn_mfma_f32_16x16x32_bf16(w0l, nh, aO, 0, 0, 0);
  }
  const size_t obase = (size_t)b * H_ * Lout + 2 * j;
#pragma unroll
  for (int r = 0; r < 4; ++r) {
    const int ca = 16 * w + 4 * g4 + r;
    const float bb = hasBias ? bias[ca] : 0.f;
    const size_t pos = obase + (size_t)ca * Lout;
    out[pos] = aE[r] + bb + skip[pos];
    out[pos + 1] = aO[r] + bb + skip[pos + 1];
  }
}

// ---------------------------------------------------------------------------
// MFMA causal conv + D-skip + gelu (unchanged).
// ---------------------------------------------------------------------------
template <int L>
__global__ __launch_bounds__(256) void k_conv_gelu_mfma(
    const float* __restrict__ u, const unsigned short* __restrict__ Tt,
    const float* __restrict__ D, float* __restrict__ y) {
  constexpr int NT = L / 16;
  constexpr int NG = (NT + 3) / 4;
  constexpr int LP = L + 8;
  __shared__ unsigned short uhi[16 * LP];
  __shared__ unsigned short ulo[16 * LP];

  const int h = blockIdx.x & 63;
  const int b0 = (blockIdx.x >> 6) * 16;
  const int tid = threadIdx.x;

  constexpr int PR = L / 2;
  for (int wp = tid; wp < 16 * PR; wp += 256) {
    const int row = wp / PR, cp = wp % PR;
    const float2 v = *(const float2*)(u + ((size_t)(b0 + row) * H_ + h) * L + 2 * cp);
    const unsigned short h0 = f2bf(v.x), h1 = f2bf(v.y);
    const unsigned short q0 = f2bf(v.x - bf2f(h0)), q1 = f2bf(v.y - bf2f(h1));
    *(unsigned int*)&uhi[row * LP + 2 * cp] = (unsigned int)h0 | ((unsigned int)h1 << 16);
    *(unsigned int*)&ulo[row * LP + 2 * cp] = (unsigned int)q0 | ((unsigned int)q1 << 16);
  }
  __syncthreads();

  const int wv = tid >> 6;
  const int lane = tid & 63;
  const float Dh = D[h];
  const int lquad = lane & 15;
  const int lhi = lane >> 4;
  const unsigned short* Th = Tt + (size_t)h * NT * 512 + lane * 8;

  for (int g = wv; g < NG; g += 4) {
    const int t0 = g * 4;
    const int ntile = (NT - t0 < 4) ? (NT - t0) : 4;
    f32x4 acc[4];
#pragma unroll
    for (int t = 0; t < 4; ++t) acc[t] = (f32x4){0.f, 0.f, 0.f, 0.f};
    const int nsteps = ((t0 + ntile - 1) * 16) / 32 + 1;
    for (int s = 0; s < nsteps; ++s) {
      const int j0 = 32 * s;
      const int colbase = j0 + (lhi << 3);
      const bf16x8 ah = *(const bf16x8*)&uhi[lquad * LP + colbase];
      const bf16x8 al = *(const bf16x8*)&ulo[lquad * LP + colbase];
#pragma unroll
      for (int t = 0; t < 4; ++t) {
        if (t >= ntile) break;
        const int d0 = (t0 + t) * 16 - j0;
        if (d0 < 0) continue;
        const bf16x8 bf = *(const bf16x8*)(Th + (size_t)(d0 >> 4) * 512);
        acc[t] = __builtin_amdgcn_mfma_f32_16x16x32_bf16(ah, bf, acc[t], 0, 0, 0);
        acc[t] = __builtin_amdgcn_mfma_f32_16x16x32_bf16(al, bf, acc[t], 0, 0, 0);
      }
    }
#pragma unroll
    for (int t = 0; t < 4; ++t) {
      if (t >= ntile) break;
      const int l = (t0 + t) * 16 + lquad;
#pragma unroll
      for (int r = 0; r < 4; ++r) {
        const int row = (lhi << 2) + r;
        const float uv = bf2f(uhi[row * LP + l]) + bf2f(ulo[row * LP + l]);
        const float val = acc[t][r] + uv * Dh;
        y[((size_t)(b0 + row) * H_ + h) * L + l] = gelu_f(val);
      }
    }
  }
}

// ---------------------------------------------------------------------------
// MFMA out-proj (64->128) + GLU + residual + LayerNorm (unchanged).
// ---------------------------------------------------------------------------
__global__ __launch_bounds__(256) void k_glu_ln_mfma(
    const unsigned short* __restrict__ Whi, const unsigned short* __restrict__ Wlo,
    const float* __restrict__ ob, const float* __restrict__ lng,
    const float* __restrict__ lnb, const float* __restrict__ ybuf,
    const float* __restrict__ xbuf, float* __restrict__ obuf, int Lcur) {
  const int tid = threadIdx.x;
  const int w = tid >> 6;
  const int lane = tid & 63;
  const int c15 = lane & 15;
  const int g4 = lane >> 4;
  const int tilesPerB = Lcur >> 4;
  const int b = blockIdx.x / tilesPerB;
  const int l = ((blockIdx.x % tilesPerB) << 4) + c15;
  const size_t bbase = (size_t)b * H_ * Lcur;

  f32x4 accA = {0.f, 0.f, 0.f, 0.f}, accG = {0.f, 0.f, 0.f, 0.f};
#pragma unroll
  for (int k0 = 0; k0 < 64; k0 += 32) {
    const int crow = k0 + 8 * g4;
    float yv[8];
#pragma unroll
    for (int i = 0; i < 8; ++i)
      yv[i] = ybuf[bbase + (size_t)(crow + i) * Lcur + l];
    bf16x8 yhi, ylo;
    split8(yv, yhi, ylo);
    const int ra = (16 * w + c15) * 64 + crow;
    const int rg = ((64 + 16 * w) + c15) * 64 + crow;
    const bf16x8 wa_hi = *(const bf16x8*)(Whi + ra);
    const bf16x8 wa_lo = *(const bf16x8*)(Wlo + ra);
    const bf16x8 wg_hi = *(const bf16x8*)(Whi + rg);
    const bf16x8 wg_lo = *(const bf16x8*)(Wlo + rg);
    accA = __builtin_amdgcn_mfma_f32_16x16x32_bf16(wa_hi, yhi, accA, 0, 0, 0);
    accA = __builtin_amdgcn_mfma_f32_16x16x32_bf16(wa_hi, ylo, accA, 0, 0, 0);
    accA = __builtin_amdgcn_mfma_f32_16x16x32_bf16(wa_lo, yhi, accA, 0, 0, 0);
    accG = __builtin_amdgcn_mfma_f32_16x16x32_bf16(wg_hi, yhi, accG, 0, 0, 0);
    accG = __builtin_amdgcn_mfma_f32_16x16x32_bf16(wg_hi, ylo, accG, 0, 0, 0);
    accG = __builtin_amdgcn_mfma_f32_16x16x32_bf16(wg_lo, yhi, accG, 0, 0, 0);
  }

  __shared__ float red[4][16][2];
  float wv[4];
  float s1 = 0.f, s2 = 0.f;
#pragma unroll
  for (int r = 0; r < 4; ++r) {
    const int ca = 16 * w + 4 * g4 + r;
    const float a = accA[r] + ob[ca];
    const float g = accG[r] + ob[H_ + ca];
    const float z = a / (1.f + expf(-g));
    const float xv = xbuf[bbase + (size_t)ca * Lcur + l];
    wv[r] = z + xv;
    s1 += wv[r];
    s2 += wv[r] * wv[r];
  }
  s1 += __shfl_xor(s1, 16);
  s2 += __shfl_xor(s2, 16);
  s1 += __shfl_xor(s1, 32);
  s2 += __shfl_xor(s2, 32);
  if (g4 == 0) {
    red[w][c15][0] = s1;
    red[w][c15][1] = s2;
  }
  __syncthreads();
  float t1 = 0.f, t2 = 0.f;
#pragma unroll
  for (int q = 0; q < 4; ++q) {
    t1 += red[q][c15][0];
    t2 += red[q][c15][1];
  }
  const float mean = t1 * (1.f / 64.f);
  const float var = t2 * (1.f / 64.f) - mean * mean;
  const float rstd = rsqrtf(var + 1e-5f);
#pragma unroll
  for (int r = 0; r < 4; ++r) {
    const int ca = 16 * w + 4 * g4 + r;
    obuf[bbase + (size_t)ca * Lcur + l] = (wv[r] - mean) * rstd * lng[ca] + lnb[ca];
  }
}

}  // namespace

// ---------------------------------------------------------------------------
extern "C" void kernel_launch(void* const* d_in, const int* in_sizes, int n_in,
                              void* d_out, int out_size, void* d_ws, size_t ws_size,
                              hipStream_t stream) {
  const float* x       = (const float*)d_in[0];
  const float* enc_W   = (const float*)d_in[1];
  const float* enc_b   = (const float*)d_in[2];
  const float* ln_g    = (const float*)d_in[3];
  const float* ln_b    = (const float*)d_in[4];
  const float* s4_D    = (const float*)d_in[5];
  const float* s4_ldt  = (const float*)d_in[6];
  const float* s4_C    = (const float*)d_in[7];
  const float* s4_logA = (const float*)d_in[8];
  const float* s4_Aim  = (const float*)d_in[9];
  const float* out_W   = (const float*)d_in[10];
  const float* out_b   = (const float*)d_in[11];
  const float* cd1_W   = (const float*)d_in[12];
  const float* cd1_b   = (const float*)d_in[13];
  const float* cd2_W   = (const float*)d_in[14];
  const float* cd2_b   = (const float*)d_in[15];
  const float* up_W    = (const float*)d_in[16];
  const float* up_b    = (const float*)d_in[17];
  const float* up1_W   = (const float*)d_in[18];
  float* outp = (float*)d_out;

  // ---- workspace arena (~127.2 MB, lifetime-overlapped) ----
  unsigned short* TtG = (unsigned short*)d_ws;
  const size_t ttg_shorts = (size_t)64 * NL_ * 70 * 512;      // 18.35M
  const size_t nWsz = (size_t)NM_ * NL_ * 2 * H_ * H_;        // 1.57M
  unsigned short* oWhi = TtG + ttg_shorts;
  unsigned short* oWlo = oWhi + nWsz;
  unsigned short* eWhi = oWlo + nWsz;        // 3*4096
  unsigned short* eWlo = eWhi + 3 * 4096;
  unsigned short* c1hi = eWlo + 3 * 4096;    // 3*4096
  unsigned short* c1lo = c1hi + 3 * 4096;
  unsigned short* c2hi = c1lo + 3 * 4096;    // 2*4096
  unsigned short* c2lo = c2hi + 2 * 4096;
  unsigned short* uphi = c2lo + 2 * 4096;    // 3*4096
  unsigned short* uplo = uphi + 3 * 4096;
  unsigned short* u1hi = uplo + 3 * 4096;    // 3*4096
  unsigned short* u1lo = u1hi + 3 * 4096;
  float* slotA = (float*)(u1lo + 3 * 4096);            // B*H*L0 floats
  float* slotB = slotA + (size_t)B_ * H_ * L0_;        // B*H*L0 floats

  // lifetime map (stream-serial, encoders all OUT-OF-PLACE):
  float* enc1  = slotA;                                // B*H*L1
  float* enc2  = slotA + (size_t)B_ * H_ * L1_;        // B*H*L2
  float* st0   = slotB;                                // B*H*L2 (model-0 state)
  float* scr0  = slotB + (size_t)B_ * H_ * L2_;        // B*H*L2
  float* dec21 = slotB;                                // B*H*L1 (st0/scr0 dead)
  float* st1   = slotA;                                // B*H*L1 (enc1/enc2 dead)
  float* scr1  = slotA + (size_t)B_ * H_ * L1_;        // B*H*L1
  float* dec32 = slotB;                                // B*H*L0 (dec21 dead)
  float* st2   = slotA;                                // B*H*L0 (st1/scr1 dead)
  float* scr2  = slotB;                                // B*H*L0 (dec32 dead post-enc)

  auto tt_layer = [&](int m, int i) -> const unsigned short* {
    const size_t NTm = (m == 0) ? 10 : (m == 1) ? 20 : 40;
    const size_t base = (m == 0) ? 0 : (m == 1) ? (size_t)64 * NL_ * 10
                                                : (size_t)64 * NL_ * 30;
    return TtG + (base + (size_t)i * 64 * NTm) * 512;
  };

  k_compute_K_tt<<<NM_ * NL_ * H_, 256, 0, stream>>>(s4_ldt, s4_C, s4_logA, s4_Aim, TtG);
  k_pack_w<<<((int)nWsz + 255) / 256, 256, 0, stream>>>(out_W, oWhi, oWlo, (int)nWsz);
  k_pack_w<<<48, 256, 0, stream>>>(enc_W, eWhi, eWlo, 3 * 4096);
  k_pack_gather<<<48, 256, 0, stream>>>(cd1_W, c1hi, c1lo, 3 * 4096, 192, 3);
  k_pack_gather<<<32, 256, 0, stream>>>(cd2_W, c2hi, c2lo, 2 * 4096, 128, 2);
  k_pack_gather<<<48, 256, 0, stream>>>(up_W, uphi, uplo, 3 * 4096, 3, 192);
  k_pack_gather<<<48, 256, 0, stream>>>(up1_W, u1hi, u1lo, 3 * 4096, 3, 192);

  // enc1 = conv_d1(x), enc2 = conv_d2(enc1)
  k_down_mfma<3, 1><<<B_ * (L1_ / 16), 256, 0, stream>>>(c1hi, c1lo, cd1_b, x, enc1,
                                                         L0_, L1_);
  k_down_mfma<2, 0><<<B_ * (L2_ / 16), 256, 0, stream>>>(c2hi, c2lo, cd2_b, enc1, enc2,
                                                         L1_, L2_);

  auto run_model = [&](int m, const float* input, float* state, float* scratch,
                       int Lm, float* final_out) {
    k_enc_mfma<<<B_ * (Lm / 16), 256, 0, stream>>>(eWhi + m * 4096, eWlo + m * 4096,
                                                   enc_b + (size_t)m * H_, input, state, Lm);
    for (int i = 0; i < NL_; ++i) {
      const unsigned short* Tl = tt_layer(m, i);
      const float* Dl = s4_D + ((size_t)m * NL_ + i) * H_;
      const int cgrid = (B_ / 16) * H_;
      if (Lm == L2_)
        k_conv_gelu_mfma<L2_><<<cgrid, 256, 0, stream>>>(state, Tl, Dl, scratch);
      else if (Lm == L1_)
        k_conv_gelu_mfma<L1_><<<cgrid, 256, 0, stream>>>(state, Tl, Dl, scratch);
      else
        k_conv_gelu_mfma<L0_><<<cgrid, 256, 0, stream>>>(state, Tl, Dl, scratch);
      float* obuf = (i == NL_ - 1 && final_out) ? final_out : state;
      const size_t wbase = ((size_t)m * NL_ + i) * 2 * H_ * H_;
      k_glu_ln_mfma<<<B_ * (Lm / 16), 256, 0, stream>>>(
          oWhi + wbase, oWlo + wbase,
          out_b + ((size_t)m * NL_ + i) * 2 * H_,
          ln_g + ((size_t)m * NL_ + i) * H_,
          ln_b + ((size_t)m * NL_ + i) * H_,
          scratch, state, obuf, Lm);
    }
  };

  // model 0 on enc2 (L=160): encoder out-of-place into st0
  run_model(0, enc2, st0, scr0, L2_, nullptr);
  // dec1 = enc2 + m0-out  (in place into enc2; elementwise, thread-local safe)
  k_add<<<(B_ * H_ * L2_) / 256, 256, 0, stream>>>(enc2, st0);
  // dec21 = convT(dec1, up_W) + up_b + enc1   -> slotB
  k_convT_mfma<<<B_ * (L2_ / 16), 256, 0, stream>>>(uphi, uplo, up_b, enc1, enc2, dec21,
                                                    L2_, 1);
  // model 1 on dec21 (L=320): encoder into st1 (slotA)
  run_model(1, dec21, st1, scr1, L1_, nullptr);
  // dec32 = convT(m1-out, up1_W) + enc0   -> slotB
  k_convT_mfma<<<B_ * (L1_ / 16), 256, 0, stream>>>(u1hi, u1lo, up_b, x, st1, dec32,
                                                    L1_, 0);
  // model 2 on dec32 (L=640): encoder into st2 (slotA); final layer -> d_out
  run_model(2, dec32, st2, scr2, L0_, outp);
}

// Round 10
// 1491.069 us; speedup vs baseline: 5.7250x; 1.2363x over previous
//
#include <hip/hip_runtime.h>
#include <math.h>

namespace {

constexpr int B_ = 256, H_ = 64, L0_ = 640, L1_ = 320, L2_ = 160;
constexpr int N2_ = 32, NL_ = 8, NM_ = 3;

typedef __attribute__((ext_vector_type(8))) short bf16x8;
typedef __attribute__((ext_vector_type(4))) float f32x4;

__device__ __forceinline__ unsigned short f2bf(float x) {
  unsigned int u = __float_as_uint(x);
  unsigned int r = (u + 0x7FFFu + ((u >> 16) & 1u)) >> 16;
  return (unsigned short)r;
}
__device__ __forceinline__ float bf2f(unsigned short h) {
  return __uint_as_float(((unsigned int)h) << 16);
}
__device__ __forceinline__ float gelu_f(float x) {
  // x * sigmoid(2t); overflow-safe (never inf/inf)
  const float t = 0.7978845608028654f * (x + 0.044715f * x * x * x);
  return x / (1.f + __expf(-2.f * t));
}
__device__ __forceinline__ void split8(const float* v, bf16x8& hi, bf16x8& lo) {
#pragma unroll
  for (int i = 0; i < 8; ++i) {
    const unsigned short hh = f2bf(v[i]);
    hi[i] = (short)hh;
    lo[i] = (short)f2bf(v[i] - bf2f(hh));
  }
}

// ---------------------------------------------------------------------------
// K + Toeplitz-fragment precompute. One block per (m, layer, h). Spill-free
// (8 poles/thread, 4-lane shfl reduce).
// ---------------------------------------------------------------------------
__global__ __launch_bounds__(256) void k_compute_K_tt(
    const float* __restrict__ log_dt, const float* __restrict__ C,
    const float* __restrict__ logA, const float* __restrict__ Aim,
    unsigned short* __restrict__ TtG) {
  const int bid = blockIdx.x;
  const int m = bid / (NL_ * H_);
  const int rest = bid % (NL_ * H_);
  const int li = rest / H_;
  const int h = rest % H_;
  const int ph = (m * NL_ + li) * H_ + h;
  __shared__ float qkr[7][N2_], qki[7][N2_];
  __shared__ float sCr[N2_], sCi[N2_];
  __shared__ float Ksh[L0_];
  const int tid = threadIdx.x;
  if (tid < N2_) {
    const int n = tid;
    const float dt = expf(log_dt[ph]);
    const float Are = -expf(logA[(size_t)ph * N2_ + n]);
    const float Ai = Aim[(size_t)ph * N2_ + n];
    const float ar = dt * Are, ai = dt * Ai;
    const float er = expf(ar);
    float sn, cs;
    sincosf(ai, &sn, &cs);  // small args: fast path
    const float mr = er * cs - 1.f;
    const float mi = er * sn;
    const float den = Are * Are + Ai * Ai;
    const float qr_ = (mr * Are + mi * Ai) / den;
    const float qi_ = (mi * Are - mr * Ai) / den;
    const float C0 = C[((size_t)ph * N2_ + n) * 2 + 0];
    const float C1 = C[((size_t)ph * N2_ + n) * 2 + 1];
    sCr[n] = C0 * qr_ - C1 * qi_;
    sCi[n] = C0 * qi_ + C1 * qr_;
    float qr = er * cs, qi = er * sn;  // q = exp(dtA)
#pragma unroll
    for (int k = 0; k < 7; ++k) {
      qkr[k][n] = qr;
      qki[k][n] = qi;
      const float nr = qr * qr - qi * qi;
      qi = 2.f * qr * qi;
      qr = nr;
    }
  }
  __syncthreads();
  const int Lm = (m == 0) ? L2_ : (m == 1) ? L1_ : L0_;
  const int NT = Lm / 16;

  const int l0 = tid >> 2;
  const int g = tid & 3;
  float pr[8], pi[8];
#pragma unroll
  for (int j = 0; j < 8; ++j) { pr[j] = 1.f; pi[j] = 0.f; }
#pragma unroll
  for (int k = 0; k < 6; ++k) {
    if ((l0 >> k) & 1) {
#pragma unroll
      for (int j = 0; j < 8; ++j) {
        const int n = g * 8 + j;
        const float qr = qkr[k][n], qi = qki[k][n];
        const float nr = pr[j] * qr - pi[j] * qi;
        pi[j] = pr[j] * qi + pi[j] * qr;
        pr[j] = nr;
      }
    }
  }
  for (int l = l0; l < Lm; l += 64) {
    float acc = 0.f;
#pragma unroll
    for (int j = 0; j < 8; ++j) {
      const int n = g * 8 + j;
      acc += sCr[n] * pr[j] - sCi[n] * pi[j];
    }
    acc += __shfl_xor(acc, 1);
    acc += __shfl_xor(acc, 2);
    if (g == 0) Ksh[l] = 2.f * acc;
    if (l + 64 < Lm) {
#pragma unroll
      for (int j = 0; j < 8; ++j) {
        const int n = g * 8 + j;
        const float qr = qkr[6][n], qi = qki[6][n];
        const float nr = pr[j] * qr - pi[j] * qi;
        pi[j] = pr[j] * qi + pi[j] * qr;
        pr[j] = nr;
      }
    }
  }
  __syncthreads();
  // Toeplitz fragment build -> global (bf16)
  const size_t base_tiles = ((m == 0) ? 0 : (m == 1) ? (size_t)64 * NL_ * 10
                                                     : (size_t)64 * NL_ * 30) +
                            (size_t)li * 64 * NT + (size_t)h * NT;
  unsigned short* Tg = TtG + base_tiles * 512;
  for (int w = tid; w < NT * 256; w += 256) {
    const int nd = w >> 8;
    const int rem = w & 255;
    const int lane = rem >> 2;
    const int pp = rem & 3;
    const int base = nd * 16 + (lane & 15) - ((lane >> 4) << 3) - 2 * pp;
    const float f0 = (base >= 0) ? Ksh[base] : 0.f;
    const float f1 = (base - 1 >= 0) ? Ksh[base - 1] : 0.f;
    *(unsigned int*)&Tg[nd * 512 + lane * 8 + 2 * pp] =
        (unsigned int)f2bf(f0) | ((unsigned int)f2bf(f1) << 16);
  }
}

// ---------------------------------------------------------------------------
// Pack f32 weights -> bf16 hi/lo (identity indexing).
// ---------------------------------------------------------------------------
__global__ void k_pack_w(const float* __restrict__ W, unsigned short* __restrict__ hi,
                         unsigned short* __restrict__ lo, int n) {
  const int p = blockIdx.x * 256 + threadIdx.x;
  if (p < n) {
    const float w = W[p];
    const unsigned short h = f2bf(w);
    hi[p] = h;
    lo[p] = f2bf(w - bf2f(h));
  }
}

// Gather-pack conv weights into P[k][o*64+i] hi/lo. src = o*so + i*si + k.
__global__ void k_pack_gather(const float* __restrict__ W, unsigned short* __restrict__ hi,
                              unsigned short* __restrict__ lo, int n, int so, int si) {
  const int idx = blockIdx.x * 256 + threadIdx.x;
  if (idx < n) {
    const int k = idx >> 12;
    const int rem = idx & 4095;
    const int o = rem >> 6;
    const int i = rem & 63;
    const float w = W[o * so + i * si + k];
    const unsigned short h = f2bf(w);
    hi[idx] = h;
    lo[idx] = f2bf(w - bf2f(h));
  }
}

// elementwise a += b
__global__ void k_add(float* a, const float* __restrict__ b) {
  const int p = blockIdx.x * 256 + threadIdx.x;
  a[p] += b[p];
}

// ---------------------------------------------------------------------------
// MFMA 1x1 encoder: out[b,o,l] = bias[o] + sum_i W[o,i] in[b,i,l].
// ---------------------------------------------------------------------------
__global__ __launch_bounds__(256) void k_enc_mfma(
    const unsigned short* __restrict__ Whi, const unsigned short* __restrict__ Wlo,
    const float* __restrict__ bvec, const float* __restrict__ in_,
    float* __restrict__ out, int Lcur) {
  const int tid = threadIdx.x;
  const int w = tid >> 6, lane = tid & 63, c15 = lane & 15, g4 = lane >> 4;
  const int tilesPerB = Lcur >> 4;
  const int b = blockIdx.x / tilesPerB;
  const int l = ((blockIdx.x % tilesPerB) << 4) + c15;
  const size_t bbase = (size_t)b * H_ * Lcur;
  f32x4 acc = {0.f, 0.f, 0.f, 0.f};
#pragma unroll
  for (int k0 = 0; k0 < 64; k0 += 32) {
    const int crow = k0 + 8 * g4;
    float xv[8];
#pragma unroll
    for (int i = 0; i < 8; ++i) xv[i] = in_[bbase + (size_t)(crow + i) * Lcur + l];
    bf16x8 xh, xl;
    split8(xv, xh, xl);
    const int ra = (16 * w + c15) * 64 + crow;
    const bf16x8 wh = *(const bf16x8*)(Whi + ra);
    const bf16x8 wl = *(const bf16x8*)(Wlo + ra);
    acc = __builtin_amdgcn_mfma_f32_16x16x32_bf16(wh, xh, acc, 0, 0, 0);
    acc = __builtin_amdgcn_mfma_f32_16x16x32_bf16(wh, xl, acc, 0, 0, 0);
    acc = __builtin_amdgcn_mfma_f32_16x16x32_bf16(wl, xh, acc, 0, 0, 0);
  }
#pragma unroll
  for (int r = 0; r < 4; ++r) {
    const int ca = 16 * w + 4 * g4 + r;
    out[bbase + (size_t)ca * Lcur + l] = acc[r] + bvec[ca];
  }
}

// ---------------------------------------------------------------------------
// MFMA strided down-conv (k=KW, s=2, pad=PAD).
// ---------------------------------------------------------------------------
template <int KW, int PAD>
__global__ __launch_bounds__(256) void k_down_mfma(
    const unsigned short* __restrict__ Phi, const unsigned short* __restrict__ Plo,
    const float* __restrict__ bias, const float* __restrict__ in_,
    float* __restrict__ out, int Lin, int Lout) {
  const int tid = threadIdx.x;
  const int w = tid >> 6, lane = tid & 63, c15 = lane & 15, g4 = lane >> 4;
  const int tilesPerB = Lout >> 4;
  const int b = blockIdx.x / tilesPerB;
  const int t = ((blockIdx.x % tilesPerB) << 4) + c15;
  const size_t ibase = (size_t)b * H_ * Lin;
  f32x4 acc = {0.f, 0.f, 0.f, 0.f};
#pragma unroll
  for (int k0 = 0; k0 < 64; k0 += 32) {
    const int crow = k0 + 8 * g4;
#pragma unroll
    for (int k = 0; k < KW; ++k) {
      const int c = 2 * t - PAD + k;
      const bool ok = (c >= 0) && (c < Lin);
      float xv[8];
#pragma unroll
      for (int i = 0; i < 8; ++i)
        xv[i] = ok ? in_[ibase + (size_t)(crow + i) * Lin + c] : 0.f;
      bf16x8 xh, xl;
      split8(xv, xh, xl);
      const int ra = (k << 12) + (16 * w + c15) * 64 + crow;
      const bf16x8 wh = *(const bf16x8*)(Phi + ra);
      const bf16x8 wl = *(const bf16x8*)(Plo + ra);
      acc = __builtin_amdgcn_mfma_f32_16x16x32_bf16(wh, xh, acc, 0, 0, 0);
      acc = __builtin_amdgcn_mfma_f32_16x16x32_bf16(wh, xl, acc, 0, 0, 0);
      acc = __builtin_amdgcn_mfma_f32_16x16x32_bf16(wl, xh, acc, 0, 0, 0);
    }
  }
  const size_t obase = (size_t)b * H_ * Lout;
#pragma unroll
  for (int r = 0; r < 4; ++r) {
    const int ca = 16 * w + 4 * g4 + r;
    out[obase + (size_t)ca * Lout + t] = acc[r] + bias[ca];
  }
}

// ---------------------------------------------------------------------------
// MFMA ConvTranspose1d k=3 s=2 p=1 op=1 (+bias? +skip). W prepacked [k][o,i].
// ---------------------------------------------------------------------------
__global__ __launch_bounds__(256) void k_convT_mfma(
    const unsigned short* __restrict__ Phi, const unsigned short* __restrict__ Plo,
    const float* __restrict__ bias, const float* __restrict__ skip,
    const float* __restrict__ in_, float* __restrict__ out, int Lin, int hasBias) {
  const int tid = threadIdx.x;
  const int w = tid >> 6, lane = tid & 63, c15 = lane & 15, g4 = lane >> 4;
  const int tilesPerB = Lin >> 4;
  const int b = blockIdx.x / tilesPerB;
  const int j = ((blockIdx.x % tilesPerB) << 4) + c15;
  const int Lout = 2 * Lin;
  const size_t ibase = (size_t)b * H_ * Lin;
  const bool nok = (j + 1) < Lin;
  f32x4 aE = {0.f, 0.f, 0.f, 0.f}, aO = {0.f, 0.f, 0.f, 0.f};
#pragma unroll
  for (int k0 = 0; k0 < 64; k0 += 32) {
    const int crow = k0 + 8 * g4;
    float xj[8], xn[8];
#pragma unroll
    for (int i = 0; i < 8; ++i) {
      const size_t rowo = ibase + (size_t)(crow + i) * Lin;
      xj[i] = in_[rowo + j];
      xn[i] = nok ? in_[rowo + j + 1] : 0.f;
    }
    bf16x8 jh, jl, nh, nl;
    split8(xj, jh, jl);
    split8(xn, nh, nl);
    const int rbase = (16 * w + c15) * 64 + crow;
    const bf16x8 w1h = *(const bf16x8*)(Phi + 4096 + rbase);
    const bf16x8 w1l = *(const bf16x8*)(Plo + 4096 + rbase);
    const bf16x8 w2h = *(const bf16x8*)(Phi + 8192 + rbase);
    const bf16x8 w2l = *(const bf16x8*)(Plo + 8192 + rbase);
    const bf16x8 w0h = *(const bf16x8*)(Phi + rbase);
    const bf16x8 w0l = *(const bf16x8*)(Plo + rbase);
    aE = __builtin_amdgcn_mfma_f32_16x16x32_bf16(w1h, jh, aE, 0, 0, 0);
    aE = __builtin_amdgcn_mfma_f32_16x16x32_bf16(w1h, jl, aE, 0, 0, 0);
    aE = __builtin_amdgcn_mfma_f32_16x16x32_bf16(w1l, jh, aE, 0, 0, 0);
    aO = __builtin_amdgcn_mfma_f32_16x16x32_bf16(w2h, jh, aO, 0, 0, 0);
    aO = __builtin_amdgcn_mfma_f32_16x16x32_bf16(w2h, jl, aO, 0, 0, 0);
    aO = __builtin_amdgcn_mfma_f32_16x16x32_bf16(w2l, jh, aO, 0, 0, 0);
    aO = __builtin_amdgcn_mfma_f32_16x16x32_bf16(w0h, nh, aO, 0, 0, 0);
    aO = __builtin_amdgcn_mfma_f32_16x16x32_bf16(w0h, nl, aO, 0, 0, 0);
    aO = __builtin_amdgcn_mfma_f32_16x16x32_bf16(w0l, nh, aO, 0, 0, 0);
  }
  const size_t obase = (size_t)b * H_ * Lout + 2 * j;
#pragma unroll
  for (int r = 0; r < 4; ++r) {
    const int ca = 16 * w + 4 * g4 + r;
    const float bb = hasBias ? bias[ca] : 0.f;
    const size_t pos = obase + (size_t)ca * Lout;
    out[pos] = aE[r] + bb + skip[pos];
    out[pos + 1] = aO[r] + bb + skip[pos + 1];
  }
}

// ---------------------------------------------------------------------------
// MFMA causal conv + D-skip + gelu (unchanged).
// ---------------------------------------------------------------------------
template <int L>
__global__ __launch_bounds__(256) void k_conv_gelu_mfma(
    const float* __restrict__ u, const unsigned short* __restrict__ Tt,
    const float* __restrict__ D, float* __restrict__ y) {
  constexpr int NT = L / 16;
  constexpr int NG = (NT + 3) / 4;
  constexpr int LP = L + 8;
  __shared__ unsigned short uhi[16 * LP];
  __shared__ unsigned short ulo[16 * LP];

  const int h = blockIdx.x & 63;
  const int b0 = (blockIdx.x >> 6) * 16;
  const int tid = threadIdx.x;

  constexpr int PR = L / 2;
  for (int wp = tid; wp < 16 * PR; wp += 256) {
    const int row = wp / PR, cp = wp % PR;
    const float2 v = *(const float2*)(u + ((size_t)(b0 + row) * H_ + h) * L + 2 * cp);
    const unsigned short h0 = f2bf(v.x), h1 = f2bf(v.y);
    const unsigned short q0 = f2bf(v.x - bf2f(h0)), q1 = f2bf(v.y - bf2f(h1));
    *(unsigned int*)&uhi[row * LP + 2 * cp] = (unsigned int)h0 | ((unsigned int)h1 << 16);
    *(unsigned int*)&ulo[row * LP + 2 * cp] = (unsigned int)q0 | ((unsigned int)q1 << 16);
  }
  __syncthreads();

  const int wv = tid >> 6;
  const int lane = tid & 63;
  const float Dh = D[h];
  const int lquad = lane & 15;
  const int lhi = lane >> 4;
  const unsigned short* Th = Tt + (size_t)h * NT * 512 + lane * 8;

  for (int g = wv; g < NG; g += 4) {
    const int t0 = g * 4;
    const int ntile = (NT - t0 < 4) ? (NT - t0) : 4;
    f32x4 acc[4];
#pragma unroll
    for (int t = 0; t < 4; ++t) acc[t] = (f32x4){0.f, 0.f, 0.f, 0.f};
    const int nsteps = ((t0 + ntile - 1) * 16) / 32 + 1;
    for (int s = 0; s < nsteps; ++s) {
      const int j0 = 32 * s;
      const int colbase = j0 + (lhi << 3);
      const bf16x8 ah = *(const bf16x8*)&uhi[lquad * LP + colbase];
      const bf16x8 al = *(const bf16x8*)&ulo[lquad * LP + colbase];
#pragma unroll
      for (int t = 0; t < 4; ++t) {
        if (t >= ntile) break;
        const int d0 = (t0 + t) * 16 - j0;
        if (d0 < 0) continue;
        const bf16x8 bf = *(const bf16x8*)(Th + (size_t)(d0 >> 4) * 512);
        acc[t] = __builtin_amdgcn_mfma_f32_16x16x32_bf16(ah, bf, acc[t], 0, 0, 0);
        acc[t] = __builtin_amdgcn_mfma_f32_16x16x32_bf16(al, bf, acc[t], 0, 0, 0);
      }
    }
#pragma unroll
    for (int t = 0; t < 4; ++t) {
      if (t >= ntile) break;
      const int l = (t0 + t) * 16 + lquad;
#pragma unroll
      for (int r = 0; r < 4; ++r) {
        const int row = (lhi << 2) + r;
        const float uv = bf2f(uhi[row * LP + l]) + bf2f(ulo[row * LP + l]);
        const float val = acc[t][r] + uv * Dh;
        y[((size_t)(b0 + row) * H_ + h) * L + l] = gelu_f(val);
      }
    }
  }
}

// ---------------------------------------------------------------------------
// MFMA out-proj (64->128) + GLU + residual + LayerNorm, v2.
// Block = (b, LT*16 l-tile), 4 waves. Y staged ONCE to LDS transposed bf16
// hi/lo (Yt[l][k], k-stride 72 -> 16B-aligned b128 frags); W frags hoisted
// to registers; wave w owns (a rows 16w.., g rows 64+16w..) for LT l-subtiles.
// Per-element math identical to v1. In-place safe (obuf may == xbuf).
// ---------------------------------------------------------------------------
template <int LT>
__global__ __launch_bounds__(256) void k_glu_ln_mfma2(
    const unsigned short* __restrict__ Whi, const unsigned short* __restrict__ Wlo,
    const float* __restrict__ ob, const float* __restrict__ lng,
    const float* __restrict__ lnb, const float* __restrict__ ybuf,
    const float* __restrict__ xbuf, float* __restrict__ obuf, int Lcur) {
  constexpr int LTILE = LT * 16;
  constexpr int KS = 72;  // padded k-stride (bf16): 144B rows, 16B-aligned
  __shared__ unsigned short Yhi[LTILE * KS];
  __shared__ unsigned short Ylo[LTILE * KS];
  __shared__ float red[4][LTILE][2];
  const int tid = threadIdx.x;
  const int w = tid >> 6, lane = tid & 63, c15 = lane & 15, g4 = lane >> 4;
  const int tilesPerB = Lcur / LTILE;
  const int b = blockIdx.x / tilesPerB;
  const int l0 = (blockIdx.x % tilesPerB) * LTILE;
  const size_t bbase = (size_t)b * H_ * Lcur;

  // stage Y -> LDS (transposed, bf16 hi/lo), each element converted once
  constexpr int NE = (64 * LTILE) / 256;
#pragma unroll
  for (int e = 0; e < NE; ++e) {
    const int idx = e * 256 + tid;
    const int k = idx / LTILE;
    const int l = idx % LTILE;
    const float v = ybuf[bbase + (size_t)k * Lcur + l0 + l];
    const unsigned short hh = f2bf(v);
    Yhi[l * KS + k] = hh;
    Ylo[l * KS + k] = f2bf(v - bf2f(hh));
  }

  // hoist W frags (independent of l)
  bf16x8 wah[2], wal[2], wgh[2], wgl[2];
#pragma unroll
  for (int q = 0; q < 2; ++q) {
    const int crow = q * 32 + 8 * g4;
    const int ra = (16 * w + c15) * 64 + crow;
    const int rg = ((64 + 16 * w) + c15) * 64 + crow;
    wah[q] = *(const bf16x8*)(Whi + ra);
    wal[q] = *(const bf16x8*)(Wlo + ra);
    wgh[q] = *(const bf16x8*)(Whi + rg);
    wgl[q] = *(const bf16x8*)(Wlo + rg);
  }
  __syncthreads();

  float wv[LT][4];
#pragma unroll
  for (int lt = 0; lt < LT; ++lt) {
    const int ll = lt * 16 + c15;
    f32x4 accA = {0.f, 0.f, 0.f, 0.f}, accG = {0.f, 0.f, 0.f, 0.f};
#pragma unroll
    for (int q = 0; q < 2; ++q) {
      const int crow = q * 32 + 8 * g4;
      const bf16x8 yh = *(const bf16x8*)&Yhi[ll * KS + crow];
      const bf16x8 yl = *(const bf16x8*)&Ylo[ll * KS + crow];
      accA = __builtin_amdgcn_mfma_f32_16x16x32_bf16(wah[q], yh, accA, 0, 0, 0);
      accA = __builtin_amdgcn_mfma_f32_16x16x32_bf16(wah[q], yl, accA, 0, 0, 0);
      accA = __builtin_amdgcn_mfma_f32_16x16x32_bf16(wal[q], yh, accA, 0, 0, 0);
      accG = __builtin_amdgcn_mfma_f32_16x16x32_bf16(wgh[q], yh, accG, 0, 0, 0);
      accG = __builtin_amdgcn_mfma_f32_16x16x32_bf16(wgh[q], yl, accG, 0, 0, 0);
      accG = __builtin_amdgcn_mfma_f32_16x16x32_bf16(wgl[q], yh, accG, 0, 0, 0);
    }
    float s1 = 0.f, s2 = 0.f;
#pragma unroll
    for (int r = 0; r < 4; ++r) {
      const int ca = 16 * w + 4 * g4 + r;
      const float a = accA[r] + ob[ca];
      const float g = accG[r] + ob[H_ + ca];
      const float z = a / (1.f + expf(-g));
      const float xv = xbuf[bbase + (size_t)ca * Lcur + l0 + ll];
      wv[lt][r] = z + xv;
      s1 += wv[lt][r];
      s2 += wv[lt][r] * wv[lt][r];
    }
    s1 += __shfl_xor(s1, 16);
    s2 += __shfl_xor(s2, 16);
    s1 += __shfl_xor(s1, 32);
    s2 += __shfl_xor(s2, 32);
    if (g4 == 0) {
      red[w][ll][0] = s1;
      red[w][ll][1] = s2;
    }
  }
  __syncthreads();
#pragma unroll
  for (int lt = 0; lt < LT; ++lt) {
    const int ll = lt * 16 + c15;
    float t1 = 0.f, t2 = 0.f;
#pragma unroll
    for (int q = 0; q < 4; ++q) {
      t1 += red[q][ll][0];
      t2 += red[q][ll][1];
    }
    const float mean = t1 * (1.f / 64.f);
    const float var = t2 * (1.f / 64.f) - mean * mean;
    const float rstd = rsqrtf(var + 1e-5f);
#pragma unroll
    for (int r = 0; r < 4; ++r) {
      const int ca = 16 * w + 4 * g4 + r;
      obuf[bbase + (size_t)ca * Lcur + l0 + ll] =
          (wv[lt][r] - mean) * rstd * lng[ca] + lnb[ca];
    }
  }
}

}  // namespace

// ---------------------------------------------------------------------------
extern "C" void kernel_launch(void* const* d_in, const int* in_sizes, int n_in,
                              void* d_out, int out_size, void* d_ws, size_t ws_size,
                              hipStream_t stream) {
  const float* x       = (const float*)d_in[0];
  const float* enc_W   = (const float*)d_in[1];
  const float* enc_b   = (const float*)d_in[2];
  const float* ln_g    = (const float*)d_in[3];
  const float* ln_b    = (const float*)d_in[4];
  const float* s4_D    = (const float*)d_in[5];
  const float* s4_ldt  = (const float*)d_in[6];
  const float* s4_C    = (const float*)d_in[7];
  const float* s4_logA = (const float*)d_in[8];
  const float* s4_Aim  = (const float*)d_in[9];
  const float* out_W   = (const float*)d_in[10];
  const float* out_b   = (const float*)d_in[11];
  const float* cd1_W   = (const float*)d_in[12];
  const float* cd1_b   = (const float*)d_in[13];
  const float* cd2_W   = (const float*)d_in[14];
  const float* cd2_b   = (const float*)d_in[15];
  const float* up_W    = (const float*)d_in[16];
  const float* up_b    = (const float*)d_in[17];
  const float* up1_W   = (const float*)d_in[18];
  float* outp = (float*)d_out;

  // ---- workspace arena (~127.2 MB, lifetime-overlapped) ----
  unsigned short* TtG = (unsigned short*)d_ws;
  const size_t ttg_shorts = (size_t)64 * NL_ * 70 * 512;      // 18.35M
  const size_t nWsz = (size_t)NM_ * NL_ * 2 * H_ * H_;        // 1.57M
  unsigned short* oWhi = TtG + ttg_shorts;
  unsigned short* oWlo = oWhi + nWsz;
  unsigned short* eWhi = oWlo + nWsz;
  unsigned short* eWlo = eWhi + 3 * 4096;
  unsigned short* c1hi = eWlo + 3 * 4096;
  unsigned short* c1lo = c1hi + 3 * 4096;
  unsigned short* c2hi = c1lo + 3 * 4096;
  unsigned short* c2lo = c2hi + 2 * 4096;
  unsigned short* uphi = c2lo + 2 * 4096;
  unsigned short* uplo = uphi + 3 * 4096;
  unsigned short* u1hi = uplo + 3 * 4096;
  unsigned short* u1lo = u1hi + 3 * 4096;
  float* slotA = (float*)(u1lo + 3 * 4096);            // B*H*L0 floats
  float* slotB = slotA + (size_t)B_ * H_ * L0_;        // B*H*L0 floats

  // lifetime map (stream-serial, encoders all OUT-OF-PLACE):
  float* enc1  = slotA;                                // B*H*L1
  float* enc2  = slotA + (size_t)B_ * H_ * L1_;        // B*H*L2
  float* st0   = slotB;                                // B*H*L2
  float* scr0  = slotB + (size_t)B_ * H_ * L2_;        // B*H*L2
  float* dec21 = slotB;                                // B*H*L1
  float* st1   = slotA;                                // B*H*L1
  float* scr1  = slotA + (size_t)B_ * H_ * L1_;        // B*H*L1
  float* dec32 = slotB;                                // B*H*L0
  float* st2   = slotA;                                // B*H*L0
  float* scr2  = slotB;                                // B*H*L0

  auto tt_layer = [&](int m, int i) -> const unsigned short* {
    const size_t NTm = (m == 0) ? 10 : (m == 1) ? 20 : 40;
    const size_t base = (m == 0) ? 0 : (m == 1) ? (size_t)64 * NL_ * 10
                                                : (size_t)64 * NL_ * 30;
    return TtG + (base + (size_t)i * 64 * NTm) * 512;
  };

  k_compute_K_tt<<<NM_ * NL_ * H_, 256, 0, stream>>>(s4_ldt, s4_C, s4_logA, s4_Aim, TtG);
  k_pack_w<<<((int)nWsz + 255) / 256, 256, 0, stream>>>(out_W, oWhi, oWlo, (int)nWsz);
  k_pack_w<<<48, 256, 0, stream>>>(enc_W, eWhi, eWlo, 3 * 4096);
  k_pack_gather<<<48, 256, 0, stream>>>(cd1_W, c1hi, c1lo, 3 * 4096, 192, 3);
  k_pack_gather<<<32, 256, 0, stream>>>(cd2_W, c2hi, c2lo, 2 * 4096, 128, 2);
  k_pack_gather<<<48, 256, 0, stream>>>(up_W, uphi, uplo, 3 * 4096, 3, 192);
  k_pack_gather<<<48, 256, 0, stream>>>(up1_W, u1hi, u1lo, 3 * 4096, 3, 192);

  // enc1 = conv_d1(x), enc2 = conv_d2(enc1)
  k_down_mfma<3, 1><<<B_ * (L1_ / 16), 256, 0, stream>>>(c1hi, c1lo, cd1_b, x, enc1,
                                                         L0_, L1_);
  k_down_mfma<2, 0><<<B_ * (L2_ / 16), 256, 0, stream>>>(c2hi, c2lo, cd2_b, enc1, enc2,
                                                         L1_, L2_);

  auto run_model = [&](int m, const float* input, float* state, float* scratch,
                       int Lm, float* final_out) {
    k_enc_mfma<<<B_ * (Lm / 16), 256, 0, stream>>>(eWhi + m * 4096, eWlo + m * 4096,
                                                   enc_b + (size_t)m * H_, input, state, Lm);
    for (int i = 0; i < NL_; ++i) {
      const unsigned short* Tl = tt_layer(m, i);
      const float* Dl = s4_D + ((size_t)m * NL_ + i) * H_;
      const int cgrid = (B_ / 16) * H_;
      if (Lm == L2_)
        k_conv_gelu_mfma<L2_><<<cgrid, 256, 0, stream>>>(state, Tl, Dl, scratch);
      else if (Lm == L1_)
        k_conv_gelu_mfma<L1_><<<cgrid, 256, 0, stream>>>(state, Tl, Dl, scratch);
      else
        k_conv_gelu_mfma<L0_><<<cgrid, 256, 0, stream>>>(state, Tl, Dl, scratch);
      float* obuf = (i == NL_ - 1 && final_out) ? final_out : state;
      const size_t wbase = ((size_t)m * NL_ + i) * 2 * H_ * H_;
      if (Lm == L2_)
        k_glu_ln_mfma2<2><<<B_ * (Lm / 32), 256, 0, stream>>>(
            oWhi + wbase, oWlo + wbase,
            out_b + ((size_t)m * NL_ + i) * 2 * H_,
            ln_g + ((size_t)m * NL_ + i) * H_,
            ln_b + ((size_t)m * NL_ + i) * H_,
            scratch, state, obuf, Lm);
      else
        k_glu_ln_mfma2<4><<<B_ * (Lm / 64), 256, 0, stream>>>(
            oWhi + wbase, oWlo + wbase,
            out_b + ((size_t)m * NL_ + i) * 2 * H_,
            ln_g + ((size_t)m * NL_ + i) * H_,
            ln_b + ((size_t)m * NL_ + i) * H_,
            scratch, state, obuf, Lm);
    }
  };

  // model 0 on enc2 (L=160): encoder out-of-place into st0
  run_model(0, enc2, st0, scr0, L2_, nullptr);
  // dec1 = enc2 + m0-out (elementwise in place)
  k_add<<<(B_ * H_ * L2_) / 256, 256, 0, stream>>>(enc2, st0);
  // dec21 = convT(dec1, up_W) + up_b + enc1 -> slotB
  k_convT_mfma<<<B_ * (L2_ / 16), 256, 0, stream>>>(uphi, uplo, up_b, enc1, enc2, dec21,
                                                    L2_, 1);
  // model 1 on dec21 (L=320): encoder into st1 (slotA)
  run_model(1, dec21, st1, scr1, L1_, nullptr);
  // dec32 = convT(m1-out, up1_W) + enc0 -> slotB
  k_convT_mfma<<<B_ * (L1_ / 16), 256, 0, stream>>>(u1hi, u1lo, up_b, x, st1, dec32,
                                                    L1_, 0);
  // model 2 on dec32 (L=640): encoder into st2 (slotA); final layer -> d_out
  run_model(2, dec32, st2, scr2, L0_, outp);
}

// Round 11
// 1245.485 us; speedup vs baseline: 6.8539x; 1.1972x over previous
//
#include <hip/hip_runtime.h>
#include <hip/hip_bf16.h>
#include <math.h>

namespace {

constexpr int B_ = 256, H_ = 64, L0_ = 640, L1_ = 320, L2_ = 160;
constexpr int N2_ = 32, NL_ = 8, NM_ = 3;

typedef __attribute__((ext_vector_type(8))) short bf16x8;
typedef __attribute__((ext_vector_type(4))) float f32x4;

__device__ __forceinline__ unsigned short f2bf(float x) {
  // hardware cvt (RTNE) — single VALU op, pairs fuse to v_cvt_pk_bf16_f32
  __hip_bfloat16 h = __float2bfloat16(x);
  unsigned short u;
  __builtin_memcpy(&u, &h, 2);
  return u;
}
__device__ __forceinline__ float bf2f(unsigned short h) {
  return __uint_as_float(((unsigned int)h) << 16);
}
__device__ __forceinline__ float gelu_f(float x) {
  // x * sigmoid(2t); overflow-safe (never inf/inf)
  const float t = 0.7978845608028654f * (x + 0.044715f * x * x * x);
  return x / (1.f + __expf(-2.f * t));
}
__device__ __forceinline__ void split8(const float* v, bf16x8& hi, bf16x8& lo) {
#pragma unroll
  for (int i = 0; i < 8; ++i) {
    const unsigned short hh = f2bf(v[i]);
    hi[i] = (short)hh;
    lo[i] = (short)f2bf(v[i] - bf2f(hh));
  }
}

// ---------------------------------------------------------------------------
// K + Toeplitz-fragment precompute. One block per (m, layer, h). Spill-free
// (8 poles/thread, 4-lane shfl reduce).
// ---------------------------------------------------------------------------
__global__ __launch_bounds__(256) void k_compute_K_tt(
    const float* __restrict__ log_dt, const float* __restrict__ C,
    const float* __restrict__ logA, const float* __restrict__ Aim,
    unsigned short* __restrict__ TtG) {
  const int bid = blockIdx.x;
  const int m = bid / (NL_ * H_);
  const int rest = bid % (NL_ * H_);
  const int li = rest / H_;
  const int h = rest % H_;
  const int ph = (m * NL_ + li) * H_ + h;
  __shared__ float qkr[7][N2_], qki[7][N2_];
  __shared__ float sCr[N2_], sCi[N2_];
  __shared__ float Ksh[L0_];
  const int tid = threadIdx.x;
  if (tid < N2_) {
    const int n = tid;
    const float dt = expf(log_dt[ph]);
    const float Are = -expf(logA[(size_t)ph * N2_ + n]);
    const float Ai = Aim[(size_t)ph * N2_ + n];
    const float ar = dt * Are, ai = dt * Ai;
    const float er = expf(ar);
    float sn, cs;
    sincosf(ai, &sn, &cs);  // small args: fast path
    const float mr = er * cs - 1.f;
    const float mi = er * sn;
    const float den = Are * Are + Ai * Ai;
    const float qr_ = (mr * Are + mi * Ai) / den;
    const float qi_ = (mi * Are - mr * Ai) / den;
    const float C0 = C[((size_t)ph * N2_ + n) * 2 + 0];
    const float C1 = C[((size_t)ph * N2_ + n) * 2 + 1];
    sCr[n] = C0 * qr_ - C1 * qi_;
    sCi[n] = C0 * qi_ + C1 * qr_;
    float qr = er * cs, qi = er * sn;  // q = exp(dtA)
#pragma unroll
    for (int k = 0; k < 7; ++k) {
      qkr[k][n] = qr;
      qki[k][n] = qi;
      const float nr = qr * qr - qi * qi;
      qi = 2.f * qr * qi;
      qr = nr;
    }
  }
  __syncthreads();
  const int Lm = (m == 0) ? L2_ : (m == 1) ? L1_ : L0_;
  const int NT = Lm / 16;

  const int l0 = tid >> 2;
  const int g = tid & 3;
  float pr[8], pi[8];
#pragma unroll
  for (int j = 0; j < 8; ++j) { pr[j] = 1.f; pi[j] = 0.f; }
#pragma unroll
  for (int k = 0; k < 6; ++k) {
    if ((l0 >> k) & 1) {
#pragma unroll
      for (int j = 0; j < 8; ++j) {
        const int n = g * 8 + j;
        const float qr = qkr[k][n], qi = qki[k][n];
        const float nr = pr[j] * qr - pi[j] * qi;
        pi[j] = pr[j] * qi + pi[j] * qr;
        pr[j] = nr;
      }
    }
  }
  for (int l = l0; l < Lm; l += 64) {
    float acc = 0.f;
#pragma unroll
    for (int j = 0; j < 8; ++j) {
      const int n = g * 8 + j;
      acc += sCr[n] * pr[j] - sCi[n] * pi[j];
    }
    acc += __shfl_xor(acc, 1);
    acc += __shfl_xor(acc, 2);
    if (g == 0) Ksh[l] = 2.f * acc;
    if (l + 64 < Lm) {
#pragma unroll
      for (int j = 0; j < 8; ++j) {
        const int n = g * 8 + j;
        const float qr = qkr[6][n], qi = qki[6][n];
        const float nr = pr[j] * qr - pi[j] * qi;
        pi[j] = pr[j] * qi + pi[j] * qr;
        pr[j] = nr;
      }
    }
  }
  __syncthreads();
  // Toeplitz fragment build -> global (bf16)
  const size_t base_tiles = ((m == 0) ? 0 : (m == 1) ? (size_t)64 * NL_ * 10
                                                     : (size_t)64 * NL_ * 30) +
                            (size_t)li * 64 * NT + (size_t)h * NT;
  unsigned short* Tg = TtG + base_tiles * 512;
  for (int w = tid; w < NT * 256; w += 256) {
    const int nd = w >> 8;
    const int rem = w & 255;
    const int lane = rem >> 2;
    const int pp = rem & 3;
    const int base = nd * 16 + (lane & 15) - ((lane >> 4) << 3) - 2 * pp;
    const float f0 = (base >= 0) ? Ksh[base] : 0.f;
    const float f1 = (base - 1 >= 0) ? Ksh[base - 1] : 0.f;
    *(unsigned int*)&Tg[nd * 512 + lane * 8 + 2 * pp] =
        (unsigned int)f2bf(f0) | ((unsigned int)f2bf(f1) << 16);
  }
}

// ---------------------------------------------------------------------------
// Pack f32 weights -> bf16 hi/lo (identity indexing).
// ---------------------------------------------------------------------------
__global__ void k_pack_w(const float* __restrict__ W, unsigned short* __restrict__ hi,
                         unsigned short* __restrict__ lo, int n) {
  const int p = blockIdx.x * 256 + threadIdx.x;
  if (p < n) {
    const float w = W[p];
    const unsigned short h = f2bf(w);
    hi[p] = h;
    lo[p] = f2bf(w - bf2f(h));
  }
}

// Gather-pack conv weights into P[k][o*64+i] hi/lo. src = o*so + i*si + k.
__global__ void k_pack_gather(const float* __restrict__ W, unsigned short* __restrict__ hi,
                              unsigned short* __restrict__ lo, int n, int so, int si) {
  const int idx = blockIdx.x * 256 + threadIdx.x;
  if (idx < n) {
    const int k = idx >> 12;
    const int rem = idx & 4095;
    const int o = rem >> 6;
    const int i = rem & 63;
    const float w = W[o * so + i * si + k];
    const unsigned short h = f2bf(w);
    hi[idx] = h;
    lo[idx] = f2bf(w - bf2f(h));
  }
}

// elementwise a += b
__global__ void k_add(float* a, const float* __restrict__ b) {
  const int p = blockIdx.x * 256 + threadIdx.x;
  a[p] += b[p];
}

// ---------------------------------------------------------------------------
// MFMA 1x1 encoder: out[b,o,l] = bias[o] + sum_i W[o,i] in[b,i,l].
// ---------------------------------------------------------------------------
__global__ __launch_bounds__(256) void k_enc_mfma(
    const unsigned short* __restrict__ Whi, const unsigned short* __restrict__ Wlo,
    const float* __restrict__ bvec, const float* __restrict__ in_,
    float* __restrict__ out, int Lcur) {
  const int tid = threadIdx.x;
  const int w = tid >> 6, lane = tid & 63, c15 = lane & 15, g4 = lane >> 4;
  const int tilesPerB = Lcur >> 4;
  const int b = blockIdx.x / tilesPerB;
  const int l = ((blockIdx.x % tilesPerB) << 4) + c15;
  const size_t bbase = (size_t)b * H_ * Lcur;
  f32x4 acc = {0.f, 0.f, 0.f, 0.f};
#pragma unroll
  for (int k0 = 0; k0 < 64; k0 += 32) {
    const int crow = k0 + 8 * g4;
    float xv[8];
#pragma unroll
    for (int i = 0; i < 8; ++i) xv[i] = in_[bbase + (size_t)(crow + i) * Lcur + l];
    bf16x8 xh, xl;
    split8(xv, xh, xl);
    const int ra = (16 * w + c15) * 64 + crow;
    const bf16x8 wh = *(const bf16x8*)(Whi + ra);
    const bf16x8 wl = *(const bf16x8*)(Wlo + ra);
    acc = __builtin_amdgcn_mfma_f32_16x16x32_bf16(wh, xh, acc, 0, 0, 0);
    acc = __builtin_amdgcn_mfma_f32_16x16x32_bf16(wh, xl, acc, 0, 0, 0);
    acc = __builtin_amdgcn_mfma_f32_16x16x32_bf16(wl, xh, acc, 0, 0, 0);
  }
#pragma unroll
  for (int r = 0; r < 4; ++r) {
    const int ca = 16 * w + 4 * g4 + r;
    out[bbase + (size_t)ca * Lcur + l] = acc[r] + bvec[ca];
  }
}

// ---------------------------------------------------------------------------
// MFMA strided down-conv (k=KW, s=2, pad=PAD).
// ---------------------------------------------------------------------------
template <int KW, int PAD>
__global__ __launch_bounds__(256) void k_down_mfma(
    const unsigned short* __restrict__ Phi, const unsigned short* __restrict__ Plo,
    const float* __restrict__ bias, const float* __restrict__ in_,
    float* __restrict__ out, int Lin, int Lout) {
  const int tid = threadIdx.x;
  const int w = tid >> 6, lane = tid & 63, c15 = lane & 15, g4 = lane >> 4;
  const int tilesPerB = Lout >> 4;
  const int b = blockIdx.x / tilesPerB;
  const int t = ((blockIdx.x % tilesPerB) << 4) + c15;
  const size_t ibase = (size_t)b * H_ * Lin;
  f32x4 acc = {0.f, 0.f, 0.f, 0.f};
#pragma unroll
  for (int k0 = 0; k0 < 64; k0 += 32) {
    const int crow = k0 + 8 * g4;
#pragma unroll
    for (int k = 0; k < KW; ++k) {
      const int c = 2 * t - PAD + k;
      const bool ok = (c >= 0) && (c < Lin);
      float xv[8];
#pragma unroll
      for (int i = 0; i < 8; ++i)
        xv[i] = ok ? in_[ibase + (size_t)(crow + i) * Lin + c] : 0.f;
      bf16x8 xh, xl;
      split8(xv, xh, xl);
      const int ra = (k << 12) + (16 * w + c15) * 64 + crow;
      const bf16x8 wh = *(const bf16x8*)(Phi + ra);
      const bf16x8 wl = *(const bf16x8*)(Plo + ra);
      acc = __builtin_amdgcn_mfma_f32_16x16x32_bf16(wh, xh, acc, 0, 0, 0);
      acc = __builtin_amdgcn_mfma_f32_16x16x32_bf16(wh, xl, acc, 0, 0, 0);
      acc = __builtin_amdgcn_mfma_f32_16x16x32_bf16(wl, xh, acc, 0, 0, 0);
    }
  }
  const size_t obase = (size_t)b * H_ * Lout;
#pragma unroll
  for (int r = 0; r < 4; ++r) {
    const int ca = 16 * w + 4 * g4 + r;
    out[obase + (size_t)ca * Lout + t] = acc[r] + bias[ca];
  }
}

// ---------------------------------------------------------------------------
// MFMA ConvTranspose1d k=3 s=2 p=1 op=1 (+bias? +skip). W prepacked [k][o,i].
// ---------------------------------------------------------------------------
__global__ __launch_bounds__(256) void k_convT_mfma(
    const unsigned short* __restrict__ Phi, const unsigned short* __restrict__ Plo,
    const float* __restrict__ bias, const float* __restrict__ skip,
    const float* __restrict__ in_, float* __restrict__ out, int Lin, int hasBias) {
  const int tid = threadIdx.x;
  const int w = tid >> 6, lane = tid & 63, c15 = lane & 15, g4 = lane >> 4;
  const int tilesPerB = Lin >> 4;
  const int b = blockIdx.x / tilesPerB;
  const int j = ((blockIdx.x % tilesPerB) << 4) + c15;
  const int Lout = 2 * Lin;
  const size_t ibase = (size_t)b * H_ * Lin;
  const bool nok = (j + 1) < Lin;
  f32x4 aE = {0.f, 0.f, 0.f, 0.f}, aO = {0.f, 0.f, 0.f, 0.f};
#pragma unroll
  for (int k0 = 0; k0 < 64; k0 += 32) {
    const int crow = k0 + 8 * g4;
    float xj[8], xn[8];
#pragma unroll
    for (int i = 0; i < 8; ++i) {
      const size_t rowo = ibase + (size_t)(crow + i) * Lin;
      xj[i] = in_[rowo + j];
      xn[i] = nok ? in_[rowo + j + 1] : 0.f;
    }
    bf16x8 jh, jl, nh, nl;
    split8(xj, jh, jl);
    split8(xn, nh, nl);
    const int rbase = (16 * w + c15) * 64 + crow;
    const bf16x8 w1h = *(const bf16x8*)(Phi + 4096 + rbase);
    const bf16x8 w1l = *(const bf16x8*)(Plo + 4096 + rbase);
    const bf16x8 w2h = *(const bf16x8*)(Phi + 8192 + rbase);
    const bf16x8 w2l = *(const bf16x8*)(Plo + 8192 + rbase);
    const bf16x8 w0h = *(const bf16x8*)(Phi + rbase);
    const bf16x8 w0l = *(const bf16x8*)(Plo + rbase);
    aE = __builtin_amdgcn_mfma_f32_16x16x32_bf16(w1h, jh, aE, 0, 0, 0);
    aE = __builtin_amdgcn_mfma_f32_16x16x32_bf16(w1h, jl, aE, 0, 0, 0);
    aE = __builtin_amdgcn_mfma_f32_16x16x32_bf16(w1l, jh, aE, 0, 0, 0);
    aO = __builtin_amdgcn_mfma_f32_16x16x32_bf16(w2h, jh, aO, 0, 0, 0);
    aO = __builtin_amdgcn_mfma_f32_16x16x32_bf16(w2h, jl, aO, 0, 0, 0);
    aO = __builtin_amdgcn_mfma_f32_16x16x32_bf16(w2l, jh, aO, 0, 0, 0);
    aO = __builtin_amdgcn_mfma_f32_16x16x32_bf16(w0h, nh, aO, 0, 0, 0);
    aO = __builtin_amdgcn_mfma_f32_16x16x32_bf16(w0h, nl, aO, 0, 0, 0);
    aO = __builtin_amdgcn_mfma_f32_16x16x32_bf16(w0l, nh, aO, 0, 0, 0);
  }
  const size_t obase = (size_t)b * H_ * Lout + 2 * j;
#pragma unroll
  for (int r = 0; r < 4; ++r) {
    const int ca = 16 * w + 4 * g4 + r;
    const float bb = hasBias ? bias[ca] : 0.f;
    const size_t pos = obase + (size_t)ca * Lout;
    out[pos] = aE[r] + bb + skip[pos];
    out[pos + 1] = aO[r] + bb + skip[pos + 1];
  }
}

// ---------------------------------------------------------------------------
// MFMA causal conv + D-skip + gelu, v3: single-bf16 u (no lo path).
// K is bf16 anyway (2^-8 relative) so u hi/lo only polished below K's floor;
// dropping it halves LDS (20.7KB -> 7 blk/CU, no grid tail), halves MFMA,
// halves staging conversions. Staging: float4 + hw cvt, shift-only addressing.
// ---------------------------------------------------------------------------
template <int L>
__global__ __launch_bounds__(256) void k_conv_gelu_mfma(
    const float* __restrict__ u, const unsigned short* __restrict__ Tt,
    const float* __restrict__ D, float* __restrict__ y) {
  constexpr int NT = L / 16;
  constexpr int NG = (NT + 3) / 4;
  constexpr int LP = L + 8;
  __shared__ unsigned short uhi[16 * LP];

  const int h = blockIdx.x & 63;
  const int b0 = (blockIdx.x >> 6) * 16;
  const int tid = threadIdx.x;

  // stage u (bf16): row = tid>>4 (16 rows), 16 threads per row, float4 loads
  {
    const int row = tid >> 4;
    const int ct = tid & 15;
    const float4* src = (const float4*)(u + ((size_t)(b0 + row) * H_ + h) * L);
#pragma unroll
    for (int c4 = ct; c4 < L / 4; c4 += 16) {
      const float4 v = src[c4];
      const unsigned int p0 = (unsigned int)f2bf(v.x) | ((unsigned int)f2bf(v.y) << 16);
      const unsigned int p1 = (unsigned int)f2bf(v.z) | ((unsigned int)f2bf(v.w) << 16);
      unsigned int* dst = (unsigned int*)&uhi[row * LP + 4 * c4];
      dst[0] = p0;
      dst[1] = p1;
    }
  }
  __syncthreads();

  const int wv = tid >> 6;
  const int lane = tid & 63;
  const float Dh = D[h];
  const int lquad = lane & 15;
  const int lhi = lane >> 4;
  const unsigned short* Th = Tt + (size_t)h * NT * 512 + lane * 8;

  for (int g = wv; g < NG; g += 4) {
    const int t0 = g * 4;
    const int ntile = (NT - t0 < 4) ? (NT - t0) : 4;
    f32x4 acc[4];
#pragma unroll
    for (int t = 0; t < 4; ++t) acc[t] = (f32x4){0.f, 0.f, 0.f, 0.f};
    const int nsteps = ((t0 + ntile - 1) * 16) / 32 + 1;
    for (int s = 0; s < nsteps; ++s) {
      const int j0 = 32 * s;
      const int colbase = j0 + (lhi << 3);
      const bf16x8 ah = *(const bf16x8*)&uhi[lquad * LP + colbase];
#pragma unroll
      for (int t = 0; t < 4; ++t) {
        if (t >= ntile) break;
        const int d0 = (t0 + t) * 16 - j0;
        if (d0 < 0) continue;  // causal: wave-uniform skip
        const bf16x8 bf = *(const bf16x8*)(Th + (size_t)(d0 >> 4) * 512);
        acc[t] = __builtin_amdgcn_mfma_f32_16x16x32_bf16(ah, bf, acc[t], 0, 0, 0);
      }
    }
#pragma unroll
    for (int t = 0; t < 4; ++t) {
      if (t >= ntile) break;
      const int l = (t0 + t) * 16 + lquad;
#pragma unroll
      for (int r = 0; r < 4; ++r) {
        const int row = (lhi << 2) + r;
        const float uv = bf2f(uhi[row * LP + l]);
        const float val = acc[t][r] + uv * Dh;
        y[((size_t)(b0 + row) * H_ + h) * L + l] = gelu_f(val);
      }
    }
  }
}

// ---------------------------------------------------------------------------
// MFMA out-proj (64->128) + GLU + residual + LayerNorm, v2 (unchanged).
// ---------------------------------------------------------------------------
template <int LT>
__global__ __launch_bounds__(256) void k_glu_ln_mfma2(
    const unsigned short* __restrict__ Whi, const unsigned short* __restrict__ Wlo,
    const float* __restrict__ ob, const float* __restrict__ lng,
    const float* __restrict__ lnb, const float* __restrict__ ybuf,
    const float* __restrict__ xbuf, float* __restrict__ obuf, int Lcur) {
  constexpr int LTILE = LT * 16;
  constexpr int KS = 72;  // padded k-stride (bf16): 144B rows, 16B-aligned
  __shared__ unsigned short Yhi[LTILE * KS];
  __shared__ unsigned short Ylo[LTILE * KS];
  __shared__ float red[4][LTILE][2];
  const int tid = threadIdx.x;
  const int w = tid >> 6, lane = tid & 63, c15 = lane & 15, g4 = lane >> 4;
  const int tilesPerB = Lcur / LTILE;
  const int b = blockIdx.x / tilesPerB;
  const int l0 = (blockIdx.x % tilesPerB) * LTILE;
  const size_t bbase = (size_t)b * H_ * Lcur;

  // stage Y -> LDS (transposed, bf16 hi/lo), each element converted once
  constexpr int NE = (64 * LTILE) / 256;
#pragma unroll
  for (int e = 0; e < NE; ++e) {
    const int idx = e * 256 + tid;
    const int k = idx / LTILE;
    const int l = idx % LTILE;
    const float v = ybuf[bbase + (size_t)k * Lcur + l0 + l];
    const unsigned short hh = f2bf(v);
    Yhi[l * KS + k] = hh;
    Ylo[l * KS + k] = f2bf(v - bf2f(hh));
  }

  // hoist W frags (independent of l)
  bf16x8 wah[2], wal[2], wgh[2], wgl[2];
#pragma unroll
  for (int q = 0; q < 2; ++q) {
    const int crow = q * 32 + 8 * g4;
    const int ra = (16 * w + c15) * 64 + crow;
    const int rg = ((64 + 16 * w) + c15) * 64 + crow;
    wah[q] = *(const bf16x8*)(Whi + ra);
    wal[q] = *(const bf16x8*)(Wlo + ra);
    wgh[q] = *(const bf16x8*)(Whi + rg);
    wgl[q] = *(const bf16x8*)(Wlo + rg);
  }
  __syncthreads();

  float wv[LT][4];
#pragma unroll
  for (int lt = 0; lt < LT; ++lt) {
    const int ll = lt * 16 + c15;
    f32x4 accA = {0.f, 0.f, 0.f, 0.f}, accG = {0.f, 0.f, 0.f, 0.f};
#pragma unroll
    for (int q = 0; q < 2; ++q) {
      const int crow = q * 32 + 8 * g4;
      const bf16x8 yh = *(const bf16x8*)&Yhi[ll * KS + crow];
      const bf16x8 yl = *(const bf16x8*)&Ylo[ll * KS + crow];
      accA = __builtin_amdgcn_mfma_f32_16x16x32_bf16(wah[q], yh, accA, 0, 0, 0);
      accA = __builtin_amdgcn_mfma_f32_16x16x32_bf16(wah[q], yl, accA, 0, 0, 0);
      accA = __builtin_amdgcn_mfma_f32_16x16x32_bf16(wal[q], yh, accA, 0, 0, 0);
      accG = __builtin_amdgcn_mfma_f32_16x16x32_bf16(wgh[q], yh, accG, 0, 0, 0);
      accG = __builtin_amdgcn_mfma_f32_16x16x32_bf16(wgh[q], yl, accG, 0, 0, 0);
      accG = __builtin_amdgcn_mfma_f32_16x16x32_bf16(wgl[q], yh, accG, 0, 0, 0);
    }
    float s1 = 0.f, s2 = 0.f;
#pragma unroll
    for (int r = 0; r < 4; ++r) {
      const int ca = 16 * w + 4 * g4 + r;
      const float a = accA[r] + ob[ca];
      const float g = accG[r] + ob[H_ + ca];
      const float z = a / (1.f + expf(-g));
      const float xv = xbuf[bbase + (size_t)ca * Lcur + l0 + ll];
      wv[lt][r] = z + xv;
      s1 += wv[lt][r];
      s2 += wv[lt][r] * wv[lt][r];
    }
    s1 += __shfl_xor(s1, 16);
    s2 += __shfl_xor(s2, 16);
    s1 += __shfl_xor(s1, 32);
    s2 += __shfl_xor(s2, 32);
    if (g4 == 0) {
      red[w][ll][0] = s1;
      red[w][ll][1] = s2;
    }
  }
  __syncthreads();
#pragma unroll
  for (int lt = 0; lt < LT; ++lt) {
    const int ll = lt * 16 + c15;
    float t1 = 0.f, t2 = 0.f;
#pragma unroll
    for (int q = 0; q < 4; ++q) {
      t1 += red[q][ll][0];
      t2 += red[q][ll][1];
    }
    const float mean = t1 * (1.f / 64.f);
    const float var = t2 * (1.f / 64.f) - mean * mean;
    const float rstd = rsqrtf(var + 1e-5f);
#pragma unroll
    for (int r = 0; r < 4; ++r) {
      const int ca = 16 * w + 4 * g4 + r;
      obuf[bbase + (size_t)ca * Lcur + l0 + ll] =
          (wv[lt][r] - mean) * rstd * lng[ca] + lnb[ca];
    }
  }
}

}  // namespace

// ---------------------------------------------------------------------------
extern "C" void kernel_launch(void* const* d_in, const int* in_sizes, int n_in,
                              void* d_out, int out_size, void* d_ws, size_t ws_size,
                              hipStream_t stream) {
  const float* x       = (const float*)d_in[0];
  const float* enc_W   = (const float*)d_in[1];
  const float* enc_b   = (const float*)d_in[2];
  const float* ln_g    = (const float*)d_in[3];
  const float* ln_b    = (const float*)d_in[4];
  const float* s4_D    = (const float*)d_in[5];
  const float* s4_ldt  = (const float*)d_in[6];
  const float* s4_C    = (const float*)d_in[7];
  const float* s4_logA = (const float*)d_in[8];
  const float* s4_Aim  = (const float*)d_in[9];
  const float* out_W   = (const float*)d_in[10];
  const float* out_b   = (const float*)d_in[11];
  const float* cd1_W   = (const float*)d_in[12];
  const float* cd1_b   = (const float*)d_in[13];
  const float* cd2_W   = (const float*)d_in[14];
  const float* cd2_b   = (const float*)d_in[15];
  const float* up_W    = (const float*)d_in[16];
  const float* up_b    = (const float*)d_in[17];
  const float* up1_W   = (const float*)d_in[18];
  float* outp = (float*)d_out;

  // ---- workspace arena (~127.2 MB, lifetime-overlapped) ----
  unsigned short* TtG = (unsigned short*)d_ws;
  const size_t ttg_shorts = (size_t)64 * NL_ * 70 * 512;      // 18.35M
  const size_t nWsz = (size_t)NM_ * NL_ * 2 * H_ * H_;        // 1.57M
  unsigned short* oWhi = TtG + ttg_shorts;
  unsigned short* oWlo = oWhi + nWsz;
  unsigned short* eWhi = oWlo + nWsz;
  unsigned short* eWlo = eWhi + 3 * 4096;
  unsigned short* c1hi = eWlo + 3 * 4096;
  unsigned short* c1lo = c1hi + 3 * 4096;
  unsigned short* c2hi = c1lo + 3 * 4096;
  unsigned short* c2lo = c2hi + 2 * 4096;
  unsigned short* uphi = c2lo + 2 * 4096;
  unsigned short* uplo = uphi + 3 * 4096;
  unsigned short* u1hi = uplo + 3 * 4096;
  unsigned short* u1lo = u1hi + 3 * 4096;
  float* slotA = (float*)(u1lo + 3 * 4096);            // B*H*L0 floats
  float* slotB = slotA + (size_t)B_ * H_ * L0_;        // B*H*L0 floats

  // lifetime map (stream-serial, encoders all OUT-OF-PLACE):
  float* enc1  = slotA;                                // B*H*L1
  float* enc2  = slotA + (size_t)B_ * H_ * L1_;        // B*H*L2
  float* st0   = slotB;                                // B*H*L2
  float* scr0  = slotB + (size_t)B_ * H_ * L2_;        // B*H*L2
  float* dec21 = slotB;                                // B*H*L1
  float* st1   = slotA;                                // B*H*L1
  float* scr1  = slotA + (size_t)B_ * H_ * L1_;        // B*H*L1
  float* dec32 = slotB;                                // B*H*L0
  float* st2   = slotA;                                // B*H*L0
  float* scr2  = slotB;                                // B*H*L0

  auto tt_layer = [&](int m, int i) -> const unsigned short* {
    const size_t NTm = (m == 0) ? 10 : (m == 1) ? 20 : 40;
    const size_t base = (m == 0) ? 0 : (m == 1) ? (size_t)64 * NL_ * 10
                                                : (size_t)64 * NL_ * 30;
    return TtG + (base + (size_t)i * 64 * NTm) * 512;
  };

  k_compute_K_tt<<<NM_ * NL_ * H_, 256, 0, stream>>>(s4_ldt, s4_C, s4_logA, s4_Aim, TtG);
  k_pack_w<<<((int)nWsz + 255) / 256, 256, 0, stream>>>(out_W, oWhi, oWlo, (int)nWsz);
  k_pack_w<<<48, 256, 0, stream>>>(enc_W, eWhi, eWlo, 3 * 4096);
  k_pack_gather<<<48, 256, 0, stream>>>(cd1_W, c1hi, c1lo, 3 * 4096, 192, 3);
  k_pack_gather<<<32, 256, 0, stream>>>(cd2_W, c2hi, c2lo, 2 * 4096, 128, 2);
  k_pack_gather<<<48, 256, 0, stream>>>(up_W, uphi, uplo, 3 * 4096, 3, 192);
  k_pack_gather<<<48, 256, 0, stream>>>(up1_W, u1hi, u1lo, 3 * 4096, 3, 192);

  // enc1 = conv_d1(x), enc2 = conv_d2(enc1)
  k_down_mfma<3, 1><<<B_ * (L1_ / 16), 256, 0, stream>>>(c1hi, c1lo, cd1_b, x, enc1,
                                                         L0_, L1_);
  k_down_mfma<2, 0><<<B_ * (L2_ / 16), 256, 0, stream>>>(c2hi, c2lo, cd2_b, enc1, enc2,
                                                         L1_, L2_);

  auto run_model = [&](int m, const float* input, float* state, float* scratch,
                       int Lm, float* final_out) {
    k_enc_mfma<<<B_ * (Lm / 16), 256, 0, stream>>>(eWhi + m * 4096, eWlo + m * 4096,
                                                   enc_b + (size_t)m * H_, input, state, Lm);
    for (int i = 0; i < NL_; ++i) {
      const unsigned short* Tl = tt_layer(m, i);
      const float* Dl = s4_D + ((size_t)m * NL_ + i) * H_;
      const int cgrid = (B_ / 16) * H_;
      if (Lm == L2_)
        k_conv_gelu_mfma<L2_><<<cgrid, 256, 0, stream>>>(state, Tl, Dl, scratch);
      else if (Lm == L1_)
        k_conv_gelu_mfma<L1_><<<cgrid, 256, 0, stream>>>(state, Tl, Dl, scratch);
      else
        k_conv_gelu_mfma<L0_><<<cgrid, 256, 0, stream>>>(state, Tl, Dl, scratch);
      float* obuf = (i == NL_ - 1 && final_out) ? final_out : state;
      const size_t wbase = ((size_t)m * NL_ + i) * 2 * H_ * H_;
      if (Lm == L2_)
        k_glu_ln_mfma2<2><<<B_ * (Lm / 32), 256, 0, stream>>>(
            oWhi + wbase, oWlo + wbase,
            out_b + ((size_t)m * NL_ + i) * 2 * H_,
            ln_g + ((size_t)m * NL_ + i) * H_,
            ln_b + ((size_t)m * NL_ + i) * H_,
            scratch, state, obuf, Lm);
      else
        k_glu_ln_mfma2<4><<<B_ * (Lm / 64), 256, 0, stream>>>(
            oWhi + wbase, oWlo + wbase,
            out_b + ((size_t)m * NL_ + i) * 2 * H_,
            ln_g + ((size_t)m * NL_ + i) * H_,
            ln_b + ((size_t)m * NL_ + i) * H_,
            scratch, state, obuf, Lm);
    }
  };

  // model 0 on enc2 (L=160): encoder out-of-place into st0
  run_model(0, enc2, st0, scr0, L2_, nullptr);
  // dec1 = enc2 + m0-out (elementwise in place)
  k_add<<<(B_ * H_ * L2_) / 256, 256, 0, stream>>>(enc2, st0);
  // dec21 = convT(dec1, up_W) + up_b + enc1 -> slotB
  k_convT_mfma<<<B_ * (L2_ / 16), 256, 0, stream>>>(uphi, uplo, up_b, enc1, enc2, dec21,
                                                    L2_, 1);
  // model 1 on dec21 (L=320): encoder into st1 (slotA)
  run_model(1, dec21, st1, scr1, L1_, nullptr);
  // dec32 = convT(m1-out, up1_W) + enc0 -> slotB
  k_convT_mfma<<<B_ * (L1_ / 16), 256, 0, stream>>>(u1hi, u1lo, up_b, x, st1, dec32,
                                                    L1_, 0);
  // model 2 on dec32 (L=640): encoder into st2 (slotA); final layer -> d_out
  run_model(2, dec32, st2, scr2, L0_, outp);
}

// Round 13
// 1166.510 us; speedup vs baseline: 7.3179x; 1.0677x over previous
//
#include <hip/hip_runtime.h>
#include <hip/hip_bf16.h>
#include <math.h>

namespace {

constexpr int B_ = 256, H_ = 64, L0_ = 640, L1_ = 320, L2_ = 160;
constexpr int N2_ = 32, NL_ = 8, NM_ = 3;

typedef __attribute__((ext_vector_type(8))) short bf16x8;
typedef __attribute__((ext_vector_type(4))) float f32x4;

__device__ __forceinline__ unsigned short f2bf(float x) {
  __hip_bfloat16 h = __float2bfloat16(x);
  unsigned short u;
  __builtin_memcpy(&u, &h, 2);
  return u;
}
__device__ __forceinline__ float bf2f(unsigned short h) {
  return __uint_as_float(((unsigned int)h) << 16);
}
__device__ __forceinline__ float gelu_f(float x) {
  const float t = 0.7978845608028654f * (x + 0.044715f * x * x * x);
  return x / (1.f + __expf(-2.f * t));
}
__device__ __forceinline__ void split8(const float* v, bf16x8& hi, bf16x8& lo) {
#pragma unroll
  for (int i = 0; i < 8; ++i) {
    const unsigned short hh = f2bf(v[i]);
    hi[i] = (short)hh;
    lo[i] = (short)f2bf(v[i] - bf2f(hh));
  }
}

// ---------------------------------------------------------------------------
// K + Toeplitz-fragment precompute (spill-free). One block per (m, layer, h).
// ---------------------------------------------------------------------------
__global__ __launch_bounds__(256) void k_compute_K_tt(
    const float* __restrict__ log_dt, const float* __restrict__ C,
    const float* __restrict__ logA, const float* __restrict__ Aim,
    unsigned short* __restrict__ TtG) {
  const int bid = blockIdx.x;
  const int m = bid / (NL_ * H_);
  const int rest = bid % (NL_ * H_);
  const int li = rest / H_;
  const int h = rest % H_;
  const int ph = (m * NL_ + li) * H_ + h;
  __shared__ float qkr[7][N2_], qki[7][N2_];
  __shared__ float sCr[N2_], sCi[N2_];
  __shared__ float Ksh[L0_];
  const int tid = threadIdx.x;
  if (tid < N2_) {
    const int n = tid;
    const float dt = expf(log_dt[ph]);
    const float Are = -expf(logA[(size_t)ph * N2_ + n]);
    const float Ai = Aim[(size_t)ph * N2_ + n];
    const float ar = dt * Are, ai = dt * Ai;
    const float er = expf(ar);
    float sn, cs;
    sincosf(ai, &sn, &cs);
    const float mr = er * cs - 1.f;
    const float mi = er * sn;
    const float den = Are * Are + Ai * Ai;
    const float qr_ = (mr * Are + mi * Ai) / den;
    const float qi_ = (mi * Are - mr * Ai) / den;
    const float C0 = C[((size_t)ph * N2_ + n) * 2 + 0];
    const float C1 = C[((size_t)ph * N2_ + n) * 2 + 1];
    sCr[n] = C0 * qr_ - C1 * qi_;
    sCi[n] = C0 * qi_ + C1 * qr_;
    float qr = er * cs, qi = er * sn;
#pragma unroll
    for (int k = 0; k < 7; ++k) {
      qkr[k][n] = qr;
      qki[k][n] = qi;
      const float nr = qr * qr - qi * qi;
      qi = 2.f * qr * qi;
      qr = nr;
    }
  }
  __syncthreads();
  const int Lm = (m == 0) ? L2_ : (m == 1) ? L1_ : L0_;
  const int NT = Lm / 16;

  const int l0 = tid >> 2;
  const int g = tid & 3;
  float pr[8], pi[8];
#pragma unroll
  for (int j = 0; j < 8; ++j) { pr[j] = 1.f; pi[j] = 0.f; }
#pragma unroll
  for (int k = 0; k < 6; ++k) {
    if ((l0 >> k) & 1) {
#pragma unroll
      for (int j = 0; j < 8; ++j) {
        const int n = g * 8 + j;
        const float qr = qkr[k][n], qi = qki[k][n];
        const float nr = pr[j] * qr - pi[j] * qi;
        pi[j] = pr[j] * qi + pi[j] * qr;
        pr[j] = nr;
      }
    }
  }
  for (int l = l0; l < Lm; l += 64) {
    float acc = 0.f;
#pragma unroll
    for (int j = 0; j < 8; ++j) {
      const int n = g * 8 + j;
      acc += sCr[n] * pr[j] - sCi[n] * pi[j];
    }
    acc += __shfl_xor(acc, 1);
    acc += __shfl_xor(acc, 2);
    if (g == 0) Ksh[l] = 2.f * acc;
    if (l + 64 < Lm) {
#pragma unroll
      for (int j = 0; j < 8; ++j) {
        const int n = g * 8 + j;
        const float qr = qkr[6][n], qi = qki[6][n];
        const float nr = pr[j] * qr - pi[j] * qi;
        pi[j] = pr[j] * qi + pi[j] * qr;
        pr[j] = nr;
      }
    }
  }
  __syncthreads();
  const size_t base_tiles = ((m == 0) ? 0 : (m == 1) ? (size_t)64 * NL_ * 10
                                                     : (size_t)64 * NL_ * 30) +
                            (size_t)li * 64 * NT + (size_t)h * NT;
  unsigned short* Tg = TtG + base_tiles * 512;
  for (int w = tid; w < NT * 256; w += 256) {
    const int nd = w >> 8;
    const int rem = w & 255;
    const int lane = rem >> 2;
    const int pp = rem & 3;
    const int base = nd * 16 + (lane & 15) - ((lane >> 4) << 3) - 2 * pp;
    const float f0 = (base >= 0) ? Ksh[base] : 0.f;
    const float f1 = (base - 1 >= 0) ? Ksh[base - 1] : 0.f;
    *(unsigned int*)&Tg[nd * 512 + lane * 8 + 2 * pp] =
        (unsigned int)f2bf(f0) | ((unsigned int)f2bf(f1) << 16);
  }
}

// ---------------------------------------------------------------------------
// Pack f32 weights -> bf16 hi/lo (identity indexing).
// ---------------------------------------------------------------------------
__global__ void k_pack_w(const float* __restrict__ W, unsigned short* __restrict__ hi,
                         unsigned short* __restrict__ lo, int n) {
  const int p = blockIdx.x * 256 + threadIdx.x;
  if (p < n) {
    const float w = W[p];
    const unsigned short h = f2bf(w);
    hi[p] = h;
    lo[p] = f2bf(w - bf2f(h));
  }
}

// Gather-pack conv weights into P[k][o*64+i] hi/lo. src = o*so + i*si + k.
__global__ void k_pack_gather(const float* __restrict__ W, unsigned short* __restrict__ hi,
                              unsigned short* __restrict__ lo, int n, int so, int si) {
  const int idx = blockIdx.x * 256 + threadIdx.x;
  if (idx < n) {
    const int k = idx >> 12;
    const int rem = idx & 4095;
    const int o = rem >> 6;
    const int i = rem & 63;
    const float w = W[o * so + i * si + k];
    const unsigned short h = f2bf(w);
    hi[idx] = h;
    lo[idx] = f2bf(w - bf2f(h));
  }
}

// ---------------------------------------------------------------------------
// MFMA 1x1 encoder v2: LDS-staged (transpose-once, convert-once).
// Block = (b, 32-l tile), 4 waves. OUT-OF-PLACE only.
// ---------------------------------------------------------------------------
__global__ __launch_bounds__(256) void k_enc_mfma(
    const unsigned short* __restrict__ Whi, const unsigned short* __restrict__ Wlo,
    const float* __restrict__ bvec, const float* __restrict__ in_,
    float* __restrict__ out, int Lcur) {
  constexpr int KS = 72;
  __shared__ __align__(16) unsigned short Xhi[32 * KS];
  __shared__ __align__(16) unsigned short Xlo[32 * KS];
  const int tid = threadIdx.x;
  const int w = tid >> 6, lane = tid & 63, c15 = lane & 15, g4 = lane >> 4;
  const int tilesPerB = Lcur >> 5;
  const int b = blockIdx.x / tilesPerB;
  const int l0 = ((blockIdx.x % tilesPerB) << 5);
  const size_t bbase = (size_t)b * H_ * Lcur;

#pragma unroll
  for (int e = 0; e < 8; ++e) {
    const int idx = e * 256 + tid;
    const int ch = idx >> 5;
    const int c = idx & 31;
    const float v = in_[bbase + (size_t)ch * Lcur + l0 + c];
    const unsigned short hh = f2bf(v);
    Xhi[c * KS + ch] = hh;
    Xlo[c * KS + ch] = f2bf(v - bf2f(hh));
  }
  bf16x8 wh[2], wl[2];
#pragma unroll
  for (int q = 0; q < 2; ++q) {
    const int ra = (16 * w + c15) * 64 + q * 32 + 8 * g4;
    wh[q] = *(const bf16x8*)(Whi + ra);
    wl[q] = *(const bf16x8*)(Wlo + ra);
  }
  __syncthreads();

  f32x4 acc[2] = {{0.f, 0.f, 0.f, 0.f}, {0.f, 0.f, 0.f, 0.f}};
#pragma unroll
  for (int lt = 0; lt < 2; ++lt) {
    const int lc = lt * 16 + c15;
#pragma unroll
    for (int q = 0; q < 2; ++q) {
      const int crow = q * 32 + 8 * g4;
      const bf16x8 xh = *(const bf16x8*)&Xhi[lc * KS + crow];
      const bf16x8 xl = *(const bf16x8*)&Xlo[lc * KS + crow];
      acc[lt] = __builtin_amdgcn_mfma_f32_16x16x32_bf16(wh[q], xh, acc[lt], 0, 0, 0);
      acc[lt] = __builtin_amdgcn_mfma_f32_16x16x32_bf16(wh[q], xl, acc[lt], 0, 0, 0);
      acc[lt] = __builtin_amdgcn_mfma_f32_16x16x32_bf16(wl[q], xh, acc[lt], 0, 0, 0);
    }
  }
#pragma unroll
  for (int lt = 0; lt < 2; ++lt) {
#pragma unroll
    for (int r = 0; r < 4; ++r) {
      const int ca = 16 * w + 4 * g4 + r;
      out[bbase + (size_t)ca * Lcur + l0 + lt * 16 + c15] = acc[lt][r] + bvec[ca];
    }
  }
}

// ---------------------------------------------------------------------------
// MFMA strided down-conv v2 (k=KW, s=2, pad=PAD), LDS-staged.
// ---------------------------------------------------------------------------
template <int KW, int PAD>
__global__ __launch_bounds__(256) void k_down_mfma(
    const unsigned short* __restrict__ Phi, const unsigned short* __restrict__ Plo,
    const float* __restrict__ bias, const float* __restrict__ in_,
    float* __restrict__ out, int Lin, int Lout) {
  constexpr int WCOLS = 62 + KW;
  constexpr int KS = 72;
  __shared__ __align__(16) unsigned short Xhi[WCOLS * KS];
  __shared__ __align__(16) unsigned short Xlo[WCOLS * KS];
  const int tid = threadIdx.x;
  const int w = tid >> 6, lane = tid & 63, c15 = lane & 15, g4 = lane >> 4;
  const int tilesPerB = Lout >> 5;
  const int b = blockIdx.x / tilesPerB;
  const int t0 = ((blockIdx.x % tilesPerB) << 5);
  const int c0 = 2 * t0 - PAD;
  const size_t ibase = (size_t)b * H_ * Lin;

  for (int idx = tid; idx < 64 * WCOLS; idx += 256) {
    const int ch = idx / WCOLS;
    const int c = idx % WCOLS;
    const int gc = c0 + c;
    const float v = (gc >= 0 && gc < Lin) ? in_[ibase + (size_t)ch * Lin + gc] : 0.f;
    const unsigned short hh = f2bf(v);
    Xhi[c * KS + ch] = hh;
    Xlo[c * KS + ch] = f2bf(v - bf2f(hh));
  }
  bf16x8 wh[KW][2], wl[KW][2];
#pragma unroll
  for (int k = 0; k < KW; ++k)
#pragma unroll
    for (int q = 0; q < 2; ++q) {
      const int ra = (k << 12) + (16 * w + c15) * 64 + q * 32 + 8 * g4;
      wh[k][q] = *(const bf16x8*)(Phi + ra);
      wl[k][q] = *(const bf16x8*)(Plo + ra);
    }
  __syncthreads();

  f32x4 acc[2] = {{0.f, 0.f, 0.f, 0.f}, {0.f, 0.f, 0.f, 0.f}};
#pragma unroll
  for (int lt = 0; lt < 2; ++lt) {
#pragma unroll
    for (int q = 0; q < 2; ++q) {
      const int crow = q * 32 + 8 * g4;
#pragma unroll
      for (int k = 0; k < KW; ++k) {
        const int lc = 2 * (lt * 16 + c15) + k;
        const bf16x8 xh = *(const bf16x8*)&Xhi[lc * KS + crow];
        const bf16x8 xl = *(const bf16x8*)&Xlo[lc * KS + crow];
        acc[lt] = __builtin_amdgcn_mfma_f32_16x16x32_bf16(wh[k][q], xh, acc[lt], 0, 0, 0);
        acc[lt] = __builtin_amdgcn_mfma_f32_16x16x32_bf16(wh[k][q], xl, acc[lt], 0, 0, 0);
        acc[lt] = __builtin_amdgcn_mfma_f32_16x16x32_bf16(wl[k][q], xh, acc[lt], 0, 0, 0);
      }
    }
  }
  const size_t obase = (size_t)b * H_ * Lout;
#pragma unroll
  for (int lt = 0; lt < 2; ++lt) {
#pragma unroll
    for (int r = 0; r < 4; ++r) {
      const int ca = 16 * w + 4 * g4 + r;
      out[obase + (size_t)ca * Lout + t0 + lt * 16 + c15] = acc[lt][r] + bias[ca];
    }
  }
}

// ---------------------------------------------------------------------------
// MFMA ConvTranspose1d v2 (k=3 s=2 p=1 op=1), LDS-staged; optional fused
// second input (staged as in_+in2, f32 exact) and +bias? +skip epilogue.
// NOTE: out must NOT alias in_/in2/skip (cross-block race otherwise).
// ---------------------------------------------------------------------------
__global__ __launch_bounds__(256) void k_convT_mfma(
    const unsigned short* __restrict__ Phi, const unsigned short* __restrict__ Plo,
    const float* __restrict__ bias, const float* __restrict__ skip,
    const float* __restrict__ in_, const float* __restrict__ in2,
    float* __restrict__ out, int Lin, int hasBias) {
  constexpr int WCOLS = 33;
  constexpr int KS = 72;
  __shared__ __align__(16) unsigned short Xhi[WCOLS * KS];
  __shared__ __align__(16) unsigned short Xlo[WCOLS * KS];
  const int tid = threadIdx.x;
  const int w = tid >> 6, lane = tid & 63, c15 = lane & 15, g4 = lane >> 4;
  const int tilesPerB = Lin >> 5;
  const int b = blockIdx.x / tilesPerB;
  const int j0 = ((blockIdx.x % tilesPerB) << 5);
  const int Lout = 2 * Lin;
  const size_t ibase = (size_t)b * H_ * Lin;

  for (int idx = tid; idx < 64 * WCOLS; idx += 256) {
    const int ch = idx / WCOLS;
    const int c = idx % WCOLS;
    const int gc = j0 + c;
    float v = 0.f;
    if (gc < Lin) {
      const size_t p = ibase + (size_t)ch * Lin + gc;
      v = in_[p];
      if (in2) v += in2[p];
    }
    const unsigned short hh = f2bf(v);
    Xhi[c * KS + ch] = hh;
    Xlo[c * KS + ch] = f2bf(v - bf2f(hh));
  }
  bf16x8 wh[3][2], wl[3][2];
#pragma unroll
  for (int k = 0; k < 3; ++k)
#pragma unroll
    for (int q = 0; q < 2; ++q) {
      const int ra = (k << 12) + (16 * w + c15) * 64 + q * 32 + 8 * g4;
      wh[k][q] = *(const bf16x8*)(Phi + ra);
      wl[k][q] = *(const bf16x8*)(Plo + ra);
    }
  __syncthreads();

  f32x4 aE[2] = {{0.f, 0.f, 0.f, 0.f}, {0.f, 0.f, 0.f, 0.f}};
  f32x4 aO[2] = {{0.f, 0.f, 0.f, 0.f}, {0.f, 0.f, 0.f, 0.f}};
#pragma unroll
  for (int lt = 0; lt < 2; ++lt) {
    const int lc = lt * 16 + c15;
#pragma unroll
    for (int q = 0; q < 2; ++q) {
      const int crow = q * 32 + 8 * g4;
      const bf16x8 xjh = *(const bf16x8*)&Xhi[lc * KS + crow];
      const bf16x8 xjl = *(const bf16x8*)&Xlo[lc * KS + crow];
      const bf16x8 xnh = *(const bf16x8*)&Xhi[(lc + 1) * KS + crow];
      const bf16x8 xnl = *(const bf16x8*)&Xlo[(lc + 1) * KS + crow];
      aE[lt] = __builtin_amdgcn_mfma_f32_16x16x32_bf16(wh[1][q], xjh, aE[lt], 0, 0, 0);
      aE[lt] = __builtin_amdgcn_mfma_f32_16x16x32_bf16(wh[1][q], xjl, aE[lt], 0, 0, 0);
      aE[lt] = __builtin_amdgcn_mfma_f32_16x16x32_bf16(wl[1][q], xjh, aE[lt], 0, 0, 0);
      aO[lt] = __builtin_amdgcn_mfma_f32_16x16x32_bf16(wh[2][q], xjh, aO[lt], 0, 0, 0);
      aO[lt] = __builtin_amdgcn_mfma_f32_16x16x32_bf16(wh[2][q], xjl, aO[lt], 0, 0, 0);
      aO[lt] = __builtin_amdgcn_mfma_f32_16x16x32_bf16(wl[2][q], xjh, aO[lt], 0, 0, 0);
      aO[lt] = __builtin_amdgcn_mfma_f32_16x16x32_bf16(wh[0][q], xnh, aO[lt], 0, 0, 0);
      aO[lt] = __builtin_amdgcn_mfma_f32_16x16x32_bf16(wh[0][q], xnl, aO[lt], 0, 0, 0);
      aO[lt] = __builtin_amdgcn_mfma_f32_16x16x32_bf16(wl[0][q], xnh, aO[lt], 0, 0, 0);
    }
  }
  const size_t obase = (size_t)b * H_ * Lout;
#pragma unroll
  for (int lt = 0; lt < 2; ++lt) {
#pragma unroll
    for (int r = 0; r < 4; ++r) {
      const int ca = 16 * w + 4 * g4 + r;
      const float bb = hasBias ? bias[ca] : 0.f;
      const size_t pos = obase + (size_t)ca * Lout + 2 * (j0 + lt * 16 + c15);
      out[pos] = aE[lt][r] + bb + skip[pos];
      out[pos + 1] = aO[lt][r] + bb + skip[pos + 1];
    }
  }
}

// ---------------------------------------------------------------------------
// MFMA causal conv + D-skip + gelu, v3 (unchanged).
// ---------------------------------------------------------------------------
template <int L>
__global__ __launch_bounds__(256) void k_conv_gelu_mfma(
    const float* __restrict__ u, const unsigned short* __restrict__ Tt,
    const float* __restrict__ D, float* __restrict__ y) {
  constexpr int NT = L / 16;
  constexpr int NG = (NT + 3) / 4;
  constexpr int LP = L + 8;
  __shared__ unsigned short uhi[16 * LP];

  const int h = blockIdx.x & 63;
  const int b0 = (blockIdx.x >> 6) * 16;
  const int tid = threadIdx.x;

  {
    const int row = tid >> 4;
    const int ct = tid & 15;
    const float4* src = (const float4*)(u + ((size_t)(b0 + row) * H_ + h) * L);
#pragma unroll
    for (int c4 = ct; c4 < L / 4; c4 += 16) {
      const float4 v = src[c4];
      const unsigned int p0 = (unsigned int)f2bf(v.x) | ((unsigned int)f2bf(v.y) << 16);
      const unsigned int p1 = (unsigned int)f2bf(v.z) | ((unsigned int)f2bf(v.w) << 16);
      unsigned int* dst = (unsigned int*)&uhi[row * LP + 4 * c4];
      dst[0] = p0;
      dst[1] = p1;
    }
  }
  __syncthreads();

  const int wv = tid >> 6;
  const int lane = tid & 63;
  const float Dh = D[h];
  const int lquad = lane & 15;
  const int lhi = lane >> 4;
  const unsigned short* Th = Tt + (size_t)h * NT * 512 + lane * 8;

  for (int g = wv; g < NG; g += 4) {
    const int t0 = g * 4;
    const int ntile = (NT - t0 < 4) ? (NT - t0) : 4;
    f32x4 acc[4];
#pragma unroll
    for (int t = 0; t < 4; ++t) acc[t] = (f32x4){0.f, 0.f, 0.f, 0.f};
    const int nsteps = ((t0 + ntile - 1) * 16) / 32 + 1;
    for (int s = 0; s < nsteps; ++s) {
      const int j0 = 32 * s;
      const int colbase = j0 + (lhi << 3);
      const bf16x8 ah = *(const bf16x8*)&uhi[lquad * LP + colbase];
#pragma unroll
      for (int t = 0; t < 4; ++t) {
        if (t >= ntile) break;
        const int d0 = (t0 + t) * 16 - j0;
        if (d0 < 0) continue;
        const bf16x8 bf = *(const bf16x8*)(Th + (size_t)(d0 >> 4) * 512);
        acc[t] = __builtin_amdgcn_mfma_f32_16x16x32_bf16(ah, bf, acc[t], 0, 0, 0);
      }
    }
#pragma unroll
    for (int t = 0; t < 4; ++t) {
      if (t >= ntile) break;
      const int l = (t0 + t) * 16 + lquad;
#pragma unroll
      for (int r = 0; r < 4; ++r) {
        const int row = (lhi << 2) + r;
        const float uv = bf2f(uhi[row * LP + l]);
        const float val = acc[t][r] + uv * Dh;
        y[((size_t)(b0 + row) * H_ + h) * L + l] = gelu_f(val);
      }
    }
  }
}

// ---------------------------------------------------------------------------
// MFMA out-proj (64->128) + GLU + residual + LayerNorm, v2 (unchanged).
// ---------------------------------------------------------------------------
template <int LT>
__global__ __launch_bounds__(256) void k_glu_ln_mfma2(
    const unsigned short* __restrict__ Whi, const unsigned short* __restrict__ Wlo,
    const float* __restrict__ ob, const float* __restrict__ lng,
    const float* __restrict__ lnb, const float* __restrict__ ybuf,
    const float* __restrict__ xbuf, float* __restrict__ obuf, int Lcur) {
  constexpr int LTILE = LT * 16;
  constexpr int KS = 72;
  __shared__ __align__(16) unsigned short Yhi[LTILE * KS];
  __shared__ __align__(16) unsigned short Ylo[LTILE * KS];
  __shared__ float red[4][LTILE][2];
  const int tid = threadIdx.x;
  const int w = tid >> 6, lane = tid & 63, c15 = lane & 15, g4 = lane >> 4;
  const int tilesPerB = Lcur / LTILE;
  const int b = blockIdx.x / tilesPerB;
  const int l0 = (blockIdx.x % tilesPerB) * LTILE;
  const size_t bbase = (size_t)b * H_ * Lcur;

  constexpr int NE = (64 * LTILE) / 256;
#pragma unroll
  for (int e = 0; e < NE; ++e) {
    const int idx = e * 256 + tid;
    const int k = idx / LTILE;
    const int l = idx % LTILE;
    const float v = ybuf[bbase + (size_t)k * Lcur + l0 + l];
    const unsigned short hh = f2bf(v);
    Yhi[l * KS + k] = hh;
    Ylo[l * KS + k] = f2bf(v - bf2f(hh));
  }

  bf16x8 wah[2], wal[2], wgh[2], wgl[2];
#pragma unroll
  for (int q = 0; q < 2; ++q) {
    const int crow = q * 32 + 8 * g4;
    const int ra = (16 * w + c15) * 64 + crow;
    const int rg = ((64 + 16 * w) + c15) * 64 + crow;
    wah[q] = *(const bf16x8*)(Whi + ra);
    wal[q] = *(const bf16x8*)(Wlo + ra);
    wgh[q] = *(const bf16x8*)(Whi + rg);
    wgl[q] = *(const bf16x8*)(Wlo + rg);
  }
  __syncthreads();

  float wv[LT][4];
#pragma unroll
  for (int lt = 0; lt < LT; ++lt) {
    const int ll = lt * 16 + c15;
    f32x4 accA = {0.f, 0.f, 0.f, 0.f}, accG = {0.f, 0.f, 0.f, 0.f};
#pragma unroll
    for (int q = 0; q < 2; ++q) {
      const int crow = q * 32 + 8 * g4;
      const bf16x8 yh = *(const bf16x8*)&Yhi[ll * KS + crow];
      const bf16x8 yl = *(const bf16x8*)&Ylo[ll * KS + crow];
      accA = __builtin_amdgcn_mfma_f32_16x16x32_bf16(wah[q], yh, accA, 0, 0, 0);
      accA = __builtin_amdgcn_mfma_f32_16x16x32_bf16(wah[q], yl, accA, 0, 0, 0);
      accA = __builtin_amdgcn_mfma_f32_16x16x32_bf16(wal[q], yh, accA, 0, 0, 0);
      accG = __builtin_amdgcn_mfma_f32_16x16x32_bf16(wgh[q], yh, accG, 0, 0, 0);
      accG = __builtin_amdgcn_mfma_f32_16x16x32_bf16(wgh[q], yl, accG, 0, 0, 0);
      accG = __builtin_amdgcn_mfma_f32_16x16x32_bf16(wgl[q], yh, accG, 0, 0, 0);
    }
    float s1 = 0.f, s2 = 0.f;
#pragma unroll
    for (int r = 0; r < 4; ++r) {
      const int ca = 16 * w + 4 * g4 + r;
      const float a = accA[r] + ob[ca];
      const float g = accG[r] + ob[H_ + ca];
      const float z = a / (1.f + expf(-g));
      const float xv = xbuf[bbase + (size_t)ca * Lcur + l0 + ll];
      wv[lt][r] = z + xv;
      s1 += wv[lt][r];
      s2 += wv[lt][r] * wv[lt][r];
    }
    s1 += __shfl_xor(s1, 16);
    s2 += __shfl_xor(s2, 16);
    s1 += __shfl_xor(s1, 32);
    s2 += __shfl_xor(s2, 32);
    if (g4 == 0) {
      red[w][ll][0] = s1;
      red[w][ll][1] = s2;
    }
  }
  __syncthreads();
#pragma unroll
  for (int lt = 0; lt < LT; ++lt) {
    const int ll = lt * 16 + c15;
    float t1 = 0.f, t2 = 0.f;
#pragma unroll
    for (int q = 0; q < 4; ++q) {
      t1 += red[q][ll][0];
      t2 += red[q][ll][1];
    }
    const float mean = t1 * (1.f / 64.f);
    const float var = t2 * (1.f / 64.f) - mean * mean;
    const float rstd = rsqrtf(var + 1e-5f);
#pragma unroll
    for (int r = 0; r < 4; ++r) {
      const int ca = 16 * w + 4 * g4 + r;
      obuf[bbase + (size_t)ca * Lcur + l0 + ll] =
          (wv[lt][r] - mean) * rstd * lng[ca] + lnb[ca];
    }
  }
}

}  // namespace

// ---------------------------------------------------------------------------
extern "C" void kernel_launch(void* const* d_in, const int* in_sizes, int n_in,
                              void* d_out, int out_size, void* d_ws, size_t ws_size,
                              hipStream_t stream) {
  const float* x       = (const float*)d_in[0];
  const float* enc_W   = (const float*)d_in[1];
  const float* enc_b   = (const float*)d_in[2];
  const float* ln_g    = (const float*)d_in[3];
  const float* ln_b    = (const float*)d_in[4];
  const float* s4_D    = (const float*)d_in[5];
  const float* s4_ldt  = (const float*)d_in[6];
  const float* s4_C    = (const float*)d_in[7];
  const float* s4_logA = (const float*)d_in[8];
  const float* s4_Aim  = (const float*)d_in[9];
  const float* out_W   = (const float*)d_in[10];
  const float* out_b   = (const float*)d_in[11];
  const float* cd1_W   = (const float*)d_in[12];
  const float* cd1_b   = (const float*)d_in[13];
  const float* cd2_W   = (const float*)d_in[14];
  const float* cd2_b   = (const float*)d_in[15];
  const float* up_W    = (const float*)d_in[16];
  const float* up_b    = (const float*)d_in[17];
  const float* up1_W   = (const float*)d_in[18];
  float* outp = (float*)d_out;

  // ---- workspace arena (~127.2 MB, lifetime-overlapped) ----
  unsigned short* TtG = (unsigned short*)d_ws;
  const size_t ttg_shorts = (size_t)64 * NL_ * 70 * 512;      // 18.35M
  const size_t nWsz = (size_t)NM_ * NL_ * 2 * H_ * H_;        // 1.57M
  unsigned short* oWhi = TtG + ttg_shorts;
  unsigned short* oWlo = oWhi + nWsz;
  unsigned short* eWhi = oWlo + nWsz;
  unsigned short* eWlo = eWhi + 3 * 4096;
  unsigned short* c1hi = eWlo + 3 * 4096;
  unsigned short* c1lo = c1hi + 3 * 4096;
  unsigned short* c2hi = c1lo + 3 * 4096;
  unsigned short* c2lo = c2hi + 2 * 4096;
  unsigned short* uphi = c2lo + 2 * 4096;
  unsigned short* uplo = uphi + 3 * 4096;
  unsigned short* u1hi = uplo + 3 * 4096;
  unsigned short* u1lo = u1hi + 3 * 4096;
  float* slotA = (float*)(u1lo + 3 * 4096);            // B*H*L0 floats
  float* slotB = slotA + (size_t)B_ * H_ * L0_;        // B*H*L0 floats

  // lifetime map (stream-serial, encoders all OUT-OF-PLACE):
  float* enc1  = slotA;                                // B*H*L1
  float* enc2  = slotA + (size_t)B_ * H_ * L1_;        // B*H*L2
  float* st0   = slotB;                                // B*H*L2
  float* scr0  = slotB + (size_t)B_ * H_ * L2_;        // B*H*L2
  float* dec21 = slotB + (size_t)2 * B_ * H_ * L2_;    // B*H*L1 — DISJOINT from
                                                       // st0 (read by fused convT)
  float* st1   = slotA;                                // B*H*L1 (enc1/enc2 dead)
  float* scr1  = slotA + (size_t)B_ * H_ * L1_;        // B*H*L1
  float* dec32 = slotB;                                // B*H*L0 (st0/dec21 dead)
  float* st2   = slotA;                                // B*H*L0 (st1/scr1 dead)
  float* scr2  = slotB;                                // B*H*L0 (dec32 dead post-enc)

  auto tt_layer = [&](int m, int i) -> const unsigned short* {
    const size_t NTm = (m == 0) ? 10 : (m == 1) ? 20 : 40;
    const size_t base = (m == 0) ? 0 : (m == 1) ? (size_t)64 * NL_ * 10
                                                : (size_t)64 * NL_ * 30;
    return TtG + (base + (size_t)i * 64 * NTm) * 512;
  };

  k_compute_K_tt<<<NM_ * NL_ * H_, 256, 0, stream>>>(s4_ldt, s4_C, s4_logA, s4_Aim, TtG);
  k_pack_w<<<((int)nWsz + 255) / 256, 256, 0, stream>>>(out_W, oWhi, oWlo, (int)nWsz);
  k_pack_w<<<48, 256, 0, stream>>>(enc_W, eWhi, eWlo, 3 * 4096);
  k_pack_gather<<<48, 256, 0, stream>>>(cd1_W, c1hi, c1lo, 3 * 4096, 192, 3);
  k_pack_gather<<<32, 256, 0, stream>>>(cd2_W, c2hi, c2lo, 2 * 4096, 128, 2);
  k_pack_gather<<<48, 256, 0, stream>>>(up_W, uphi, uplo, 3 * 4096, 3, 192);
  k_pack_gather<<<48, 256, 0, stream>>>(up1_W, u1hi, u1lo, 3 * 4096, 3, 192);

  // enc1 = conv_d1(x), enc2 = conv_d2(enc1)
  k_down_mfma<3, 1><<<B_ * (L1_ / 32), 256, 0, stream>>>(c1hi, c1lo, cd1_b, x, enc1,
                                                         L0_, L1_);
  k_down_mfma<2, 0><<<B_ * (L2_ / 32), 256, 0, stream>>>(c2hi, c2lo, cd2_b, enc1, enc2,
                                                         L1_, L2_);

  auto run_model = [&](int m, const float* input, float* state, float* scratch,
                       int Lm, float* final_out) {
    k_enc_mfma<<<B_ * (Lm / 32), 256, 0, stream>>>(eWhi + m * 4096, eWlo + m * 4096,
                                                   enc_b + (size_t)m * H_, input, state, Lm);
    for (int i = 0; i < NL_; ++i) {
      const unsigned short* Tl = tt_layer(m, i);
      const float* Dl = s4_D + ((size_t)m * NL_ + i) * H_;
      const int cgrid = (B_ / 16) * H_;
      if (Lm == L2_)
        k_conv_gelu_mfma<L2_><<<cgrid, 256, 0, stream>>>(state, Tl, Dl, scratch);
      else if (Lm == L1_)
        k_conv_gelu_mfma<L1_><<<cgrid, 256, 0, stream>>>(state, Tl, Dl, scratch);
      else
        k_conv_gelu_mfma<L0_><<<cgrid, 256, 0, stream>>>(state, Tl, Dl, scratch);
      float* obuf = (i == NL_ - 1 && final_out) ? final_out : state;
      const size_t wbase = ((size_t)m * NL_ + i) * 2 * H_ * H_;
      if (Lm == L2_)
        k_glu_ln_mfma2<2><<<B_ * (Lm / 32), 256, 0, stream>>>(
            oWhi + wbase, oWlo + wbase,
            out_b + ((size_t)m * NL_ + i) * 2 * H_,
            ln_g + ((size_t)m * NL_ + i) * H_,
            ln_b + ((size_t)m * NL_ + i) * H_,
            scratch, state, obuf, Lm);
      else
        k_glu_ln_mfma2<4><<<B_ * (Lm / 64), 256, 0, stream>>>(
            oWhi + wbase, oWlo + wbase,
            out_b + ((size_t)m * NL_ + i) * 2 * H_,
            ln_g + ((size_t)m * NL_ + i) * H_,
            ln_b + ((size_t)m * NL_ + i) * H_,
            scratch, state, obuf, Lm);
    }
  };

  // model 0 on enc2 (L=160): encoder out-of-place into st0
  run_model(0, enc2, st0, scr0, L2_, nullptr);
  // dec21 = convT(enc2 + m0out, up_W) + up_b + enc1  (fused add; dec21 disjoint
  // from st0/enc2/enc1 -> no cross-block alias)
  k_convT_mfma<<<B_ * (L2_ / 32), 256, 0, stream>>>(uphi, uplo, up_b, enc1, enc2, st0,
                                                    dec21, L2_, 1);
  // model 1 on dec21 (L=320): encoder into st1 (slotA)
  run_model(1, dec21, st1, scr1, L1_, nullptr);
  // dec32 = convT(m1-out, up1_W) + enc0 -> slotB (dec21/st0 dead)
  k_convT_mfma<<<B_ * (L1_ / 32), 256, 0, stream>>>(u1hi, u1lo, up_b, x, st1, nullptr,
                                                    dec32, L1_, 0);
  // model 2 on dec32 (L=640): encoder into st2 (slotA); final layer -> d_out
  run_model(2, dec32, st2, scr2, L0_, outp);
}